// Round 1
// baseline (663.635 us; speedup 1.0000x reference)
//
#include <hip/hip_runtime.h>
#include <hip/hip_bf16.h>

#define DIM_ 2048
#define L_   2048
#define B_   2
#define H_   16
#define DH_  128

typedef __attribute__((ext_vector_type(4))) float fp32x4;
typedef __attribute__((ext_vector_type(8))) short s16x8;

__device__ __forceinline__ unsigned short bf16_rne(float f) {
    unsigned u = __builtin_bit_cast(unsigned, f);
    u += 0x7fffu + ((u >> 16) & 1u);
    return (unsigned short)(u >> 16);
}

__device__ __forceinline__ fp32x4 MFMA(s16x8 a, s16x8 b, fp32x4 c) {
    return __builtin_amdgcn_mfma_f32_16x16x32_bf16(a, b, c, 0, 0, 0);
}

// C[m][n] = sum_k X[m][k] * W[n][k]  (torch Linear x @ W.T)
// M=4096 (b*L+l), N=2048 (h*DH+d), K=2048
// MODE 0: out q[b,h,l,d] scaled by 1/sqrt(DH); MODE 1: out k[b,h,l,d]; MODE 2: out vT[b,h,d,l]
template <int MODE>
__global__ void __launch_bounds__(256)
proj_gemm(const float* __restrict__ X, const float* __restrict__ W,
          unsigned short* __restrict__ out)
{
    __shared__ __align__(16) char As[128 * 128];  // 128 rows x 64 bf16 (128B rows), XOR-swizzled
    __shared__ __align__(16) char Bs[128 * 128];

    const int tid  = threadIdx.x;
    const int lane = tid & 63;
    const int wid  = tid >> 6;
    const int wm   = (wid >> 1) << 6;   // wave row offset (0/64)
    const int wn   = (wid & 1) << 6;    // wave col offset (0/64)
    const int bm   = blockIdx.x << 7;   // 32 blocks
    const int bn   = blockIdx.y << 7;   // 16 blocks
    const int lr   = lane & 15;
    const int lg   = lane >> 4;

    fp32x4 acc[4][4] = {};

    for (int k0 = 0; k0 < DIM_; k0 += 64) {
        // stage: each thread 8 float4 units per matrix, f32 -> bf16, swizzled ds_write_b64
        #pragma unroll
        for (int i = 0; i < 8; ++i) {
            int u   = i * 256 + tid;       // 0..2047
            int row = u >> 4;              // 0..127
            int c4  = (u & 15) << 2;       // float col, 0..60 step 4
            const float4 av = *reinterpret_cast<const float4*>(&X[(size_t)(bm + row) * DIM_ + k0 + c4]);
            const float4 wv = *reinterpret_cast<const float4*>(&W[(size_t)(bn + row) * DIM_ + k0 + c4]);
            int addr = (row * 128 + (c4 << 1)) ^ ((row & 7) << 4);
            ushort4 ap, wp;
            ap.x = bf16_rne(av.x); ap.y = bf16_rne(av.y); ap.z = bf16_rne(av.z); ap.w = bf16_rne(av.w);
            wp.x = bf16_rne(wv.x); wp.y = bf16_rne(wv.y); wp.z = bf16_rne(wv.z); wp.w = bf16_rne(wv.w);
            *reinterpret_cast<ushort4*>(As + addr) = ap;
            *reinterpret_cast<ushort4*>(Bs + addr) = wp;
        }
        __syncthreads();

        #pragma unroll
        for (int kk = 0; kk < 2; ++kk) {
            s16x8 af[4], bf[4];
            #pragma unroll
            for (int mi = 0; mi < 4; ++mi) {
                int row = wm + mi * 16 + lr;
                af[mi] = *reinterpret_cast<const s16x8*>(As + ((row * 128 + kk * 64 + lg * 16) ^ ((row & 7) << 4)));
            }
            #pragma unroll
            for (int ni = 0; ni < 4; ++ni) {
                int row = wn + ni * 16 + lr;
                bf[ni] = *reinterpret_cast<const s16x8*>(Bs + ((row * 128 + kk * 64 + lg * 16) ^ ((row & 7) << 4)));
            }
            #pragma unroll
            for (int mi = 0; mi < 4; ++mi)
                #pragma unroll
                for (int ni = 0; ni < 4; ++ni)
                    acc[mi][ni] = MFMA(af[mi], bf[ni], acc[mi][ni]);
        }
        __syncthreads();
    }

    const int h  = bn >> 7;       // one head per block column (BN==DH)
    const int bb = bm >> 11;      // batch index (block fully inside one batch)

    if (MODE == 2) {
        // vT[b][h][d][l]; regs are consecutive l -> pack ushort4
        #pragma unroll
        for (int mi = 0; mi < 4; ++mi) {
            int l0 = (bm + wm + mi * 16 + lg * 4) & (L_ - 1);
            #pragma unroll
            for (int ni = 0; ni < 4; ++ni) {
                int d = wn + ni * 16 + lr;
                ushort4 pk;
                pk.x = bf16_rne(acc[mi][ni][0]);
                pk.y = bf16_rne(acc[mi][ni][1]);
                pk.z = bf16_rne(acc[mi][ni][2]);
                pk.w = bf16_rne(acc[mi][ni][3]);
                *reinterpret_cast<ushort4*>(&out[((size_t)(bb * H_ + h) * DH_ + d) * L_ + l0]) = pk;
            }
        }
    } else {
        const float scale = (MODE == 0) ? 0.08838834764831845f : 1.0f;  // 1/sqrt(128)
        #pragma unroll
        for (int mi = 0; mi < 4; ++mi)
            #pragma unroll
            for (int r = 0; r < 4; ++r) {
                int row = bm + wm + mi * 16 + lg * 4 + r;
                int l   = row & (L_ - 1);
                #pragma unroll
                for (int ni = 0; ni < 4; ++ni) {
                    int d = wn + ni * 16 + lr;
                    out[((size_t)(bb * H_ + h) * L_ + l) * DH_ + d] = bf16_rne(acc[mi][ni][r] * scale);
                }
            }
    }
}

// Flash-style attention, no K/V LDS staging (L2-served), max-free online softmax.
// Block = 4 waves x 16 q-rows = 64 q-rows. Grid = B*H*(L/64) = 1024.
__global__ void __launch_bounds__(256)
attn_fused(const unsigned short* __restrict__ qw, const unsigned short* __restrict__ kw,
           const unsigned short* __restrict__ vtw, const float* __restrict__ mask,
           float* __restrict__ out)
{
    __shared__ __align__(16) char P_lds[4][16 * 80];  // per-wave [16 q][40 bf16] (pad 32->40)

    const int tid  = threadIdx.x;
    const int lane = tid & 63;
    const int w    = tid >> 6;
    const int qt   = blockIdx.x & 31;
    const int bh   = blockIdx.x >> 5;
    const int b    = bh >> 4;
    const int h    = bh & 15;
    const int q0   = qt * 64 + w * 16;
    const int lr   = lane & 15;
    const int lg   = lane >> 4;

    const unsigned short* qbase = qw  + (size_t)bh * L_ * DH_;
    const unsigned short* kbase = kw  + (size_t)bh * L_ * DH_;
    const unsigned short* vbase = vtw + (size_t)bh * DH_ * L_;

    // Q fragments held in registers for the whole kernel (q pre-scaled by 1/sqrt(DH))
    s16x8 qf[4];
    #pragma unroll
    for (int kk = 0; kk < 4; ++kk)
        qf[kk] = *reinterpret_cast<const s16x8*>(&qbase[(size_t)(q0 + lr) * DH_ + kk * 32 + lg * 8]);

    float mv[4];
    #pragma unroll
    for (int r = 0; r < 4; ++r) mv[r] = mask[b * L_ + q0 + lg * 4 + r];

    fp32x4 acc_o[8] = {};
    float rowsum[4] = {0.f, 0.f, 0.f, 0.f};

    char* P = &P_lds[w][0];

    for (int kv0 = 0; kv0 < L_; kv0 += 32) {
        // S = Q K^T  (16 q x 32 kv), C-layout: row q = 4*lg+r, col kv = ni*16+lr
        fp32x4 s[2] = {};
        #pragma unroll
        for (int kk = 0; kk < 4; ++kk) {
            #pragma unroll
            for (int ni = 0; ni < 2; ++ni) {
                s16x8 kf = *reinterpret_cast<const s16x8*>(
                    &kbase[(size_t)(kv0 + ni * 16 + lr) * DH_ + kk * 32 + lg * 8]);
                s[ni] = MFMA(qf[kk], kf, s[ni]);
            }
        }
        // p = exp(s * mask_row); accumulate unnormalized row sums; P -> LDS (bf16)
        #pragma unroll
        for (int ni = 0; ni < 2; ++ni) {
            #pragma unroll
            for (int r = 0; r < 4; ++r) {
                float p = __expf(s[ni][r] * mv[r]);
                rowsum[r] += p;
                *reinterpret_cast<unsigned short*>(P + (lg * 4 + r) * 80 + (ni * 16 + lr) * 2) = bf16_rne(p);
            }
        }
        // A-fragment of P: row = lr, kv chunk = 8*lg (per-wave LDS is in-order; no barrier)
        s16x8 pa = *reinterpret_cast<const s16x8*>(P + lr * 80 + lg * 16);
        // O += P V  using vT (contiguous 16B B-frag reads)
        #pragma unroll
        for (int ni = 0; ni < 8; ++ni) {
            s16x8 vf = *reinterpret_cast<const s16x8*>(
                &vbase[(size_t)(ni * 16 + lr) * L_ + kv0 + lg * 8]);
            acc_o[ni] = MFMA(pa, vf, acc_o[ni]);
        }
    }

    // finalize: reduce row sums across the 16 lanes holding each row's columns
    float inv[4];
    #pragma unroll
    for (int r = 0; r < 4; ++r) {
        float v = rowsum[r];
        v += __shfl_xor(v, 1);
        v += __shfl_xor(v, 2);
        v += __shfl_xor(v, 4);
        v += __shfl_xor(v, 8);
        inv[r] = 1.0f / v;
    }
    #pragma unroll
    for (int ni = 0; ni < 8; ++ni)
        #pragma unroll
        for (int r = 0; r < 4; ++r)
            out[((size_t)(b * L_ + q0 + lg * 4 + r)) * DIM_ + h * DH_ + ni * 16 + lr]
                = acc_o[ni][r] * inv[r];
}

extern "C" void kernel_launch(void* const* d_in, const int* in_sizes, int n_in,
                              void* d_out, int out_size, void* d_ws, size_t ws_size,
                              hipStream_t stream) {
    const float* query = (const float*)d_in[0];
    const float* value = (const float*)d_in[1];
    const float* mask  = (const float*)d_in[2];
    const float* Wq    = (const float*)d_in[3];
    const float* Wk    = (const float*)d_in[4];
    const float* Wv    = (const float*)d_in[5];
    float* out = (float*)d_out;

    const size_t elems = (size_t)B_ * H_ * L_ * DH_;  // 8388608 per tensor
    unsigned short* q_ws  = (unsigned short*)d_ws;
    unsigned short* k_ws  = q_ws + elems;
    unsigned short* vT_ws = k_ws + elems;

    dim3 gg(32, 16, 1);
    dim3 blk(256, 1, 1);
    proj_gemm<0><<<gg, blk, 0, stream>>>(query, Wq, q_ws);
    proj_gemm<1><<<gg, blk, 0, stream>>>(value, Wk, k_ws);
    proj_gemm<2><<<gg, blk, 0, stream>>>(value, Wv, vT_ws);

    attn_fused<<<dim3(B_ * H_ * (L_ / 64), 1, 1), blk, 0, stream>>>(q_ws, k_ws, vT_ws, mask, out);
}

// Round 2
// 309.940 us; speedup vs baseline: 2.1412x; 2.1412x over previous
//
#include <hip/hip_runtime.h>
#include <hip/hip_bf16.h>
#include <stdint.h>

#define DIM_ 2048
#define L_   2048
#define B_   2
#define H_   16
#define DH_  128

typedef __attribute__((ext_vector_type(4))) float fp32x4;
typedef __attribute__((ext_vector_type(8))) short s16x8;

__device__ __forceinline__ unsigned short bf16_rne(float f) {
    unsigned u = __builtin_bit_cast(unsigned, f);
    u += 0x7fffu + ((u >> 16) & 1u);
    return (unsigned short)(u >> 16);
}

__device__ __forceinline__ fp32x4 MFMA(s16x8 a, s16x8 b, fp32x4 c) {
    return __builtin_amdgcn_mfma_f32_16x16x32_bf16(a, b, c, 0, 0, 0);
}

__device__ __forceinline__ void gld16(const void* g, void* l) {
    auto gp = reinterpret_cast<const uint32_t __attribute__((address_space(1)))*>(
        reinterpret_cast<uintptr_t>(g));
    auto lp = reinterpret_cast<uint32_t __attribute__((address_space(3)))*>(
        reinterpret_cast<uintptr_t>(l));
    __builtin_amdgcn_global_load_lds(gp, lp, 16, 0, 0);
}

// ---------------------------------------------------------------------------
// Fragment-linear layouts (elements, within one bh):
//   K: koff(l,d) = ((l>>4)*4 + (d>>5))*512 + ((l&15) + (((d>>3)&3)<<4))*8 + (d&7)
//      -> one 64-kv tile = 16KB contiguous; B-frag = lane*16B.
//   V: voff(l,d) = ((l>>5)*8 + (d>>4))*512 + ((d&15) + (((l>>3)&3)<<4))*8 + (l&7)
//      -> one 64-kv tile = 16KB contiguous; B-frag = lane*16B.
// ---------------------------------------------------------------------------

// C[m][n] = sum_k X[m][k] * W[n][k]  (torch Linear x @ W.T)
// MODE 0: q[bh][l][d] scaled 1/sqrt(DH); MODE 1: K fragment-linear; MODE 2: V fragment-linear
template <int MODE>
__global__ void __launch_bounds__(256)
proj_gemm(const float* __restrict__ X, const float* __restrict__ W,
          unsigned short* __restrict__ out)
{
    __shared__ __align__(16) char As[128 * 128];
    __shared__ __align__(16) char Bs[128 * 128];

    const int tid  = threadIdx.x;
    const int lane = tid & 63;
    const int wid  = tid >> 6;
    const int wm   = (wid >> 1) << 6;
    const int wn   = (wid & 1) << 6;
    const int bm   = blockIdx.x << 7;
    const int bn   = blockIdx.y << 7;
    const int lr   = lane & 15;
    const int lg   = lane >> 4;

    fp32x4 acc[4][4] = {};

    for (int k0 = 0; k0 < DIM_; k0 += 64) {
        #pragma unroll
        for (int i = 0; i < 8; ++i) {
            int u   = i * 256 + tid;
            int row = u >> 4;
            int c4  = (u & 15) << 2;
            const float4 av = *reinterpret_cast<const float4*>(&X[(size_t)(bm + row) * DIM_ + k0 + c4]);
            const float4 wv = *reinterpret_cast<const float4*>(&W[(size_t)(bn + row) * DIM_ + k0 + c4]);
            int addr = (row * 128 + (c4 << 1)) ^ ((row & 7) << 4);
            ushort4 ap, wp;
            ap.x = bf16_rne(av.x); ap.y = bf16_rne(av.y); ap.z = bf16_rne(av.z); ap.w = bf16_rne(av.w);
            wp.x = bf16_rne(wv.x); wp.y = bf16_rne(wv.y); wp.z = bf16_rne(wv.z); wp.w = bf16_rne(wv.w);
            *reinterpret_cast<ushort4*>(As + addr) = ap;
            *reinterpret_cast<ushort4*>(Bs + addr) = wp;
        }
        __syncthreads();

        #pragma unroll
        for (int kk = 0; kk < 2; ++kk) {
            s16x8 af[4], bf[4];
            #pragma unroll
            for (int mi = 0; mi < 4; ++mi) {
                int row = wm + mi * 16 + lr;
                af[mi] = *reinterpret_cast<const s16x8*>(As + ((row * 128 + kk * 64 + lg * 16) ^ ((row & 7) << 4)));
            }
            #pragma unroll
            for (int ni = 0; ni < 4; ++ni) {
                int row = wn + ni * 16 + lr;
                bf[ni] = *reinterpret_cast<const s16x8*>(Bs + ((row * 128 + kk * 64 + lg * 16) ^ ((row & 7) << 4)));
            }
            #pragma unroll
            for (int mi = 0; mi < 4; ++mi)
                #pragma unroll
                for (int ni = 0; ni < 4; ++ni)
                    acc[mi][ni] = MFMA(af[mi], bf[ni], acc[mi][ni]);
        }
        __syncthreads();
    }

    const int h  = bn >> 7;
    const int bb = bm >> 11;
    const size_t bh_base = (size_t)(bb * H_ + h) * (L_ * DH_);

    if (MODE == 2) {
        // V fragment-linear; 4 consecutive l pack into ushort4 (j = l&7 consecutive)
        #pragma unroll
        for (int mi = 0; mi < 4; ++mi) {
            int l0 = (bm + wm + mi * 16 + lg * 4) & (L_ - 1);
            #pragma unroll
            for (int ni = 0; ni < 4; ++ni) {
                int d = wn + ni * 16 + lr;
                size_t off = bh_base
                    + (size_t)(((l0 >> 5) * 8 + (d >> 4)) * 512
                    + ((d & 15) + (((l0 >> 3) & 3) << 4)) * 8 + (l0 & 7));
                ushort4 pk;
                pk.x = bf16_rne(acc[mi][ni][0]);
                pk.y = bf16_rne(acc[mi][ni][1]);
                pk.z = bf16_rne(acc[mi][ni][2]);
                pk.w = bf16_rne(acc[mi][ni][3]);
                *reinterpret_cast<ushort4*>(&out[off]) = pk;
            }
        }
    } else if (MODE == 1) {
        // K fragment-linear, scalar u16 stores
        #pragma unroll
        for (int mi = 0; mi < 4; ++mi)
            #pragma unroll
            for (int r = 0; r < 4; ++r) {
                int l = (bm + wm + mi * 16 + lg * 4 + r) & (L_ - 1);
                #pragma unroll
                for (int ni = 0; ni < 4; ++ni) {
                    int d = wn + ni * 16 + lr;
                    size_t off = bh_base
                        + (size_t)(((l >> 4) * 4 + (d >> 5)) * 512
                        + ((l & 15) + (((d >> 3) & 3) << 4)) * 8 + (d & 7));
                    out[off] = bf16_rne(acc[mi][ni][r]);
                }
            }
    } else {
        const float scale = 0.08838834764831845f;  // 1/sqrt(128)
        #pragma unroll
        for (int mi = 0; mi < 4; ++mi)
            #pragma unroll
            for (int r = 0; r < 4; ++r) {
                int l = (bm + wm + mi * 16 + lg * 4 + r) & (L_ - 1);
                #pragma unroll
                for (int ni = 0; ni < 4; ++ni) {
                    int d = wn + ni * 16 + lr;
                    out[bh_base + (size_t)l * DH_ + d] = bf16_rne(acc[mi][ni][r] * scale);
                }
            }
    }
}

// ---------------------------------------------------------------------------
// Attention: 4 waves x 32 q-rows = 128 q/block; KVBLK=64; K LDS double-buffered
// via global_load_lds (2-phase); V fragments direct from global (coalesced,
// L2-resident); P roundtrip through XOR-swizzled per-wave LDS.
// ---------------------------------------------------------------------------
__global__ void __launch_bounds__(256, 2)
attn_fused2(const unsigned short* __restrict__ qw, const unsigned short* __restrict__ kfr,
            const unsigned short* __restrict__ vfr, const float* __restrict__ mask,
            float* __restrict__ out)
{
    __shared__ __align__(16) char Ks[2][16384];
    __shared__ __align__(16) char Pl[4][32 * 144];

    const int tid  = threadIdx.x;
    const int lane = tid & 63;
    const int wid  = tid >> 6;
    const int lr   = lane & 15;
    const int lg   = lane >> 4;

    // XCD swizzle: all 16 q-tiles of a bh land on one XCD (grid 512, 8 XCDs)
    const int p  = (blockIdx.x & 7) * 64 + (blockIdx.x >> 3);
    const int bh = p >> 4;
    const int qt = p & 15;
    const int b  = bh >> 4;
    const int h  = bh & 15;
    const int q0 = qt * 128 + wid * 32;

    const unsigned short* qbase = qw  + (size_t)bh * (L_ * DH_);
    const unsigned short* kbase = kfr + (size_t)bh * (L_ * DH_);
    const unsigned short* vbase = vfr + (size_t)bh * (L_ * DH_);

    // Q fragments: 2 q-subtiles x 4 k-chunks, held all kernel
    s16x8 qf[2][4];
    #pragma unroll
    for (int qs = 0; qs < 2; ++qs)
        #pragma unroll
        for (int kc = 0; kc < 4; ++kc)
            qf[qs][kc] = *reinterpret_cast<const s16x8*>(
                &qbase[(size_t)(q0 + qs * 16 + lr) * DH_ + kc * 32 + lg * 8]);

    float mv[2][4];
    #pragma unroll
    for (int qs = 0; qs < 2; ++qs)
        #pragma unroll
        for (int r = 0; r < 4; ++r)
            mv[qs][r] = mask[b * L_ + q0 + qs * 16 + lg * 4 + r];

    fp32x4 acc[2][8] = {};
    float rs[2][4] = {};

    char* P = &Pl[wid][0];

    // stage K tile t into LDS buffer buf (16KB, 4 x 256-thread x 16B)
    auto STAGE = [&](int buf, int t) {
        const unsigned short* g = kbase + (size_t)t * 8192;
        #pragma unroll
        for (int c = 0; c < 4; ++c)
            gld16(g + c * 2048 + tid * 8, &Ks[buf][c * 4096 + wid * 1024]);
    };

    STAGE(0, 0);
    __syncthreads();

    for (int t = 0; t < L_ / 64; ++t) {
        const int buf = t & 1;
        if (t + 1 < L_ / 64) STAGE(buf ^ 1, t + 1);

        // V fragments kvc=0 (8 x 1KB coalesced global loads, L2-served)
        s16x8 vv0[8], vv1[8];
        #pragma unroll
        for (int ds = 0; ds < 8; ++ds)
            vv0[ds] = *reinterpret_cast<const s16x8*>(
                &vbase[(size_t)t * 8192 + (0 * 8 + ds) * 512 + lane * 8]);

        // QK^T: 16 LDS B-frag reads, 32 MFMA
        fp32x4 s2[2][4] = {};
        #pragma unroll
        for (int kvs = 0; kvs < 4; ++kvs)
            #pragma unroll
            for (int kc = 0; kc < 4; ++kc) {
                s16x8 kf = *reinterpret_cast<const s16x8*>(
                    Ks[buf] + (kvs * 4 + kc) * 1024 + lane * 16);
                s2[0][kvs] = MFMA(qf[0][kc], kf, s2[0][kvs]);
                s2[1][kvs] = MFMA(qf[1][kc], kf, s2[1][kvs]);
            }

        // p = exp(s*mask); P -> swizzled LDS (granule ^= (row>>2)&3)
        #pragma unroll
        for (int qs = 0; qs < 2; ++qs)
            #pragma unroll
            for (int kvs = 0; kvs < 4; ++kvs)
                #pragma unroll
                for (int r = 0; r < 4; ++r) {
                    float pv = __expf(s2[qs][kvs][r] * mv[qs][r]);
                    rs[qs][r] += pv;
                    int row  = qs * 16 + lg * 4 + r;
                    int col2 = (kvs * 16 + lr) * 2;
                    int addr = row * 144 + (((col2 & ~15) ^ (((row >> 2) & 3) << 4)) | (col2 & 15));
                    *reinterpret_cast<unsigned short*>(P + addr) = bf16_rne(pv);
                }

        // V fragments kvc=1
        #pragma unroll
        for (int ds = 0; ds < 8; ++ds)
            vv1[ds] = *reinterpret_cast<const s16x8*>(
                &vbase[(size_t)t * 8192 + (1 * 8 + ds) * 512 + lane * 8]);

        // P A-fragments (swizzled reads) + PV
        #pragma unroll
        for (int qs = 0; qs < 2; ++qs) {
            int row = qs * 16 + lr;
            int xr  = ((row >> 2) & 3) << 4;
            s16x8 pa0 = *reinterpret_cast<const s16x8*>(P + row * 144 + ((0 * 64 + lg * 16) ^ xr));
            s16x8 pa1 = *reinterpret_cast<const s16x8*>(P + row * 144 + ((1 * 64 + lg * 16) ^ xr));
            #pragma unroll
            for (int ds = 0; ds < 8; ++ds) {
                acc[qs][ds] = MFMA(pa0, vv0[ds], acc[qs][ds]);
                acc[qs][ds] = MFMA(pa1, vv1[ds], acc[qs][ds]);
            }
        }

        __syncthreads();  // drains vmcnt (staging t+1 complete) + protects K buffers
    }

    // normalize + write out
    #pragma unroll
    for (int qs = 0; qs < 2; ++qs) {
        float inv[4];
        #pragma unroll
        for (int r = 0; r < 4; ++r) {
            float v = rs[qs][r];
            v += __shfl_xor(v, 1);
            v += __shfl_xor(v, 2);
            v += __shfl_xor(v, 4);
            v += __shfl_xor(v, 8);
            inv[r] = 1.0f / v;
        }
        #pragma unroll
        for (int ds = 0; ds < 8; ++ds)
            #pragma unroll
            for (int r = 0; r < 4; ++r)
                out[((size_t)(b * L_ + q0 + qs * 16 + lg * 4 + r)) * DIM_ + h * DH_ + ds * 16 + lr]
                    = acc[qs][ds][r] * inv[r];
    }
}

extern "C" void kernel_launch(void* const* d_in, const int* in_sizes, int n_in,
                              void* d_out, int out_size, void* d_ws, size_t ws_size,
                              hipStream_t stream) {
    const float* query = (const float*)d_in[0];
    const float* value = (const float*)d_in[1];
    const float* mask  = (const float*)d_in[2];
    const float* Wq    = (const float*)d_in[3];
    const float* Wk    = (const float*)d_in[4];
    const float* Wv    = (const float*)d_in[5];
    float* out = (float*)d_out;

    const size_t elems = (size_t)B_ * H_ * L_ * DH_;
    unsigned short* q_ws = (unsigned short*)d_ws;
    unsigned short* k_ws = q_ws + elems;
    unsigned short* v_ws = k_ws + elems;

    dim3 gg(32, 16, 1);
    dim3 blk(256, 1, 1);
    proj_gemm<0><<<gg, blk, 0, stream>>>(query, Wq, q_ws);
    proj_gemm<1><<<gg, blk, 0, stream>>>(value, Wk, k_ws);
    proj_gemm<2><<<gg, blk, 0, stream>>>(value, Wv, v_ws);

    attn_fused2<<<dim3(512, 1, 1), blk, 0, stream>>>(q_ws, k_ws, v_ws, mask, out);
}

// Round 3
// 262.369 us; speedup vs baseline: 2.5294x; 1.1813x over previous
//
#include <hip/hip_runtime.h>
#include <hip/hip_bf16.h>
#include <stdint.h>

#define DIM_ 2048
#define L_   2048
#define B_   2
#define H_   16
#define DH_  128

typedef __attribute__((ext_vector_type(4))) float fp32x4;
typedef __attribute__((ext_vector_type(8))) short s16x8;

__device__ __forceinline__ unsigned short bf16_rne(float f) {
    unsigned u = __builtin_bit_cast(unsigned, f);
    u += 0x7fffu + ((u >> 16) & 1u);
    return (unsigned short)(u >> 16);
}

__device__ __forceinline__ fp32x4 MFMA(s16x8 a, s16x8 b, fp32x4 c) {
    return __builtin_amdgcn_mfma_f32_16x16x32_bf16(a, b, c, 0, 0, 0);
}

__device__ __forceinline__ void gld16(const void* g, void* l) {
    auto gp = reinterpret_cast<const uint32_t __attribute__((address_space(1)))*>(
        reinterpret_cast<uintptr_t>(g));
    auto lp = reinterpret_cast<uint32_t __attribute__((address_space(3)))*>(
        reinterpret_cast<uintptr_t>(l));
    __builtin_amdgcn_global_load_lds(gp, lp, 16, 0, 0);
}

// ---------------------------------------------------------------------------
// f32 -> bf16 convert (optionally scaled), vectorized float4 -> ushort4
// ---------------------------------------------------------------------------
__global__ void __launch_bounds__(256)
cvt_bf16(const float* __restrict__ src, unsigned short* __restrict__ dst,
         int n4, float scale)
{
    int i = blockIdx.x * blockDim.x + threadIdx.x;
    const int stride = gridDim.x * blockDim.x;
    for (; i < n4; i += stride) {
        float4 v = reinterpret_cast<const float4*>(src)[i];
        ushort4 o;
        o.x = bf16_rne(v.x * scale);
        o.y = bf16_rne(v.y * scale);
        o.z = bf16_rne(v.z * scale);
        o.w = bf16_rne(v.w * scale);
        reinterpret_cast<ushort4*>(dst)[i] = o;
    }
}

// ---------------------------------------------------------------------------
// Attention workspace fragment-linear layouts (elements, within one bh):
//   K: koff(l,d) = ((l>>4)*4 + (d>>5))*512 + ((l&15) + (((d>>3)&3)<<4))*8 + (d&7)
//   V: voff(l,d) = ((l>>5)*8 + (d>>4))*512 + ((d&15) + (((l>>3)&3)<<4))*8 + (l&7)
// ---------------------------------------------------------------------------

// ---------------------------------------------------------------------------
// bf16 GEMM, m97 structure: 128x128 tile, BK=64, global_load_lds width-16,
// double-buffered LDS, 1 barrier per K-step.
// C[m][n] = sum_k X[m][k] * W[n][k]
// MODE 0: q[bh][l][d] (scale pre-folded into Wq); MODE 1: K frag-linear;
// MODE 2: V frag-linear.
// ---------------------------------------------------------------------------
template <int MODE>
__global__ void __launch_bounds__(256)
proj_gemm_bf(const unsigned short* __restrict__ Xb, const unsigned short* __restrict__ Wb,
             unsigned short* __restrict__ out)
{
    __shared__ __align__(16) char As[2][16384];
    __shared__ __align__(16) char Bs[2][16384];

    const int tid  = threadIdx.x;
    const int lane = tid & 63;
    const int wid  = tid >> 6;
    const int wm   = (wid >> 1) << 6;
    const int wn   = (wid & 1) << 6;
    const int bm   = blockIdx.x << 7;
    const int bn   = blockIdx.y << 7;
    const int lr   = lane & 15;
    const int lg   = lane >> 4;

    fp32x4 acc[4][4] = {};

    // staging geometry: per wave-round r, 8 rows; row = r*32 + wid*8 + (lane>>3),
    // byte col = (lane&7)*16; LDS linear dest = r*4096 + wid*1024 (+ lane*16 by HW)
    const int srow = wid * 8 + (lane >> 3);
    const int scol = (lane & 7) * 8;  // elements

    auto STAGE = [&](int buf, int k0) {
        const unsigned short* ga = Xb + (size_t)(bm + srow) * DIM_ + k0 + scol;
        const unsigned short* gb = Wb + (size_t)(bn + srow) * DIM_ + k0 + scol;
        #pragma unroll
        for (int r = 0; r < 4; ++r) {
            gld16(ga + (size_t)r * 32 * DIM_, &As[buf][r * 4096 + wid * 1024]);
            gld16(gb + (size_t)r * 32 * DIM_, &Bs[buf][r * 4096 + wid * 1024]);
        }
    };

    STAGE(0, 0);
    __syncthreads();

    for (int t = 0; t < DIM_ / 64; ++t) {
        const int buf = t & 1;
        if (t + 1 < DIM_ / 64) STAGE(buf ^ 1, (t + 1) * 64);

        #pragma unroll
        for (int kk = 0; kk < 2; ++kk) {
            s16x8 af[4], bfr[4];
            #pragma unroll
            for (int mi = 0; mi < 4; ++mi)
                af[mi] = *reinterpret_cast<const s16x8*>(
                    As[buf] + (wm + mi * 16 + lr) * 128 + kk * 64 + lg * 16);
            #pragma unroll
            for (int ni = 0; ni < 4; ++ni)
                bfr[ni] = *reinterpret_cast<const s16x8*>(
                    Bs[buf] + (wn + ni * 16 + lr) * 128 + kk * 64 + lg * 16);
            #pragma unroll
            for (int mi = 0; mi < 4; ++mi)
                #pragma unroll
                for (int ni = 0; ni < 4; ++ni)
                    acc[mi][ni] = MFMA(af[mi], bfr[ni], acc[mi][ni]);
        }
        __syncthreads();  // drains vmcnt (stage t+1 done) + protects buffers
    }

    const int h  = bn >> 7;
    const int bb = bm >> 11;
    const size_t bh_base = (size_t)(bb * H_ + h) * (L_ * DH_);

    if (MODE == 2) {
        #pragma unroll
        for (int mi = 0; mi < 4; ++mi) {
            int l0 = (bm + wm + mi * 16 + lg * 4) & (L_ - 1);
            #pragma unroll
            for (int ni = 0; ni < 4; ++ni) {
                int d = wn + ni * 16 + lr;
                size_t off = bh_base
                    + (size_t)(((l0 >> 5) * 8 + (d >> 4)) * 512
                    + ((d & 15) + (((l0 >> 3) & 3) << 4)) * 8 + (l0 & 7));
                ushort4 pk;
                pk.x = bf16_rne(acc[mi][ni][0]);
                pk.y = bf16_rne(acc[mi][ni][1]);
                pk.z = bf16_rne(acc[mi][ni][2]);
                pk.w = bf16_rne(acc[mi][ni][3]);
                *reinterpret_cast<ushort4*>(&out[off]) = pk;
            }
        }
    } else if (MODE == 1) {
        #pragma unroll
        for (int mi = 0; mi < 4; ++mi)
            #pragma unroll
            for (int r = 0; r < 4; ++r) {
                int l = (bm + wm + mi * 16 + lg * 4 + r) & (L_ - 1);
                #pragma unroll
                for (int ni = 0; ni < 4; ++ni) {
                    int d = wn + ni * 16 + lr;
                    size_t off = bh_base
                        + (size_t)(((l >> 4) * 4 + (d >> 5)) * 512
                        + ((l & 15) + (((d >> 3) & 3) << 4)) * 8 + (d & 7));
                    out[off] = bf16_rne(acc[mi][ni][r]);
                }
            }
    } else {
        #pragma unroll
        for (int mi = 0; mi < 4; ++mi)
            #pragma unroll
            for (int r = 0; r < 4; ++r) {
                int l = (bm + wm + mi * 16 + lg * 4 + r) & (L_ - 1);
                #pragma unroll
                for (int ni = 0; ni < 4; ++ni) {
                    int d = wn + ni * 16 + lr;
                    out[bh_base + (size_t)l * DH_ + d] = bf16_rne(acc[mi][ni][r]);
                }
            }
    }
}

// ---------------------------------------------------------------------------
// Fallback f32-input GEMM (round-2 version) for small ws_size.
// ---------------------------------------------------------------------------
template <int MODE>
__global__ void __launch_bounds__(256)
proj_gemm(const float* __restrict__ X, const float* __restrict__ W,
          unsigned short* __restrict__ out)
{
    __shared__ __align__(16) char As[128 * 128];
    __shared__ __align__(16) char Bs[128 * 128];

    const int tid  = threadIdx.x;
    const int lane = tid & 63;
    const int wid  = tid >> 6;
    const int wm   = (wid >> 1) << 6;
    const int wn   = (wid & 1) << 6;
    const int bm   = blockIdx.x << 7;
    const int bn   = blockIdx.y << 7;
    const int lr   = lane & 15;
    const int lg   = lane >> 4;

    fp32x4 acc[4][4] = {};

    for (int k0 = 0; k0 < DIM_; k0 += 64) {
        #pragma unroll
        for (int i = 0; i < 8; ++i) {
            int u   = i * 256 + tid;
            int row = u >> 4;
            int c4  = (u & 15) << 2;
            const float4 av = *reinterpret_cast<const float4*>(&X[(size_t)(bm + row) * DIM_ + k0 + c4]);
            const float4 wv = *reinterpret_cast<const float4*>(&W[(size_t)(bn + row) * DIM_ + k0 + c4]);
            int addr = (row * 128 + (c4 << 1)) ^ ((row & 7) << 4);
            ushort4 ap, wp;
            ap.x = bf16_rne(av.x); ap.y = bf16_rne(av.y); ap.z = bf16_rne(av.z); ap.w = bf16_rne(av.w);
            wp.x = bf16_rne(wv.x); wp.y = bf16_rne(wv.y); wp.z = bf16_rne(wv.z); wp.w = bf16_rne(wv.w);
            *reinterpret_cast<ushort4*>(As + addr) = ap;
            *reinterpret_cast<ushort4*>(Bs + addr) = wp;
        }
        __syncthreads();

        #pragma unroll
        for (int kk = 0; kk < 2; ++kk) {
            s16x8 af[4], bfr[4];
            #pragma unroll
            for (int mi = 0; mi < 4; ++mi) {
                int row = wm + mi * 16 + lr;
                af[mi] = *reinterpret_cast<const s16x8*>(As + ((row * 128 + kk * 64 + lg * 16) ^ ((row & 7) << 4)));
            }
            #pragma unroll
            for (int ni = 0; ni < 4; ++ni) {
                int row = wn + ni * 16 + lr;
                bfr[ni] = *reinterpret_cast<const s16x8*>(Bs + ((row * 128 + kk * 64 + lg * 16) ^ ((row & 7) << 4)));
            }
            #pragma unroll
            for (int mi = 0; mi < 4; ++mi)
                #pragma unroll
                for (int ni = 0; ni < 4; ++ni)
                    acc[mi][ni] = MFMA(af[mi], bfr[ni], acc[mi][ni]);
        }
        __syncthreads();
    }

    const int h  = bn >> 7;
    const int bb = bm >> 11;
    const size_t bh_base = (size_t)(bb * H_ + h) * (L_ * DH_);

    if (MODE == 2) {
        #pragma unroll
        for (int mi = 0; mi < 4; ++mi) {
            int l0 = (bm + wm + mi * 16 + lg * 4) & (L_ - 1);
            #pragma unroll
            for (int ni = 0; ni < 4; ++ni) {
                int d = wn + ni * 16 + lr;
                size_t off = bh_base
                    + (size_t)(((l0 >> 5) * 8 + (d >> 4)) * 512
                    + ((d & 15) + (((l0 >> 3) & 3) << 4)) * 8 + (l0 & 7));
                ushort4 pk;
                pk.x = bf16_rne(acc[mi][ni][0]);
                pk.y = bf16_rne(acc[mi][ni][1]);
                pk.z = bf16_rne(acc[mi][ni][2]);
                pk.w = bf16_rne(acc[mi][ni][3]);
                *reinterpret_cast<ushort4*>(&out[off]) = pk;
            }
        }
    } else if (MODE == 1) {
        #pragma unroll
        for (int mi = 0; mi < 4; ++mi)
            #pragma unroll
            for (int r = 0; r < 4; ++r) {
                int l = (bm + wm + mi * 16 + lg * 4 + r) & (L_ - 1);
                #pragma unroll
                for (int ni = 0; ni < 4; ++ni) {
                    int d = wn + ni * 16 + lr;
                    size_t off = bh_base
                        + (size_t)(((l >> 4) * 4 + (d >> 5)) * 512
                        + ((l & 15) + (((d >> 3) & 3) << 4)) * 8 + (d & 7));
                    out[off] = bf16_rne(acc[mi][ni][r]);
                }
            }
    } else {
        const float scale = 0.08838834764831845f;
        #pragma unroll
        for (int mi = 0; mi < 4; ++mi)
            #pragma unroll
            for (int r = 0; r < 4; ++r) {
                int l = (bm + wm + mi * 16 + lg * 4 + r) & (L_ - 1);
                #pragma unroll
                for (int ni = 0; ni < 4; ++ni) {
                    int d = wn + ni * 16 + lr;
                    out[bh_base + (size_t)l * DH_ + d] = bf16_rne(acc[mi][ni][r] * scale);
                }
            }
    }
}

// ---------------------------------------------------------------------------
// Attention: 4 waves x 32 q-rows = 128 q/block; KVBLK=64; K LDS double-buffered
// via global_load_lds; V fragments direct from global; swizzled P roundtrip.
// ---------------------------------------------------------------------------
__global__ void __launch_bounds__(256, 2)
attn_fused2(const unsigned short* __restrict__ qw, const unsigned short* __restrict__ kfr,
            const unsigned short* __restrict__ vfr, const float* __restrict__ mask,
            float* __restrict__ out)
{
    __shared__ __align__(16) char Ks[2][16384];
    __shared__ __align__(16) char Pl[4][32 * 144];

    const int tid  = threadIdx.x;
    const int lane = tid & 63;
    const int wid  = tid >> 6;
    const int lr   = lane & 15;
    const int lg   = lane >> 4;

    const int p  = (blockIdx.x & 7) * 64 + (blockIdx.x >> 3);
    const int bh = p >> 4;
    const int qt = p & 15;
    const int b  = bh >> 4;
    const int h  = bh & 15;
    const int q0 = qt * 128 + wid * 32;

    const unsigned short* qbase = qw  + (size_t)bh * (L_ * DH_);
    const unsigned short* kbase = kfr + (size_t)bh * (L_ * DH_);
    const unsigned short* vbase = vfr + (size_t)bh * (L_ * DH_);

    s16x8 qf[2][4];
    #pragma unroll
    for (int qs = 0; qs < 2; ++qs)
        #pragma unroll
        for (int kc = 0; kc < 4; ++kc)
            qf[qs][kc] = *reinterpret_cast<const s16x8*>(
                &qbase[(size_t)(q0 + qs * 16 + lr) * DH_ + kc * 32 + lg * 8]);

    float mv[2][4];
    #pragma unroll
    for (int qs = 0; qs < 2; ++qs)
        #pragma unroll
        for (int r = 0; r < 4; ++r)
            mv[qs][r] = mask[b * L_ + q0 + qs * 16 + lg * 4 + r];

    fp32x4 acc[2][8] = {};
    float rs[2][4] = {};

    char* P = &Pl[wid][0];

    auto STAGE = [&](int buf, int t) {
        const unsigned short* g = kbase + (size_t)t * 8192;
        #pragma unroll
        for (int c = 0; c < 4; ++c)
            gld16(g + c * 2048 + tid * 8, &Ks[buf][c * 4096 + wid * 1024]);
    };

    STAGE(0, 0);
    __syncthreads();

    for (int t = 0; t < L_ / 64; ++t) {
        const int buf = t & 1;
        if (t + 1 < L_ / 64) STAGE(buf ^ 1, t + 1);

        s16x8 vv0[8], vv1[8];
        #pragma unroll
        for (int ds = 0; ds < 8; ++ds)
            vv0[ds] = *reinterpret_cast<const s16x8*>(
                &vbase[(size_t)t * 8192 + (0 * 8 + ds) * 512 + lane * 8]);

        fp32x4 s2[2][4] = {};
        #pragma unroll
        for (int kvs = 0; kvs < 4; ++kvs)
            #pragma unroll
            for (int kc = 0; kc < 4; ++kc) {
                s16x8 kf = *reinterpret_cast<const s16x8*>(
                    Ks[buf] + (kvs * 4 + kc) * 1024 + lane * 16);
                s2[0][kvs] = MFMA(qf[0][kc], kf, s2[0][kvs]);
                s2[1][kvs] = MFMA(qf[1][kc], kf, s2[1][kvs]);
            }

        #pragma unroll
        for (int qs = 0; qs < 2; ++qs)
            #pragma unroll
            for (int kvs = 0; kvs < 4; ++kvs)
                #pragma unroll
                for (int r = 0; r < 4; ++r) {
                    float pv = __expf(s2[qs][kvs][r] * mv[qs][r]);
                    rs[qs][r] += pv;
                    int row  = qs * 16 + lg * 4 + r;
                    int col2 = (kvs * 16 + lr) * 2;
                    int addr = row * 144 + (((col2 & ~15) ^ (((row >> 2) & 3) << 4)) | (col2 & 15));
                    *reinterpret_cast<unsigned short*>(P + addr) = bf16_rne(pv);
                }

        #pragma unroll
        for (int ds = 0; ds < 8; ++ds)
            vv1[ds] = *reinterpret_cast<const s16x8*>(
                &vbase[(size_t)t * 8192 + (1 * 8 + ds) * 512 + lane * 8]);

        #pragma unroll
        for (int qs = 0; qs < 2; ++qs) {
            int row = qs * 16 + lr;
            int xr  = ((row >> 2) & 3) << 4;
            s16x8 pa0 = *reinterpret_cast<const s16x8*>(P + row * 144 + ((0 * 64 + lg * 16) ^ xr));
            s16x8 pa1 = *reinterpret_cast<const s16x8*>(P + row * 144 + ((1 * 64 + lg * 16) ^ xr));
            #pragma unroll
            for (int ds = 0; ds < 8; ++ds) {
                acc[qs][ds] = MFMA(pa0, vv0[ds], acc[qs][ds]);
                acc[qs][ds] = MFMA(pa1, vv1[ds], acc[qs][ds]);
            }
        }

        __syncthreads();
    }

    #pragma unroll
    for (int qs = 0; qs < 2; ++qs) {
        float inv[4];
        #pragma unroll
        for (int r = 0; r < 4; ++r) {
            float v = rs[qs][r];
            v += __shfl_xor(v, 1);
            v += __shfl_xor(v, 2);
            v += __shfl_xor(v, 4);
            v += __shfl_xor(v, 8);
            inv[r] = 1.0f / v;
        }
        #pragma unroll
        for (int ds = 0; ds < 8; ++ds)
            #pragma unroll
            for (int r = 0; r < 4; ++r)
                out[((size_t)(b * L_ + q0 + qs * 16 + lg * 4 + r)) * DIM_ + h * DH_ + ds * 16 + lr]
                    = acc[qs][ds][r] * inv[r];
    }
}

extern "C" void kernel_launch(void* const* d_in, const int* in_sizes, int n_in,
                              void* d_out, int out_size, void* d_ws, size_t ws_size,
                              hipStream_t stream) {
    const float* query = (const float*)d_in[0];
    const float* value = (const float*)d_in[1];
    const float* mask  = (const float*)d_in[2];
    const float* Wq    = (const float*)d_in[3];
    const float* Wk    = (const float*)d_in[4];
    const float* Wv    = (const float*)d_in[5];
    float* out = (float*)d_out;

    const size_t elems = (size_t)B_ * H_ * L_ * DH_;  // 8388608
    unsigned short* q_ws = (unsigned short*)d_ws;
    unsigned short* k_ws = q_ws + elems;
    unsigned short* v_ws = k_ws + elems;

    dim3 gg(32, 16, 1);
    dim3 blk(256, 1, 1);

    const size_t need_bf = (3 * elems + elems + elems / 2) * sizeof(unsigned short); // 75.5MB

    if (ws_size >= need_bf) {
        unsigned short* Axb = v_ws + elems;        // 8388608 shorts (X bf16)
        unsigned short* Bxb = Axb + elems;         // 4194304 shorts (W bf16)
        const float kscale = 0.08838834764831845f; // 1/sqrt(128), folded into Wq

        dim3 cg(2048, 1, 1);
        cvt_bf16<<<cg, blk, 0, stream>>>(query, Axb, (int)(elems / 4), 1.0f);
        cvt_bf16<<<cg, blk, 0, stream>>>(Wq, Bxb, (int)(elems / 8), kscale);
        proj_gemm_bf<0><<<gg, blk, 0, stream>>>(Axb, Bxb, q_ws);

        cvt_bf16<<<cg, blk, 0, stream>>>(value, Axb, (int)(elems / 4), 1.0f);
        cvt_bf16<<<cg, blk, 0, stream>>>(Wk, Bxb, (int)(elems / 8), 1.0f);
        proj_gemm_bf<1><<<gg, blk, 0, stream>>>(Axb, Bxb, k_ws);

        cvt_bf16<<<cg, blk, 0, stream>>>(Wv, Bxb, (int)(elems / 8), 1.0f);
        proj_gemm_bf<2><<<gg, blk, 0, stream>>>(Axb, Bxb, v_ws);
    } else {
        proj_gemm<0><<<gg, blk, 0, stream>>>(query, Wq, q_ws);
        proj_gemm<1><<<gg, blk, 0, stream>>>(value, Wk, k_ws);
        proj_gemm<2><<<gg, blk, 0, stream>>>(value, Wv, v_ws);
    }

    attn_fused2<<<dim3(512, 1, 1), blk, 0, stream>>>(q_ws, k_ws, v_ws, mask, out);
}

// Round 4
// 254.938 us; speedup vs baseline: 2.6031x; 1.0291x over previous
//
#include <hip/hip_runtime.h>
#include <hip/hip_bf16.h>
#include <stdint.h>

#define DIM_ 2048
#define L_   2048
#define B_   2
#define H_   16
#define DH_  128

// scale folded into Wq: (1/sqrt(128)) * log2(e)  -> softmax uses exp2
#define QSCALE_ 0.12751743f

typedef __attribute__((ext_vector_type(4))) float fp32x4;
typedef __attribute__((ext_vector_type(8))) short s16x8;

__device__ __forceinline__ unsigned short bf16_rne(float f) {
    unsigned u = __builtin_bit_cast(unsigned, f);
    u += 0x7fffu + ((u >> 16) & 1u);
    return (unsigned short)(u >> 16);
}

__device__ __forceinline__ fp32x4 MFMA(s16x8 a, s16x8 b, fp32x4 c) {
    return __builtin_amdgcn_mfma_f32_16x16x32_bf16(a, b, c, 0, 0, 0);
}

__device__ __forceinline__ void gld16(const void* g, void* l) {
    auto gp = reinterpret_cast<const uint32_t __attribute__((address_space(1)))*>(
        reinterpret_cast<uintptr_t>(g));
    auto lp = reinterpret_cast<uint32_t __attribute__((address_space(3)))*>(
        reinterpret_cast<uintptr_t>(l));
    __builtin_amdgcn_global_load_lds(gp, lp, 16, 0, 0);
}

// ---------------------------------------------------------------------------
// Merged f32->bf16 conversion: query | value | Wq(*QSCALE_) | Wk | Wv in one pass
// ---------------------------------------------------------------------------
__global__ void __launch_bounds__(256)
cvt_all(const float* __restrict__ query, const float* __restrict__ value,
        const float* __restrict__ Wq, const float* __restrict__ Wk,
        const float* __restrict__ Wv,
        unsigned short* __restrict__ qb, unsigned short* __restrict__ vb,
        unsigned short* __restrict__ wqb, unsigned short* __restrict__ wkb,
        unsigned short* __restrict__ wvb)
{
    const int total4 = 7340032;  // (2*8388608 + 3*4194304) / 4
    int i = blockIdx.x * 256 + threadIdx.x;
    const int stride = gridDim.x * 256;
    for (; i < total4; i += stride) {
        const float4* s; ushort4* d; int off; float sc = 1.0f;
        if (i < 2097152)      { s = (const float4*)query; d = (ushort4*)qb;  off = i; }
        else if (i < 4194304) { s = (const float4*)value; d = (ushort4*)vb;  off = i - 2097152; }
        else if (i < 5242880) { s = (const float4*)Wq;    d = (ushort4*)wqb; off = i - 4194304; sc = QSCALE_; }
        else if (i < 6291456) { s = (const float4*)Wk;    d = (ushort4*)wkb; off = i - 5242880; }
        else                  { s = (const float4*)Wv;    d = (ushort4*)wvb; off = i - 6291456; }
        float4 v = s[off];
        ushort4 o;
        o.x = bf16_rne(v.x * sc); o.y = bf16_rne(v.y * sc);
        o.z = bf16_rne(v.z * sc); o.w = bf16_rne(v.w * sc);
        d[off] = o;
    }
}

// ---------------------------------------------------------------------------
// Attention workspace fragment-linear layouts (elements, within one bh):
//   K: koff(l,d) = ((l>>4)*4 + (d>>5))*512 + ((l&15) + (((d>>3)&3)<<4))*8 + (d&7)
//   V: voff(l,d) = ((l>>5)*8 + (d>>4))*512 + ((d&15) + (((l>>3)&3)<<4))*8 + (l&7)
// ---------------------------------------------------------------------------

// ---------------------------------------------------------------------------
// Merged QKV bf16 GEMM, m97 structure: 128x128 tile, BK=64, global_load_lds
// width-16, double-buffered LDS, 1 barrier/K-step.
// only < 0: grid 1536, which = block/512.  only >= 0: grid 512, which = only.
// which 0: q[bh][l][d] (QSCALE_ pre-folded); 1: K frag-linear; 2: V frag-linear
// ---------------------------------------------------------------------------
__global__ void __launch_bounds__(256)
gemm_qkv(const unsigned short* __restrict__ qb, const unsigned short* __restrict__ vb,
         const unsigned short* __restrict__ wqb, const unsigned short* __restrict__ wkb,
         const unsigned short* __restrict__ wvb,
         unsigned short* __restrict__ q_ws, unsigned short* __restrict__ k_ws,
         unsigned short* __restrict__ v_ws, int only)
{
    __shared__ __align__(16) char As[2][16384];
    __shared__ __align__(16) char Bs[2][16384];

    int which, r;
    if (only < 0) {
        int g = (blockIdx.x & 7) * 192 + (blockIdx.x >> 3);  // XCD swizzle, 1536%8==0
        which = g >> 9;
        r = g & 511;
    } else {
        which = only;
        r = (blockIdx.x & 7) * 64 + (blockIdx.x >> 3);       // 512%8==0
    }
    const int bm = ((r >> 4) & 31) << 7;
    const int bn = (r & 15) << 7;

    const unsigned short* Xb = (which == 0) ? qb : vb;
    const unsigned short* Wb = (which == 0) ? wqb : (which == 1) ? wkb : wvb;
    unsigned short* out      = (which == 0) ? q_ws : (which == 1) ? k_ws : v_ws;

    const int tid  = threadIdx.x;
    const int lane = tid & 63;
    const int wid  = tid >> 6;
    const int wm   = (wid >> 1) << 6;
    const int wn   = (wid & 1) << 6;
    const int lr   = lane & 15;
    const int lg   = lane >> 4;

    fp32x4 acc[4][4] = {};

    const int srow = wid * 8 + (lane >> 3);
    const int scol = (lane & 7) * 8;  // elements

    auto STAGE = [&](int buf, int k0) {
        const unsigned short* ga = Xb + (size_t)(bm + srow) * DIM_ + k0 + scol;
        const unsigned short* gb = Wb + (size_t)(bn + srow) * DIM_ + k0 + scol;
        #pragma unroll
        for (int rr = 0; rr < 4; ++rr) {
            gld16(ga + (size_t)rr * 32 * DIM_, &As[buf][rr * 4096 + wid * 1024]);
            gld16(gb + (size_t)rr * 32 * DIM_, &Bs[buf][rr * 4096 + wid * 1024]);
        }
    };

    STAGE(0, 0);
    __syncthreads();

    for (int t = 0; t < DIM_ / 64; ++t) {
        const int buf = t & 1;
        if (t + 1 < DIM_ / 64) STAGE(buf ^ 1, (t + 1) * 64);

        #pragma unroll
        for (int kk = 0; kk < 2; ++kk) {
            s16x8 af[4], bfr[4];
            #pragma unroll
            for (int mi = 0; mi < 4; ++mi)
                af[mi] = *reinterpret_cast<const s16x8*>(
                    As[buf] + (wm + mi * 16 + lr) * 128 + kk * 64 + lg * 16);
            #pragma unroll
            for (int ni = 0; ni < 4; ++ni)
                bfr[ni] = *reinterpret_cast<const s16x8*>(
                    Bs[buf] + (wn + ni * 16 + lr) * 128 + kk * 64 + lg * 16);
            #pragma unroll
            for (int mi = 0; mi < 4; ++mi)
                #pragma unroll
                for (int ni = 0; ni < 4; ++ni)
                    acc[mi][ni] = MFMA(af[mi], bfr[ni], acc[mi][ni]);
        }
        __syncthreads();
    }

    const int h  = bn >> 7;
    const int bb = bm >> 11;
    const size_t bh_base = (size_t)(bb * H_ + h) * (L_ * DH_);

    if (which == 2) {
        #pragma unroll
        for (int mi = 0; mi < 4; ++mi) {
            int l0 = (bm + wm + mi * 16 + lg * 4) & (L_ - 1);
            #pragma unroll
            for (int ni = 0; ni < 4; ++ni) {
                int d = wn + ni * 16 + lr;
                size_t off = bh_base
                    + (size_t)(((l0 >> 5) * 8 + (d >> 4)) * 512
                    + ((d & 15) + (((l0 >> 3) & 3) << 4)) * 8 + (l0 & 7));
                ushort4 pk;
                pk.x = bf16_rne(acc[mi][ni][0]);
                pk.y = bf16_rne(acc[mi][ni][1]);
                pk.z = bf16_rne(acc[mi][ni][2]);
                pk.w = bf16_rne(acc[mi][ni][3]);
                *reinterpret_cast<ushort4*>(&out[off]) = pk;
            }
        }
    } else if (which == 1) {
        #pragma unroll
        for (int mi = 0; mi < 4; ++mi)
            #pragma unroll
            for (int rr = 0; rr < 4; ++rr) {
                int l = (bm + wm + mi * 16 + lg * 4 + rr) & (L_ - 1);
                #pragma unroll
                for (int ni = 0; ni < 4; ++ni) {
                    int d = wn + ni * 16 + lr;
                    size_t off = bh_base
                        + (size_t)(((l >> 4) * 4 + (d >> 5)) * 512
                        + ((l & 15) + (((d >> 3) & 3) << 4)) * 8 + (d & 7));
                    out[off] = bf16_rne(acc[mi][ni][rr]);
                }
            }
    } else {
        #pragma unroll
        for (int mi = 0; mi < 4; ++mi)
            #pragma unroll
            for (int rr = 0; rr < 4; ++rr) {
                int l = (bm + wm + mi * 16 + lg * 4 + rr) & (L_ - 1);
                #pragma unroll
                for (int ni = 0; ni < 4; ++ni) {
                    int d = wn + ni * 16 + lr;
                    out[bh_base + (size_t)l * DH_ + d] = bf16_rne(acc[mi][ni][rr]);
                }
            }
    }
}

// ---------------------------------------------------------------------------
// Fallback f32-input GEMM (for small ws_size).
// ---------------------------------------------------------------------------
template <int MODE>
__global__ void __launch_bounds__(256)
proj_gemm(const float* __restrict__ X, const float* __restrict__ W,
          unsigned short* __restrict__ out)
{
    __shared__ __align__(16) char As[128 * 128];
    __shared__ __align__(16) char Bs[128 * 128];

    const int tid  = threadIdx.x;
    const int lane = tid & 63;
    const int wid  = tid >> 6;
    const int wm   = (wid >> 1) << 6;
    const int wn   = (wid & 1) << 6;
    const int bm   = blockIdx.x << 7;
    const int bn   = blockIdx.y << 7;
    const int lr   = lane & 15;
    const int lg   = lane >> 4;

    fp32x4 acc[4][4] = {};

    for (int k0 = 0; k0 < DIM_; k0 += 64) {
        #pragma unroll
        for (int i = 0; i < 8; ++i) {
            int u   = i * 256 + tid;
            int row = u >> 4;
            int c4  = (u & 15) << 2;
            const float4 av = *reinterpret_cast<const float4*>(&X[(size_t)(bm + row) * DIM_ + k0 + c4]);
            const float4 wv = *reinterpret_cast<const float4*>(&W[(size_t)(bn + row) * DIM_ + k0 + c4]);
            int addr = (row * 128 + (c4 << 1)) ^ ((row & 7) << 4);
            ushort4 ap, wp;
            ap.x = bf16_rne(av.x); ap.y = bf16_rne(av.y); ap.z = bf16_rne(av.z); ap.w = bf16_rne(av.w);
            wp.x = bf16_rne(wv.x); wp.y = bf16_rne(wv.y); wp.z = bf16_rne(wv.z); wp.w = bf16_rne(wv.w);
            *reinterpret_cast<ushort4*>(As + addr) = ap;
            *reinterpret_cast<ushort4*>(Bs + addr) = wp;
        }
        __syncthreads();

        #pragma unroll
        for (int kk = 0; kk < 2; ++kk) {
            s16x8 af[4], bfr[4];
            #pragma unroll
            for (int mi = 0; mi < 4; ++mi) {
                int row = wm + mi * 16 + lr;
                af[mi] = *reinterpret_cast<const s16x8*>(As + ((row * 128 + kk * 64 + lg * 16) ^ ((row & 7) << 4)));
            }
            #pragma unroll
            for (int ni = 0; ni < 4; ++ni) {
                int row = wn + ni * 16 + lr;
                bfr[ni] = *reinterpret_cast<const s16x8*>(Bs + ((row * 128 + kk * 64 + lg * 16) ^ ((row & 7) << 4)));
            }
            #pragma unroll
            for (int mi = 0; mi < 4; ++mi)
                #pragma unroll
                for (int ni = 0; ni < 4; ++ni)
                    acc[mi][ni] = MFMA(af[mi], bfr[ni], acc[mi][ni]);
        }
        __syncthreads();
    }

    const int h  = bn >> 7;
    const int bb = bm >> 11;
    const size_t bh_base = (size_t)(bb * H_ + h) * (L_ * DH_);

    if (MODE == 2) {
        #pragma unroll
        for (int mi = 0; mi < 4; ++mi) {
            int l0 = (bm + wm + mi * 16 + lg * 4) & (L_ - 1);
            #pragma unroll
            for (int ni = 0; ni < 4; ++ni) {
                int d = wn + ni * 16 + lr;
                size_t off = bh_base
                    + (size_t)(((l0 >> 5) * 8 + (d >> 4)) * 512
                    + ((d & 15) + (((l0 >> 3) & 3) << 4)) * 8 + (l0 & 7));
                ushort4 pk;
                pk.x = bf16_rne(acc[mi][ni][0]);
                pk.y = bf16_rne(acc[mi][ni][1]);
                pk.z = bf16_rne(acc[mi][ni][2]);
                pk.w = bf16_rne(acc[mi][ni][3]);
                *reinterpret_cast<ushort4*>(&out[off]) = pk;
            }
        }
    } else if (MODE == 1) {
        #pragma unroll
        for (int mi = 0; mi < 4; ++mi)
            #pragma unroll
            for (int rr = 0; rr < 4; ++rr) {
                int l = (bm + wm + mi * 16 + lg * 4 + rr) & (L_ - 1);
                #pragma unroll
                for (int ni = 0; ni < 4; ++ni) {
                    int d = wn + ni * 16 + lr;
                    size_t off = bh_base
                        + (size_t)(((l >> 4) * 4 + (d >> 5)) * 512
                        + ((l & 15) + (((d >> 3) & 3) << 4)) * 8 + (d & 7));
                    out[off] = bf16_rne(acc[mi][ni][rr]);
                }
            }
    } else {
        const float scale = QSCALE_;
        #pragma unroll
        for (int mi = 0; mi < 4; ++mi)
            #pragma unroll
            for (int rr = 0; rr < 4; ++rr) {
                int l = (bm + wm + mi * 16 + lg * 4 + rr) & (L_ - 1);
                #pragma unroll
                for (int ni = 0; ni < 4; ++ni) {
                    int d = wn + ni * 16 + lr;
                    out[bh_base + (size_t)l * DH_ + d] = bf16_rne(acc[mi][ni][rr] * scale);
                }
            }
    }
}

// ---------------------------------------------------------------------------
// Attention: 4 waves x 32 q-rows = 128 q/block; KVBLK=64; K LDS double-buffered
// via global_load_lds; V fragments direct from global; swizzled P roundtrip.
// exp2-based softmax (log2e folded into Wq); setprio around MFMA clusters.
// ---------------------------------------------------------------------------
__global__ void __launch_bounds__(256, 2)
attn_fused2(const unsigned short* __restrict__ qw, const unsigned short* __restrict__ kfr,
            const unsigned short* __restrict__ vfr, const float* __restrict__ mask,
            float* __restrict__ out)
{
    __shared__ __align__(16) char Ks[2][16384];
    __shared__ __align__(16) char Pl[4][32 * 144];

    const int tid  = threadIdx.x;
    const int lane = tid & 63;
    const int wid  = tid >> 6;
    const int lr   = lane & 15;
    const int lg   = lane >> 4;

    const int p  = (blockIdx.x & 7) * 64 + (blockIdx.x >> 3);
    const int bh = p >> 4;
    const int qt = p & 15;
    const int b  = bh >> 4;
    const int h  = bh & 15;
    const int q0 = qt * 128 + wid * 32;

    const unsigned short* qbase = qw  + (size_t)bh * (L_ * DH_);
    const unsigned short* kbase = kfr + (size_t)bh * (L_ * DH_);
    const unsigned short* vbase = vfr + (size_t)bh * (L_ * DH_);

    s16x8 qf[2][4];
    #pragma unroll
    for (int qs = 0; qs < 2; ++qs)
        #pragma unroll
        for (int kc = 0; kc < 4; ++kc)
            qf[qs][kc] = *reinterpret_cast<const s16x8*>(
                &qbase[(size_t)(q0 + qs * 16 + lr) * DH_ + kc * 32 + lg * 8]);

    float mv[2][4];
    #pragma unroll
    for (int qs = 0; qs < 2; ++qs)
        #pragma unroll
        for (int r = 0; r < 4; ++r)
            mv[qs][r] = mask[b * L_ + q0 + qs * 16 + lg * 4 + r];

    fp32x4 acc[2][8] = {};
    float rs[2][4] = {};

    char* P = &Pl[wid][0];

    auto STAGE = [&](int buf, int t) {
        const unsigned short* g = kbase + (size_t)t * 8192;
        #pragma unroll
        for (int c = 0; c < 4; ++c)
            gld16(g + c * 2048 + tid * 8, &Ks[buf][c * 4096 + wid * 1024]);
    };

    STAGE(0, 0);
    __syncthreads();

    for (int t = 0; t < L_ / 64; ++t) {
        const int buf = t & 1;
        if (t + 1 < L_ / 64) STAGE(buf ^ 1, t + 1);

        s16x8 vv0[8], vv1[8];
        #pragma unroll
        for (int ds = 0; ds < 8; ++ds)
            vv0[ds] = *reinterpret_cast<const s16x8*>(
                &vbase[(size_t)t * 8192 + (0 * 8 + ds) * 512 + lane * 8]);

        fp32x4 s2[2][4] = {};
        __builtin_amdgcn_s_setprio(1);
        #pragma unroll
        for (int kvs = 0; kvs < 4; ++kvs)
            #pragma unroll
            for (int kc = 0; kc < 4; ++kc) {
                s16x8 kf = *reinterpret_cast<const s16x8*>(
                    Ks[buf] + (kvs * 4 + kc) * 1024 + lane * 16);
                s2[0][kvs] = MFMA(qf[0][kc], kf, s2[0][kvs]);
                s2[1][kvs] = MFMA(qf[1][kc], kf, s2[1][kvs]);
            }
        __builtin_amdgcn_s_setprio(0);

        #pragma unroll
        for (int qs = 0; qs < 2; ++qs)
            #pragma unroll
            for (int kvs = 0; kvs < 4; ++kvs)
                #pragma unroll
                for (int r = 0; r < 4; ++r) {
                    float pv = exp2f(s2[qs][kvs][r] * mv[qs][r]);
                    rs[qs][r] += pv;
                    int row  = qs * 16 + lg * 4 + r;
                    int col2 = (kvs * 16 + lr) * 2;
                    int addr = row * 144 + (((col2 & ~15) ^ (((row >> 2) & 3) << 4)) | (col2 & 15));
                    *reinterpret_cast<unsigned short*>(P + addr) = bf16_rne(pv);
                }

        #pragma unroll
        for (int ds = 0; ds < 8; ++ds)
            vv1[ds] = *reinterpret_cast<const s16x8*>(
                &vbase[(size_t)t * 8192 + (1 * 8 + ds) * 512 + lane * 8]);

        __builtin_amdgcn_s_setprio(1);
        #pragma unroll
        for (int qs = 0; qs < 2; ++qs) {
            int row = qs * 16 + lr;
            int xr  = ((row >> 2) & 3) << 4;
            s16x8 pa0 = *reinterpret_cast<const s16x8*>(P + row * 144 + ((0 * 64 + lg * 16) ^ xr));
            s16x8 pa1 = *reinterpret_cast<const s16x8*>(P + row * 144 + ((1 * 64 + lg * 16) ^ xr));
            #pragma unroll
            for (int ds = 0; ds < 8; ++ds) {
                acc[qs][ds] = MFMA(pa0, vv0[ds], acc[qs][ds]);
                acc[qs][ds] = MFMA(pa1, vv1[ds], acc[qs][ds]);
            }
        }
        __builtin_amdgcn_s_setprio(0);

        __syncthreads();
    }

    #pragma unroll
    for (int qs = 0; qs < 2; ++qs) {
        float inv[4];
        #pragma unroll
        for (int r = 0; r < 4; ++r) {
            float v = rs[qs][r];
            v += __shfl_xor(v, 1);
            v += __shfl_xor(v, 2);
            v += __shfl_xor(v, 4);
            v += __shfl_xor(v, 8);
            inv[r] = 1.0f / v;
        }
        #pragma unroll
        for (int ds = 0; ds < 8; ++ds)
            #pragma unroll
            for (int r = 0; r < 4; ++r)
                out[((size_t)(b * L_ + q0 + qs * 16 + lg * 4 + r)) * DIM_ + h * DH_ + ds * 16 + lr]
                    = acc[qs][ds][r] * inv[r];
    }
}

extern "C" void kernel_launch(void* const* d_in, const int* in_sizes, int n_in,
                              void* d_out, int out_size, void* d_ws, size_t ws_size,
                              hipStream_t stream) {
    const float* query = (const float*)d_in[0];
    const float* value = (const float*)d_in[1];
    const float* mask  = (const float*)d_in[2];
    const float* Wq    = (const float*)d_in[3];
    const float* Wk    = (const float*)d_in[4];
    const float* Wv    = (const float*)d_in[5];
    float* out = (float*)d_out;

    const size_t elems = (size_t)B_ * H_ * L_ * DH_;  // 8388608
    const size_t welems = elems / 2;                  // 4194304
    unsigned short* q_ws = (unsigned short*)d_ws;
    unsigned short* k_ws = q_ws + elems;
    unsigned short* v_ws = k_ws + elems;

    dim3 blk(256, 1, 1);
    const size_t need_full = (5 * elems + 3 * welems) * sizeof(unsigned short);  // ~109 MB
    const size_t need_mid  = (4 * elems + welems) * sizeof(unsigned short);      // ~75.5 MB

    if (ws_size >= need_full) {
        unsigned short* qbf  = v_ws + elems;
        unsigned short* vbf  = qbf + elems;
        unsigned short* wqbf = vbf + elems;
        unsigned short* wkbf = wqbf + welems;
        unsigned short* wvbf = wkbf + welems;

        cvt_all<<<dim3(2048, 1, 1), blk, 0, stream>>>(query, value, Wq, Wk, Wv,
                                                      qbf, vbf, wqbf, wkbf, wvbf);
        gemm_qkv<<<dim3(1536, 1, 1), blk, 0, stream>>>(qbf, vbf, wqbf, wkbf, wvbf,
                                                       q_ws, k_ws, v_ws, -1);
    } else if (ws_size >= need_mid) {
        unsigned short* Axb = v_ws + elems;
        unsigned short* Bxb = Axb + elems;
        dim3 cg(2048, 1, 1);
        dim3 sg(512, 1, 1);

        // reuse cvt_all's per-segment paths via small dedicated launches is not
        // possible here; do scaled copies with gemm-compatible buffers.
        // Convert + GEMM sequenced with buffer reuse.
        cvt_all<<<cg, blk, 0, stream>>>(query, query, Wq, Wq, Wq,
                                        Axb, Axb, Bxb, Bxb, Bxb);  // fills Axb=query, Bxb=Wq*scale
        gemm_qkv<<<sg, blk, 0, stream>>>(Axb, Axb, Bxb, Bxb, Bxb, q_ws, k_ws, v_ws, 0);

        cvt_all<<<cg, blk, 0, stream>>>(value, value, Wk, Wk, Wk,
                                        Axb, Axb, Bxb, Bxb, Bxb);
        // note: Wk passes through the Wq segment with QSCALE_ — undo not possible;
        // instead use dedicated ordering: Wk occupies segments 3/4 (unscaled) too.
        // The Wq-segment write (scaled) is overwritten by segment-4 (unscaled) order
        // being undefined -> avoid: use only segment 4 data? Not safe. Fall through
        // to f32 path instead for mid-size workspaces.
        gemm_qkv<<<sg, blk, 0, stream>>>(Axb, Axb, Bxb, Bxb, Bxb, k_ws, k_ws, v_ws, 1);

        cvt_all<<<cg, blk, 0, stream>>>(value, value, Wv, Wv, Wv,
                                        Axb, Axb, Bxb, Bxb, Bxb);
        gemm_qkv<<<sg, blk, 0, stream>>>(Axb, Axb, Bxb, Bxb, Bxb, v_ws, v_ws, v_ws, 2);
    } else {
        dim3 gg(32, 16, 1);
        proj_gemm<0><<<gg, blk, 0, stream>>>(query, Wq, q_ws);
        proj_gemm<1><<<gg, blk, 0, stream>>>(value, Wk, k_ws);
        proj_gemm<2><<<gg, blk, 0, stream>>>(value, Wv, v_ws);
    }

    attn_fused2<<<dim3(512, 1, 1), blk, 0, stream>>>(q_ws, k_ws, v_ws, mask, out);
}

// Round 5
// 223.552 us; speedup vs baseline: 2.9686x; 1.1404x over previous
//
#include <hip/hip_runtime.h>
#include <hip/hip_bf16.h>
#include <stdint.h>

#define DIM_ 2048
#define L_   2048
#define B_   2
#define H_   16
#define DH_  128

// scale folded into Wq: (1/sqrt(128)) * log2(e)  -> softmax uses raw v_exp_f32
#define QSCALE_ 0.12751743f

typedef __attribute__((ext_vector_type(4))) float fp32x4;
typedef __attribute__((ext_vector_type(8))) short s16x8;

__device__ __forceinline__ unsigned short bf16_rne(float f) {
    unsigned u = __builtin_bit_cast(unsigned, f);
    u += 0x7fffu + ((u >> 16) & 1u);
    return (unsigned short)(u >> 16);
}

__device__ __forceinline__ fp32x4 MFMA(s16x8 a, s16x8 b, fp32x4 c) {
    return __builtin_amdgcn_mfma_f32_16x16x32_bf16(a, b, c, 0, 0, 0);
}

__device__ __forceinline__ void gld16(const void* g, void* l) {
    auto gp = reinterpret_cast<const uint32_t __attribute__((address_space(1)))*>(
        reinterpret_cast<uintptr_t>(g));
    auto lp = reinterpret_cast<uint32_t __attribute__((address_space(3)))*>(
        reinterpret_cast<uintptr_t>(l));
    __builtin_amdgcn_global_load_lds(gp, lp, 16, 0, 0);
}

__device__ __forceinline__ float exp2_raw(float x) {
    float r; asm("v_exp_f32 %0, %1" : "=v"(r) : "v"(x)); return r;
}

__device__ __forceinline__ unsigned cvtpk_bf16(float a, float b) {
    unsigned r; asm("v_cvt_pk_bf16_f32 %0, %1, %2" : "=v"(r) : "v"(a), "v"(b)); return r;
}

// ---------------------------------------------------------------------------
// Merged f32->bf16 conversion: query | value | Wq(*QSCALE_) | Wk | Wv in one pass
// ---------------------------------------------------------------------------
__global__ void __launch_bounds__(256)
cvt_all(const float* __restrict__ query, const float* __restrict__ value,
        const float* __restrict__ Wq, const float* __restrict__ Wk,
        const float* __restrict__ Wv,
        unsigned short* __restrict__ qb, unsigned short* __restrict__ vb,
        unsigned short* __restrict__ wqb, unsigned short* __restrict__ wkb,
        unsigned short* __restrict__ wvb)
{
    const int total4 = 7340032;  // (2*8388608 + 3*4194304) / 4
    int i = blockIdx.x * 256 + threadIdx.x;
    const int stride = gridDim.x * 256;
    for (; i < total4; i += stride) {
        const float4* s; ushort4* d; int off; float sc = 1.0f;
        if (i < 2097152)      { s = (const float4*)query; d = (ushort4*)qb;  off = i; }
        else if (i < 4194304) { s = (const float4*)value; d = (ushort4*)vb;  off = i - 2097152; }
        else if (i < 5242880) { s = (const float4*)Wq;    d = (ushort4*)wqb; off = i - 4194304; sc = QSCALE_; }
        else if (i < 6291456) { s = (const float4*)Wk;    d = (ushort4*)wkb; off = i - 5242880; }
        else                  { s = (const float4*)Wv;    d = (ushort4*)wvb; off = i - 6291456; }
        float4 v = s[off];
        ushort4 o;
        o.x = bf16_rne(v.x * sc); o.y = bf16_rne(v.y * sc);
        o.z = bf16_rne(v.z * sc); o.w = bf16_rne(v.w * sc);
        d[off] = o;
    }
}

// ---------------------------------------------------------------------------
// Attention workspace fragment-linear layouts (elements, within one bh):
//   K: koff(l,d) = ((l>>4)*4 + (d>>5))*512 + ((l&15) + (((d>>3)&3)<<4))*8 + (d&7)
//   V: voff(l,d) = ((l>>5)*8 + (d>>4))*512 + ((d&15) + (((l>>3)&3)<<4))*8 + (l&7)
// ---------------------------------------------------------------------------

// ---------------------------------------------------------------------------
// Merged QKV bf16 GEMM, m97 structure: 128x128 tile, BK=64, global_load_lds
// width-16, double-buffered LDS, 1 barrier/K-step.
// which 0: q[bh][l][d] (QSCALE_ pre-folded into Wq; multiplied by mask[b,l]);
// which 1: K frag-linear; which 2: V frag-linear
// ---------------------------------------------------------------------------
__global__ void __launch_bounds__(256)
gemm_qkv(const unsigned short* __restrict__ qb, const unsigned short* __restrict__ vb,
         const unsigned short* __restrict__ wqb, const unsigned short* __restrict__ wkb,
         const unsigned short* __restrict__ wvb, const float* __restrict__ mask,
         unsigned short* __restrict__ q_ws, unsigned short* __restrict__ k_ws,
         unsigned short* __restrict__ v_ws, int only)
{
    __shared__ __align__(16) char As[2][16384];
    __shared__ __align__(16) char Bs[2][16384];

    int which, r;
    if (only < 0) {
        int g = (blockIdx.x & 7) * 192 + (blockIdx.x >> 3);  // XCD swizzle, 1536%8==0
        which = g >> 9;
        r = g & 511;
    } else {
        which = only;
        r = (blockIdx.x & 7) * 64 + (blockIdx.x >> 3);
    }
    const int bm = ((r >> 4) & 31) << 7;
    const int bn = (r & 15) << 7;

    const unsigned short* Xb = (which == 0) ? qb : vb;
    const unsigned short* Wb = (which == 0) ? wqb : (which == 1) ? wkb : wvb;
    unsigned short* out      = (which == 0) ? q_ws : (which == 1) ? k_ws : v_ws;

    const int tid  = threadIdx.x;
    const int lane = tid & 63;
    const int wid  = tid >> 6;
    const int wm   = (wid >> 1) << 6;
    const int wn   = (wid & 1) << 6;
    const int lr   = lane & 15;
    const int lg   = lane >> 4;

    fp32x4 acc[4][4] = {};

    const int srow = wid * 8 + (lane >> 3);
    const int scol = (lane & 7) * 8;  // elements

    auto STAGE = [&](int buf, int k0) {
        const unsigned short* ga = Xb + (size_t)(bm + srow) * DIM_ + k0 + scol;
        const unsigned short* gb = Wb + (size_t)(bn + srow) * DIM_ + k0 + scol;
        #pragma unroll
        for (int rr = 0; rr < 4; ++rr) {
            gld16(ga + (size_t)rr * 32 * DIM_, &As[buf][rr * 4096 + wid * 1024]);
            gld16(gb + (size_t)rr * 32 * DIM_, &Bs[buf][rr * 4096 + wid * 1024]);
        }
    };

    STAGE(0, 0);
    __syncthreads();

    for (int t = 0; t < DIM_ / 64; ++t) {
        const int buf = t & 1;
        if (t + 1 < DIM_ / 64) STAGE(buf ^ 1, (t + 1) * 64);

        #pragma unroll
        for (int kk = 0; kk < 2; ++kk) {
            s16x8 af[4], bfr[4];
            #pragma unroll
            for (int mi = 0; mi < 4; ++mi)
                af[mi] = *reinterpret_cast<const s16x8*>(
                    As[buf] + (wm + mi * 16 + lr) * 128 + kk * 64 + lg * 16);
            #pragma unroll
            for (int ni = 0; ni < 4; ++ni)
                bfr[ni] = *reinterpret_cast<const s16x8*>(
                    Bs[buf] + (wn + ni * 16 + lr) * 128 + kk * 64 + lg * 16);
            #pragma unroll
            for (int mi = 0; mi < 4; ++mi)
                #pragma unroll
                for (int ni = 0; ni < 4; ++ni)
                    acc[mi][ni] = MFMA(af[mi], bfr[ni], acc[mi][ni]);
        }
        __syncthreads();
    }

    const int h  = bn >> 7;
    const int bb = bm >> 11;
    const size_t bh_base = (size_t)(bb * H_ + h) * (L_ * DH_);

    if (which == 2) {
        #pragma unroll
        for (int mi = 0; mi < 4; ++mi) {
            int l0 = (bm + wm + mi * 16 + lg * 4) & (L_ - 1);
            #pragma unroll
            for (int ni = 0; ni < 4; ++ni) {
                int d = wn + ni * 16 + lr;
                size_t off = bh_base
                    + (size_t)(((l0 >> 5) * 8 + (d >> 4)) * 512
                    + ((d & 15) + (((l0 >> 3) & 3) << 4)) * 8 + (l0 & 7));
                ushort4 pk;
                pk.x = bf16_rne(acc[mi][ni][0]);
                pk.y = bf16_rne(acc[mi][ni][1]);
                pk.z = bf16_rne(acc[mi][ni][2]);
                pk.w = bf16_rne(acc[mi][ni][3]);
                *reinterpret_cast<ushort4*>(&out[off]) = pk;
            }
        }
    } else if (which == 1) {
        #pragma unroll
        for (int mi = 0; mi < 4; ++mi)
            #pragma unroll
            for (int rr = 0; rr < 4; ++rr) {
                int l = (bm + wm + mi * 16 + lg * 4 + rr) & (L_ - 1);
                #pragma unroll
                for (int ni = 0; ni < 4; ++ni) {
                    int d = wn + ni * 16 + lr;
                    size_t off = bh_base
                        + (size_t)(((l >> 4) * 4 + (d >> 5)) * 512
                        + ((l & 15) + (((d >> 3) & 3) << 4)) * 8 + (d & 7));
                    out[off] = bf16_rne(acc[mi][ni][rr]);
                }
            }
    } else {
        const float* mrow = mask + bb * L_;
        #pragma unroll
        for (int mi = 0; mi < 4; ++mi)
            #pragma unroll
            for (int rr = 0; rr < 4; ++rr) {
                int l = (bm + wm + mi * 16 + lg * 4 + rr) & (L_ - 1);
                float mvv = mrow[l];
                #pragma unroll
                for (int ni = 0; ni < 4; ++ni) {
                    int d = wn + ni * 16 + lr;
                    out[bh_base + (size_t)l * DH_ + d] = bf16_rne(acc[mi][ni][rr] * mvv);
                }
            }
    }
}

// ---------------------------------------------------------------------------
// Fallback f32-input GEMM (for small ws_size). Mask folded into Q epilogue.
// ---------------------------------------------------------------------------
template <int MODE>
__global__ void __launch_bounds__(256)
proj_gemm(const float* __restrict__ X, const float* __restrict__ W,
          const float* __restrict__ mask, unsigned short* __restrict__ out)
{
    __shared__ __align__(16) char As[128 * 128];
    __shared__ __align__(16) char Bs[128 * 128];

    const int tid  = threadIdx.x;
    const int lane = tid & 63;
    const int wid  = tid >> 6;
    const int wm   = (wid >> 1) << 6;
    const int wn   = (wid & 1) << 6;
    const int bm   = blockIdx.x << 7;
    const int bn   = blockIdx.y << 7;
    const int lr   = lane & 15;
    const int lg   = lane >> 4;

    fp32x4 acc[4][4] = {};

    for (int k0 = 0; k0 < DIM_; k0 += 64) {
        #pragma unroll
        for (int i = 0; i < 8; ++i) {
            int u   = i * 256 + tid;
            int row = u >> 4;
            int c4  = (u & 15) << 2;
            const float4 av = *reinterpret_cast<const float4*>(&X[(size_t)(bm + row) * DIM_ + k0 + c4]);
            const float4 wv = *reinterpret_cast<const float4*>(&W[(size_t)(bn + row) * DIM_ + k0 + c4]);
            int addr = (row * 128 + (c4 << 1)) ^ ((row & 7) << 4);
            ushort4 ap, wp;
            ap.x = bf16_rne(av.x); ap.y = bf16_rne(av.y); ap.z = bf16_rne(av.z); ap.w = bf16_rne(av.w);
            wp.x = bf16_rne(wv.x); wp.y = bf16_rne(wv.y); wp.z = bf16_rne(wv.z); wp.w = bf16_rne(wv.w);
            *reinterpret_cast<ushort4*>(As + addr) = ap;
            *reinterpret_cast<ushort4*>(Bs + addr) = wp;
        }
        __syncthreads();

        #pragma unroll
        for (int kk = 0; kk < 2; ++kk) {
            s16x8 af[4], bfr[4];
            #pragma unroll
            for (int mi = 0; mi < 4; ++mi) {
                int row = wm + mi * 16 + lr;
                af[mi] = *reinterpret_cast<const s16x8*>(As + ((row * 128 + kk * 64 + lg * 16) ^ ((row & 7) << 4)));
            }
            #pragma unroll
            for (int ni = 0; ni < 4; ++ni) {
                int row = wn + ni * 16 + lr;
                bfr[ni] = *reinterpret_cast<const s16x8*>(Bs + ((row * 128 + kk * 64 + lg * 16) ^ ((row & 7) << 4)));
            }
            #pragma unroll
            for (int mi = 0; mi < 4; ++mi)
                #pragma unroll
                for (int ni = 0; ni < 4; ++ni)
                    acc[mi][ni] = MFMA(af[mi], bfr[ni], acc[mi][ni]);
        }
        __syncthreads();
    }

    const int h  = bn >> 7;
    const int bb = bm >> 11;
    const size_t bh_base = (size_t)(bb * H_ + h) * (L_ * DH_);

    if (MODE == 2) {
        #pragma unroll
        for (int mi = 0; mi < 4; ++mi) {
            int l0 = (bm + wm + mi * 16 + lg * 4) & (L_ - 1);
            #pragma unroll
            for (int ni = 0; ni < 4; ++ni) {
                int d = wn + ni * 16 + lr;
                size_t off = bh_base
                    + (size_t)(((l0 >> 5) * 8 + (d >> 4)) * 512
                    + ((d & 15) + (((l0 >> 3) & 3) << 4)) * 8 + (l0 & 7));
                ushort4 pk;
                pk.x = bf16_rne(acc[mi][ni][0]);
                pk.y = bf16_rne(acc[mi][ni][1]);
                pk.z = bf16_rne(acc[mi][ni][2]);
                pk.w = bf16_rne(acc[mi][ni][3]);
                *reinterpret_cast<ushort4*>(&out[off]) = pk;
            }
        }
    } else if (MODE == 1) {
        #pragma unroll
        for (int mi = 0; mi < 4; ++mi)
            #pragma unroll
            for (int rr = 0; rr < 4; ++rr) {
                int l = (bm + wm + mi * 16 + lg * 4 + rr) & (L_ - 1);
                #pragma unroll
                for (int ni = 0; ni < 4; ++ni) {
                    int d = wn + ni * 16 + lr;
                    size_t off = bh_base
                        + (size_t)(((l >> 4) * 4 + (d >> 5)) * 512
                        + ((l & 15) + (((d >> 3) & 3) << 4)) * 8 + (d & 7));
                    out[off] = bf16_rne(acc[mi][ni][rr]);
                }
            }
    } else {
        const float* mrow = mask + bb * L_;
        #pragma unroll
        for (int mi = 0; mi < 4; ++mi)
            #pragma unroll
            for (int rr = 0; rr < 4; ++rr) {
                int l = (bm + wm + mi * 16 + lg * 4 + rr) & (L_ - 1);
                float mvv = mrow[l] * QSCALE_;
                #pragma unroll
                for (int ni = 0; ni < 4; ++ni) {
                    int d = wn + ni * 16 + lr;
                    out[bh_base + (size_t)l * DH_ + d] = bf16_rne(acc[mi][ni][rr] * mvv);
                }
            }
    }
}

// ---------------------------------------------------------------------------
// Attention v3: swapped QK^T (C rows = kv, cols = q) so cvt_pk pairs are
// adjacent-kv; P roundtrip = 8 ds_write_b64 + 4 ds_read_b128 per tile;
// rowsums via ones-MFMA (no shuffles); mask pre-folded into Q.
// 4 waves x 32 q-rows; KVBLK=64; K LDS double-buffered via global_load_lds;
// V fragments direct from global (L2-served).
// ---------------------------------------------------------------------------
__global__ void __launch_bounds__(256, 2)
attn_fused3(const unsigned short* __restrict__ qw, const unsigned short* __restrict__ kfr,
            const unsigned short* __restrict__ vfr, float* __restrict__ out)
{
    __shared__ __align__(16) char Ks[2][16384];
    __shared__ __align__(16) char Pl[4][4608];   // per wave: 2 qs x 16 rows x 144B

    const int tid  = threadIdx.x;
    const int lane = tid & 63;
    const int wid  = tid >> 6;
    const int lr   = lane & 15;
    const int lg   = lane >> 4;

    const int p  = (blockIdx.x & 7) * 64 + (blockIdx.x >> 3);
    const int bh = p >> 4;
    const int qt = p & 15;
    const int b  = bh >> 4;
    const int h  = bh & 15;
    const int q0 = qt * 128 + wid * 32;

    const unsigned short* qbase = qw  + (size_t)bh * (L_ * DH_);
    const unsigned short* kbase = kfr + (size_t)bh * (L_ * DH_);
    const unsigned short* vbase = vfr + (size_t)bh * (L_ * DH_);

    // Q fragments (mask & scale pre-folded): used as MFMA B-operand (col = q)
    s16x8 qf[2][4];
    #pragma unroll
    for (int qs = 0; qs < 2; ++qs)
        #pragma unroll
        for (int kc = 0; kc < 4; ++kc)
            qf[qs][kc] = *reinterpret_cast<const s16x8*>(
                &qbase[(size_t)(q0 + qs * 16 + lr) * DH_ + kc * 32 + lg * 8]);

    // ones B-fragment for rowsum MFMA
    s16x8 ones;
    #pragma unroll
    for (int i = 0; i < 8; ++i) ones[i] = (short)0x3F80;

    fp32x4 acc[2][8] = {};
    fp32x4 racc[2] = {};

    char* P = &Pl[wid][0];

    auto STAGE = [&](int buf, int t) {
        const unsigned short* g = kbase + (size_t)t * 8192;
        #pragma unroll
        for (int c = 0; c < 4; ++c)
            gld16(g + c * 2048 + tid * 8, &Ks[buf][c * 4096 + wid * 1024]);
    };

    STAGE(0, 0);
    __syncthreads();

    for (int t = 0; t < L_ / 64; ++t) {
        const int buf = t & 1;
        if (t + 1 < L_ / 64) STAGE(buf ^ 1, t + 1);

        // V fragments chunk c=0 (8 x 1KB coalesced, L2-served)
        s16x8 vv0[8], vv1[8];
        #pragma unroll
        for (int ds = 0; ds < 8; ++ds)
            vv0[ds] = *reinterpret_cast<const s16x8*>(
                &vbase[(size_t)t * 8192 + (0 * 8 + ds) * 512 + lane * 8]);

        // QK^T swapped: s2[qs][kvs] rows = kv (16kvs+4lg+r), cols = q (lr)
        fp32x4 s2[2][4] = {};
        __builtin_amdgcn_s_setprio(1);
        #pragma unroll
        for (int kvs = 0; kvs < 4; ++kvs)
            #pragma unroll
            for (int kc = 0; kc < 4; ++kc) {
                s16x8 kf = *reinterpret_cast<const s16x8*>(
                    Ks[buf] + (kvs * 4 + kc) * 1024 + lane * 16);
                s2[0][kvs] = MFMA(kf, qf[0][kc], s2[0][kvs]);
                s2[1][kvs] = MFMA(kf, qf[1][kc], s2[1][kvs]);
            }
        __builtin_amdgcn_s_setprio(0);

        // p = exp2(s); pack adjacent-kv pairs; P[q=lr][kv] row-major, stride 144B
        #pragma unroll
        for (int qs = 0; qs < 2; ++qs)
            #pragma unroll
            for (int kvs = 0; kvs < 4; ++kvs) {
                float e0 = exp2_raw(s2[qs][kvs][0]);
                float e1 = exp2_raw(s2[qs][kvs][1]);
                float e2 = exp2_raw(s2[qs][kvs][2]);
                float e3 = exp2_raw(s2[qs][kvs][3]);
                uint2 pk;
                pk.x = cvtpk_bf16(e0, e1);
                pk.y = cvtpk_bf16(e2, e3);
                *reinterpret_cast<uint2*>(P + qs * 2304 + lr * 144 + kvs * 32 + lg * 8) = pk;
            }

        // V fragments chunk c=1
        #pragma unroll
        for (int ds = 0; ds < 8; ++ds)
            vv1[ds] = *reinterpret_cast<const s16x8*>(
                &vbase[(size_t)t * 8192 + (1 * 8 + ds) * 512 + lane * 8]);

        // PV: pa = P A-frags (row=q by lr, k = 32c+8lg..7); rowsum via ones-MFMA
        __builtin_amdgcn_s_setprio(1);
        #pragma unroll
        for (int qs = 0; qs < 2; ++qs) {
            s16x8 pa0 = *reinterpret_cast<const s16x8*>(P + qs * 2304 + lr * 144 + 0 * 64 + lg * 16);
            s16x8 pa1 = *reinterpret_cast<const s16x8*>(P + qs * 2304 + lr * 144 + 1 * 64 + lg * 16);
            racc[qs] = MFMA(pa0, ones, racc[qs]);
            racc[qs] = MFMA(pa1, ones, racc[qs]);
            #pragma unroll
            for (int ds = 0; ds < 8; ++ds) {
                acc[qs][ds] = MFMA(pa0, vv0[ds], acc[qs][ds]);
                acc[qs][ds] = MFMA(pa1, vv1[ds], acc[qs][ds]);
            }
        }
        __builtin_amdgcn_s_setprio(0);

        __syncthreads();
    }

    // normalize + write out; racc rows (4lg+r) align with acc rows -> no shuffle
    #pragma unroll
    for (int qs = 0; qs < 2; ++qs) {
        float inv[4];
        #pragma unroll
        for (int r = 0; r < 4; ++r) inv[r] = 1.0f / racc[qs][r];
        #pragma unroll
        for (int ds = 0; ds < 8; ++ds)
            #pragma unroll
            for (int r = 0; r < 4; ++r)
                out[((size_t)(b * L_ + q0 + qs * 16 + lg * 4 + r)) * DIM_ + h * DH_ + ds * 16 + lr]
                    = acc[qs][ds][r] * inv[r];
    }
}

extern "C" void kernel_launch(void* const* d_in, const int* in_sizes, int n_in,
                              void* d_out, int out_size, void* d_ws, size_t ws_size,
                              hipStream_t stream) {
    const float* query = (const float*)d_in[0];
    const float* value = (const float*)d_in[1];
    const float* mask  = (const float*)d_in[2];
    const float* Wq    = (const float*)d_in[3];
    const float* Wk    = (const float*)d_in[4];
    const float* Wv    = (const float*)d_in[5];
    float* out = (float*)d_out;

    const size_t elems = (size_t)B_ * H_ * L_ * DH_;  // 8388608
    const size_t welems = elems / 2;                  // 4194304
    unsigned short* q_ws = (unsigned short*)d_ws;
    unsigned short* k_ws = q_ws + elems;
    unsigned short* v_ws = k_ws + elems;

    dim3 blk(256, 1, 1);
    const size_t need_full = (5 * elems + 3 * welems) * sizeof(unsigned short);  // ~109 MB

    if (ws_size >= need_full) {
        unsigned short* qbf  = v_ws + elems;
        unsigned short* vbf  = qbf + elems;
        unsigned short* wqbf = vbf + elems;
        unsigned short* wkbf = wqbf + welems;
        unsigned short* wvbf = wkbf + welems;

        cvt_all<<<dim3(2048, 1, 1), blk, 0, stream>>>(query, value, Wq, Wk, Wv,
                                                      qbf, vbf, wqbf, wkbf, wvbf);
        gemm_qkv<<<dim3(1536, 1, 1), blk, 0, stream>>>(qbf, vbf, wqbf, wkbf, wvbf, mask,
                                                       q_ws, k_ws, v_ws, -1);
    } else {
        dim3 gg(32, 16, 1);
        proj_gemm<0><<<gg, blk, 0, stream>>>(query, Wq, mask, q_ws);
        proj_gemm<1><<<gg, blk, 0, stream>>>(value, Wk, mask, k_ws);
        proj_gemm<2><<<gg, blk, 0, stream>>>(value, Wv, mask, v_ws);
    }

    attn_fused3<<<dim3(512, 1, 1), blk, 0, stream>>>(q_ws, k_ws, v_ws, out);
}

// Round 6
// 216.646 us; speedup vs baseline: 3.0632x; 1.0319x over previous
//
#include <hip/hip_runtime.h>
#include <hip/hip_bf16.h>
#include <stdint.h>

#define DIM_ 2048
#define L_   2048
#define B_   2
#define H_   16
#define DH_  128
#define NT_  32   // K tiles of 64

// scale folded into Wq: (1/sqrt(128)) * log2(e)  -> softmax uses raw v_exp_f32
#define QSCALE_ 0.12751743f

typedef __attribute__((ext_vector_type(4))) float fp32x4;
typedef __attribute__((ext_vector_type(8))) short s16x8;

__device__ __forceinline__ unsigned short bf16_rne(float f) {
    unsigned u = __builtin_bit_cast(unsigned, f);
    u += 0x7fffu + ((u >> 16) & 1u);
    return (unsigned short)(u >> 16);
}

__device__ __forceinline__ fp32x4 MFMA(s16x8 a, s16x8 b, fp32x4 c) {
    return __builtin_amdgcn_mfma_f32_16x16x32_bf16(a, b, c, 0, 0, 0);
}

__device__ __forceinline__ void gld16(const void* g, void* l) {
    auto gp = reinterpret_cast<const uint32_t __attribute__((address_space(1)))*>(
        reinterpret_cast<uintptr_t>(g));
    auto lp = reinterpret_cast<uint32_t __attribute__((address_space(3)))*>(
        reinterpret_cast<uintptr_t>(l));
    __builtin_amdgcn_global_load_lds(gp, lp, 16, 0, 0);
}

__device__ __forceinline__ float exp2_raw(float x) {
    float r; asm("v_exp_f32 %0, %1" : "=v"(r) : "v"(x)); return r;
}

__device__ __forceinline__ unsigned cvtpk_bf16(float a, float b) {
    unsigned r; asm("v_cvt_pk_bf16_f32 %0, %1, %2" : "=v"(r) : "v"(a), "v"(b)); return r;
}

// ---------------------------------------------------------------------------
// Merged f32->bf16 conversion: query | value | Wq(*QSCALE_) | Wk | Wv
// ---------------------------------------------------------------------------
__global__ void __launch_bounds__(256)
cvt_all(const float* __restrict__ query, const float* __restrict__ value,
        const float* __restrict__ Wq, const float* __restrict__ Wk,
        const float* __restrict__ Wv,
        unsigned short* __restrict__ qb, unsigned short* __restrict__ vb,
        unsigned short* __restrict__ wqb, unsigned short* __restrict__ wkb,
        unsigned short* __restrict__ wvb)
{
    const int total4 = 7340032;
    int i = blockIdx.x * 256 + threadIdx.x;
    const int stride = gridDim.x * 256;
    for (; i < total4; i += stride) {
        const float4* s; ushort4* d; int off; float sc = 1.0f;
        if (i < 2097152)      { s = (const float4*)query; d = (ushort4*)qb;  off = i; }
        else if (i < 4194304) { s = (const float4*)value; d = (ushort4*)vb;  off = i - 2097152; }
        else if (i < 5242880) { s = (const float4*)Wq;    d = (ushort4*)wqb; off = i - 4194304; sc = QSCALE_; }
        else if (i < 6291456) { s = (const float4*)Wk;    d = (ushort4*)wkb; off = i - 5242880; }
        else                  { s = (const float4*)Wv;    d = (ushort4*)wvb; off = i - 6291456; }
        float4 v = s[off];
        ushort4 o;
        o.x = bf16_rne(v.x * sc); o.y = bf16_rne(v.y * sc);
        o.z = bf16_rne(v.z * sc); o.w = bf16_rne(v.w * sc);
        d[off] = o;
    }
}

// ---------------------------------------------------------------------------
// 256x256 8-phase QKV GEMM (T2+T3+T4+T5). BK=64 split into kk halves of 32.
// LDS slots As_[par][kk], Bs_[par][kk]: 256 rows x 32 K bf16 (64B rows),
// chunk-swizzled: byte = row*64 + ((chunk16 ^ (row&3))<<4).
// Stage schedule per tile t (1 half/phase): P1 B-k0(t+1), P2 A-k1(t+1),
// P3 B-k1(t+1), P4 A-k0(t+2). vmcnt(6) before trailing barriers of P2/P4.
// which 0: q[bh][l][d]*mask (QSCALE_ in Wq); 1: K frag-linear; 2: V frag-linear
// ---------------------------------------------------------------------------
__global__ void __launch_bounds__(512, 2)
gemm_qkv8(const unsigned short* __restrict__ qb, const unsigned short* __restrict__ vb,
          const unsigned short* __restrict__ wqb, const unsigned short* __restrict__ wkb,
          const unsigned short* __restrict__ wvb, const float* __restrict__ mask,
          unsigned short* __restrict__ q_ws, unsigned short* __restrict__ k_ws,
          unsigned short* __restrict__ v_ws)
{
    __shared__ __align__(16) char As_[2][2][16384];
    __shared__ __align__(16) char Bs_[2][2][16384];

    const int tid  = threadIdx.x;
    const int lane = tid & 63;
    const int wid  = tid >> 6;     // 0..7
    const int wm   = wid >> 2;     // 0..1  (M half)
    const int wn   = wid & 3;      // 0..3  (N quarter)
    const int lr   = lane & 15;
    const int lg   = lane >> 4;

    const int g     = (blockIdx.x & 7) * 48 + (blockIdx.x >> 3);  // XCD swizzle, 384%8==0
    const int which = g >> 7;
    const int rb    = g & 127;
    const int bm    = (rb >> 3) << 8;   // 16 M-blocks
    const int bn    = (rb & 7) << 8;    // 8 N-blocks

    const unsigned short* Xb = (which == 0) ? qb : vb;
    const unsigned short* Wb = (which == 0) ? wqb : (which == 1) ? wkb : wvb;

    // staging: thread covers rows (tid>>2) and (tid>>2)+128; pre-swizzled source chunk
    const int srow = tid >> 2;
    const int sgc  = (tid & 3) ^ (srow & 3);
    const unsigned short* gA = Xb + (size_t)(bm + srow) * DIM_ + sgc * 8;
    const unsigned short* gB = Wb + (size_t)(bn + srow) * DIM_ + sgc * 8;
    const int ldst = wid * 1024;   // wave-uniform LDS base (+ lane*16 by HW)

    // read-side: frag byte = row*64 + ((lg ^ (row&3))<<4); row&3 == lr&3
    const int xsw  = (lg ^ (lr & 3)) << 4;
    const int aoff = (wm * 128 + lr) * 64 + xsw;
    const int boff = (wn * 64 + lr) * 64 + xsw;

    fp32x4 acc[8][4] = {};
    s16x8 bq[4];

#define STG(SLOT, GPTR, T, KK) do {                                              \
    gld16((GPTR) + (size_t)(T) * 64 + (KK) * 32, (SLOT) + ldst);                 \
    gld16((GPTR) + (size_t)128 * DIM_ + (size_t)(T) * 64 + (KK) * 32,            \
          (SLOT) + 8192 + ldst);                                                 \
} while (0)

#define LDA(P, K, MS, MI) (*reinterpret_cast<const s16x8*>(&As_[P][K][aoff + (MS)*4096 + (MI)*1024]))
#define LDB(P, K, NF)     (*reinterpret_cast<const s16x8*>(&Bs_[P][K][boff + (NF)*1024]))

#define PHASE(P, K, MS, LOADB, STAGE_STMT, TAIL_STMT) do {                        \
    s16x8 a0 = LDA(P, K, MS, 0), a1 = LDA(P, K, MS, 1),                          \
          a2 = LDA(P, K, MS, 2), a3 = LDA(P, K, MS, 3);                          \
    if (LOADB) {                                                                  \
        bq[0] = LDB(P, K, 0); bq[1] = LDB(P, K, 1);                              \
        bq[2] = LDB(P, K, 2); bq[3] = LDB(P, K, 3);                              \
    }                                                                             \
    STAGE_STMT;                                                                   \
    __builtin_amdgcn_s_barrier();                                                 \
    asm volatile("s_waitcnt lgkmcnt(0)" ::: "memory");                            \
    __builtin_amdgcn_s_setprio(1);                                                \
    acc[(MS)*4+0][0] = MFMA(a0, bq[0], acc[(MS)*4+0][0]);                         \
    acc[(MS)*4+0][1] = MFMA(a0, bq[1], acc[(MS)*4+0][1]);                         \
    acc[(MS)*4+0][2] = MFMA(a0, bq[2], acc[(MS)*4+0][2]);                         \
    acc[(MS)*4+0][3] = MFMA(a0, bq[3], acc[(MS)*4+0][3]);                         \
    acc[(MS)*4+1][0] = MFMA(a1, bq[0], acc[(MS)*4+1][0]);                         \
    acc[(MS)*4+1][1] = MFMA(a1, bq[1], acc[(MS)*4+1][1]);                         \
    acc[(MS)*4+1][2] = MFMA(a1, bq[2], acc[(MS)*4+1][2]);                         \
    acc[(MS)*4+1][3] = MFMA(a1, bq[3], acc[(MS)*4+1][3]);                         \
    acc[(MS)*4+2][0] = MFMA(a2, bq[0], acc[(MS)*4+2][0]);                         \
    acc[(MS)*4+2][1] = MFMA(a2, bq[1], acc[(MS)*4+2][1]);                         \
    acc[(MS)*4+2][2] = MFMA(a2, bq[2], acc[(MS)*4+2][2]);                         \
    acc[(MS)*4+2][3] = MFMA(a2, bq[3], acc[(MS)*4+2][3]);                         \
    acc[(MS)*4+3][0] = MFMA(a3, bq[0], acc[(MS)*4+3][0]);                         \
    acc[(MS)*4+3][1] = MFMA(a3, bq[1], acc[(MS)*4+3][1]);                         \
    acc[(MS)*4+3][2] = MFMA(a3, bq[2], acc[(MS)*4+3][2]);                         \
    acc[(MS)*4+3][3] = MFMA(a3, bq[3], acc[(MS)*4+3][3]);                         \
    __builtin_amdgcn_s_setprio(0);                                                \
    TAIL_STMT;                                                                    \
    __builtin_amdgcn_s_barrier();                                                 \
} while (0)

#define W6 asm volatile("s_waitcnt vmcnt(6)" ::: "memory")
#define W4 asm volatile("s_waitcnt vmcnt(4)" ::: "memory")
#define W0 asm volatile("s_waitcnt vmcnt(0)" ::: "memory")

#define TILE(PAR, T, S1, S2, S3, S4, W2STMT, W4STMT) do {                         \
    PHASE(PAR, 0, 0, 1, if (S1) STG(&Bs_[(PAR)^1][0][0], gB, (T)+1, 0), (void)0); \
    PHASE(PAR, 0, 1, 0, if (S2) STG(&As_[(PAR)^1][1][0], gA, (T)+1, 1), W2STMT);  \
    PHASE(PAR, 1, 0, 1, if (S3) STG(&Bs_[(PAR)^1][1][0], gB, (T)+1, 1), (void)0); \
    PHASE(PAR, 1, 1, 0, if (S4) STG(&As_[PAR][0][0],     gA, (T)+2, 0), W4STMT);  \
} while (0)

    // prologue: tile0's 4 halves, vmcnt(4) (first 2 halves landed), +A-k0(1)
    STG(&As_[0][0][0], gA, 0, 0);
    STG(&Bs_[0][0][0], gB, 0, 0);
    STG(&As_[0][1][0], gA, 0, 1);
    STG(&Bs_[0][1][0], gB, 0, 1);
    W4;
    STG(&As_[1][0][0], gA, 1, 0);
    __builtin_amdgcn_s_barrier();

    for (int t = 0; t < NT_ - 2; t += 2) {
        TILE(0, t,     1, 1, 1, 1, W6, W6);
        TILE(1, t + 1, 1, 1, 1, 1, W6, W6);
    }
    TILE(0, NT_ - 2, 1, 1, 1, 0, W6, W4);   // stages tile31's B-k0, A-k1, B-k1
    TILE(1, NT_ - 1, 0, 0, 0, 0, W0, (void)0);

    // ---------------- epilogue ----------------
    const int bb = bm >> 11;
    const size_t bh0 = (size_t)(bb * H_) * (L_ * DH_);
    const int h  = (bn >> 7) + (wn >> 1);
    const size_t bh_base = bh0 + (size_t)h * (L_ * DH_);
    const int dbase = (wn & 1) * 64;
    const int rbase = bm + wm * 128;

    if (which == 2) {
        #pragma unroll
        for (int mf = 0; mf < 8; ++mf) {
            int l0 = (rbase + mf * 16 + lg * 4) & (L_ - 1);
            #pragma unroll
            for (int nf = 0; nf < 4; ++nf) {
                int d = dbase + nf * 16 + lr;
                size_t off = bh_base
                    + (size_t)(((l0 >> 5) * 8 + (d >> 4)) * 512
                    + ((d & 15) + (((l0 >> 3) & 3) << 4)) * 8 + (l0 & 7));
                ushort4 pk;
                pk.x = bf16_rne(acc[mf][nf][0]);
                pk.y = bf16_rne(acc[mf][nf][1]);
                pk.z = bf16_rne(acc[mf][nf][2]);
                pk.w = bf16_rne(acc[mf][nf][3]);
                *reinterpret_cast<ushort4*>(&v_ws[off]) = pk;
            }
        }
    } else if (which == 1) {
        #pragma unroll
        for (int mf = 0; mf < 8; ++mf)
            #pragma unroll
            for (int rr = 0; rr < 4; ++rr) {
                int l = (rbase + mf * 16 + lg * 4 + rr) & (L_ - 1);
                #pragma unroll
                for (int nf = 0; nf < 4; ++nf) {
                    int d = dbase + nf * 16 + lr;
                    size_t off = bh_base
                        + (size_t)(((l >> 4) * 4 + (d >> 5)) * 512
                        + ((l & 15) + (((d >> 3) & 3) << 4)) * 8 + (d & 7));
                    k_ws[off] = bf16_rne(acc[mf][nf][rr]);
                }
            }
    } else {
        const float* mrow = mask + bb * L_;
        #pragma unroll
        for (int mf = 0; mf < 8; ++mf)
            #pragma unroll
            for (int rr = 0; rr < 4; ++rr) {
                int l = (rbase + mf * 16 + lg * 4 + rr) & (L_ - 1);
                float mvv = mrow[l];
                #pragma unroll
                for (int nf = 0; nf < 4; ++nf) {
                    int d = dbase + nf * 16 + lr;
                    q_ws[bh_base + (size_t)l * DH_ + d] = bf16_rne(acc[mf][nf][rr] * mvv);
                }
            }
    }
#undef STG
#undef LDA
#undef LDB
#undef PHASE
#undef TILE
#undef W6
#undef W4
#undef W0
}

// ---------------------------------------------------------------------------
// Attention v3 (unchanged from round 5): swapped QK^T, cvt_pk P-pack, 
// ones-MFMA rowsums, mask pre-folded into Q, K via global_load_lds dbuf,
// V fragment-linear direct from global.
// ---------------------------------------------------------------------------
__global__ void __launch_bounds__(256, 2)
attn_fused3(const unsigned short* __restrict__ qw, const unsigned short* __restrict__ kfr,
            const unsigned short* __restrict__ vfr, float* __restrict__ out)
{
    __shared__ __align__(16) char Ks[2][16384];
    __shared__ __align__(16) char Pl[4][4608];

    const int tid  = threadIdx.x;
    const int lane = tid & 63;
    const int wid  = tid >> 6;
    const int lr   = lane & 15;
    const int lg   = lane >> 4;

    const int p  = (blockIdx.x & 7) * 64 + (blockIdx.x >> 3);
    const int bh = p >> 4;
    const int qt = p & 15;
    const int b  = bh >> 4;
    const int h  = bh & 15;
    const int q0 = qt * 128 + wid * 32;

    const unsigned short* qbase = qw  + (size_t)bh * (L_ * DH_);
    const unsigned short* kbase = kfr + (size_t)bh * (L_ * DH_);
    const unsigned short* vbase = vfr + (size_t)bh * (L_ * DH_);

    s16x8 qf[2][4];
    #pragma unroll
    for (int qs = 0; qs < 2; ++qs)
        #pragma unroll
        for (int kc = 0; kc < 4; ++kc)
            qf[qs][kc] = *reinterpret_cast<const s16x8*>(
                &qbase[(size_t)(q0 + qs * 16 + lr) * DH_ + kc * 32 + lg * 8]);

    s16x8 ones;
    #pragma unroll
    for (int i = 0; i < 8; ++i) ones[i] = (short)0x3F80;

    fp32x4 acc[2][8] = {};
    fp32x4 racc[2] = {};

    char* P = &Pl[wid][0];

    auto STAGE = [&](int buf, int t) {
        const unsigned short* g = kbase + (size_t)t * 8192;
        #pragma unroll
        for (int c = 0; c < 4; ++c)
            gld16(g + c * 2048 + tid * 8, &Ks[buf][c * 4096 + wid * 1024]);
    };

    STAGE(0, 0);
    __syncthreads();

    for (int t = 0; t < L_ / 64; ++t) {
        const int buf = t & 1;
        if (t + 1 < L_ / 64) STAGE(buf ^ 1, t + 1);

        s16x8 vv0[8], vv1[8];
        #pragma unroll
        for (int ds = 0; ds < 8; ++ds)
            vv0[ds] = *reinterpret_cast<const s16x8*>(
                &vbase[(size_t)t * 8192 + (0 * 8 + ds) * 512 + lane * 8]);

        fp32x4 s2[2][4] = {};
        __builtin_amdgcn_s_setprio(1);
        #pragma unroll
        for (int kvs = 0; kvs < 4; ++kvs)
            #pragma unroll
            for (int kc = 0; kc < 4; ++kc) {
                s16x8 kf = *reinterpret_cast<const s16x8*>(
                    Ks[buf] + (kvs * 4 + kc) * 1024 + lane * 16);
                s2[0][kvs] = MFMA(kf, qf[0][kc], s2[0][kvs]);
                s2[1][kvs] = MFMA(kf, qf[1][kc], s2[1][kvs]);
            }
        __builtin_amdgcn_s_setprio(0);

        #pragma unroll
        for (int qs = 0; qs < 2; ++qs)
            #pragma unroll
            for (int kvs = 0; kvs < 4; ++kvs) {
                float e0 = exp2_raw(s2[qs][kvs][0]);
                float e1 = exp2_raw(s2[qs][kvs][1]);
                float e2 = exp2_raw(s2[qs][kvs][2]);
                float e3 = exp2_raw(s2[qs][kvs][3]);
                uint2 pk;
                pk.x = cvtpk_bf16(e0, e1);
                pk.y = cvtpk_bf16(e2, e3);
                *reinterpret_cast<uint2*>(P + qs * 2304 + lr * 144 + kvs * 32 + lg * 8) = pk;
            }

        #pragma unroll
        for (int ds = 0; ds < 8; ++ds)
            vv1[ds] = *reinterpret_cast<const s16x8*>(
                &vbase[(size_t)t * 8192 + (1 * 8 + ds) * 512 + lane * 8]);

        __builtin_amdgcn_s_setprio(1);
        #pragma unroll
        for (int qs = 0; qs < 2; ++qs) {
            s16x8 pa0 = *reinterpret_cast<const s16x8*>(P + qs * 2304 + lr * 144 + 0 * 64 + lg * 16);
            s16x8 pa1 = *reinterpret_cast<const s16x8*>(P + qs * 2304 + lr * 144 + 1 * 64 + lg * 16);
            racc[qs] = MFMA(pa0, ones, racc[qs]);
            racc[qs] = MFMA(pa1, ones, racc[qs]);
            #pragma unroll
            for (int ds = 0; ds < 8; ++ds) {
                acc[qs][ds] = MFMA(pa0, vv0[ds], acc[qs][ds]);
                acc[qs][ds] = MFMA(pa1, vv1[ds], acc[qs][ds]);
            }
        }
        __builtin_amdgcn_s_setprio(0);

        __syncthreads();
    }

    #pragma unroll
    for (int qs = 0; qs < 2; ++qs) {
        float inv[4];
        #pragma unroll
        for (int r = 0; r < 4; ++r) inv[r] = 1.0f / racc[qs][r];
        #pragma unroll
        for (int ds = 0; ds < 8; ++ds)
            #pragma unroll
            for (int r = 0; r < 4; ++r)
                out[((size_t)(b * L_ + q0 + qs * 16 + lg * 4 + r)) * DIM_ + h * DH_ + ds * 16 + lr]
                    = acc[qs][ds][r] * inv[r];
    }
}

extern "C" void kernel_launch(void* const* d_in, const int* in_sizes, int n_in,
                              void* d_out, int out_size, void* d_ws, size_t ws_size,
                              hipStream_t stream) {
    const float* query = (const float*)d_in[0];
    const float* value = (const float*)d_in[1];
    const float* mask  = (const float*)d_in[2];
    const float* Wq    = (const float*)d_in[3];
    const float* Wk    = (const float*)d_in[4];
    const float* Wv    = (const float*)d_in[5];
    float* out = (float*)d_out;

    const size_t elems  = (size_t)B_ * H_ * L_ * DH_;  // 8388608
    const size_t welems = elems / 2;                   // 4194304
    unsigned short* q_ws = (unsigned short*)d_ws;
    unsigned short* k_ws = q_ws + elems;
    unsigned short* v_ws = k_ws + elems;

    unsigned short* qbf  = v_ws + elems;
    unsigned short* vbf  = qbf + elems;
    unsigned short* wqbf = vbf + elems;
    unsigned short* wkbf = wqbf + welems;
    unsigned short* wvbf = wkbf + welems;

    dim3 blk(256, 1, 1);

    cvt_all<<<dim3(2048, 1, 1), blk, 0, stream>>>(query, value, Wq, Wk, Wv,
                                                  qbf, vbf, wqbf, wkbf, wvbf);
    gemm_qkv8<<<dim3(384, 1, 1), dim3(512, 1, 1), 0, stream>>>(
        qbf, vbf, wqbf, wkbf, wvbf, mask, q_ws, k_ws, v_ws);

    attn_fused3<<<dim3(512, 1, 1), blk, 0, stream>>>(q_ws, k_ws, v_ws, out);
}

// Round 8
// 214.235 us; speedup vs baseline: 3.0977x; 1.0113x over previous
//
#include <hip/hip_runtime.h>
#include <hip/hip_bf16.h>
#include <stdint.h>

#define DIM_ 2048
#define L_   2048
#define B_   2
#define H_   16
#define DH_  128
#define NT_  32   // K tiles of 64

// scale folded into Wq: (1/sqrt(128)) * log2(e)  -> softmax uses raw v_exp_f32
#define QSCALE_ 0.12751743f

typedef __attribute__((ext_vector_type(4))) float fp32x4;
typedef __attribute__((ext_vector_type(8))) short s16x8;

__device__ __forceinline__ unsigned short bf16_rne(float f) {
    unsigned u = __builtin_bit_cast(unsigned, f);
    u += 0x7fffu + ((u >> 16) & 1u);
    return (unsigned short)(u >> 16);
}

__device__ __forceinline__ fp32x4 MFMA(s16x8 a, s16x8 b, fp32x4 c) {
    return __builtin_amdgcn_mfma_f32_16x16x32_bf16(a, b, c, 0, 0, 0);
}

__device__ __forceinline__ void gld16(const void* g, void* l) {
    auto gp = reinterpret_cast<const uint32_t __attribute__((address_space(1)))*>(
        reinterpret_cast<uintptr_t>(g));
    auto lp = reinterpret_cast<uint32_t __attribute__((address_space(3)))*>(
        reinterpret_cast<uintptr_t>(l));
    __builtin_amdgcn_global_load_lds(gp, lp, 16, 0, 0);
}

__device__ __forceinline__ float exp2_raw(float x) {
    float r; asm("v_exp_f32 %0, %1" : "=v"(r) : "v"(x)); return r;
}

__device__ __forceinline__ unsigned cvtpk_bf16(float a, float b) {
    unsigned r; asm("v_cvt_pk_bf16_f32 %0, %1, %2" : "=v"(r) : "v"(a), "v"(b)); return r;
}

// ---------------------------------------------------------------------------
// Merged f32->bf16 conversion: query | value | Wq(*QSCALE_) | Wk | Wv
// ---------------------------------------------------------------------------
__global__ void __launch_bounds__(256)
cvt_all(const float* __restrict__ query, const float* __restrict__ value,
        const float* __restrict__ Wq, const float* __restrict__ Wk,
        const float* __restrict__ Wv,
        unsigned short* __restrict__ qb, unsigned short* __restrict__ vb,
        unsigned short* __restrict__ wqb, unsigned short* __restrict__ wkb,
        unsigned short* __restrict__ wvb)
{
    const int total4 = 7340032;
    int i = blockIdx.x * 256 + threadIdx.x;
    const int stride = gridDim.x * 256;
    for (; i < total4; i += stride) {
        const float4* s; ushort4* d; int off; float sc = 1.0f;
        if (i < 2097152)      { s = (const float4*)query; d = (ushort4*)qb;  off = i; }
        else if (i < 4194304) { s = (const float4*)value; d = (ushort4*)vb;  off = i - 2097152; }
        else if (i < 5242880) { s = (const float4*)Wq;    d = (ushort4*)wqb; off = i - 4194304; sc = QSCALE_; }
        else if (i < 6291456) { s = (const float4*)Wk;    d = (ushort4*)wkb; off = i - 5242880; }
        else                  { s = (const float4*)Wv;    d = (ushort4*)wvb; off = i - 6291456; }
        float4 v = s[off];
        ushort4 o;
        o.x = bf16_rne(v.x * sc); o.y = bf16_rne(v.y * sc);
        o.z = bf16_rne(v.z * sc); o.w = bf16_rne(v.w * sc);
        d[off] = o;
    }
}

// ---------------------------------------------------------------------------
// 256x128 8-phase QKV GEMM. BK=64, 128B LDS rows, st_16x32 swizzle
// (byte ^= ((row>>2)&1)<<5) via pre-permuted gld16 source + XORed reads.
// Triple-buffered tiles; stage 2 ahead; vmcnt(6) at tile boundaries only.
// Grid 768 = 3 exact rounds of 256 blocks (1 block/CU at 144KB LDS).
// which 0: q[bh][l][d]*mask (QSCALE_ in Wq); 1: K frag-linear; 2: V frag-linear
// ---------------------------------------------------------------------------
__global__ void __launch_bounds__(512, 2)
gemm_qkv8(const unsigned short* __restrict__ qb, const unsigned short* __restrict__ vb,
          const unsigned short* __restrict__ wqb, const unsigned short* __restrict__ wkb,
          const unsigned short* __restrict__ wvb, const float* __restrict__ mask,
          unsigned short* __restrict__ q_ws, unsigned short* __restrict__ k_ws,
          unsigned short* __restrict__ v_ws)
{
    __shared__ __align__(16) char As_[3][32768];   // 256 rows x 128B
    __shared__ __align__(16) char Bs_[3][16384];   // 128 rows x 128B

    const int tid  = threadIdx.x;
    const int lane = tid & 63;
    const int wid  = tid >> 6;     // 0..7
    const int wm   = wid >> 1;     // 0..3 (M quarter, 64 rows)
    const int wn   = wid & 1;      // 0..1 (N half, 64 cols)
    const int lr   = lane & 15;
    const int lg   = lane >> 4;

    const int g     = (blockIdx.x & 7) * 96 + (blockIdx.x >> 3);  // XCD swizzle, 768%8==0
    const int which = g >> 8;
    const int rb    = g & 255;
    const int bm    = (rb >> 4) << 8;   // 16 M-tiles of 256
    const int bn    = (rb & 15) << 7;   // 16 N-tiles of 128

    const unsigned short* Xb = (which == 0) ? qb : vb;
    const unsigned short* Wb = (which == 0) ? wqb : (which == 1) ? wkb : wvb;

    // staging: LDS byte (per 8KB issue) = tid*16 -> row = tid>>3, chunk16 = tid&7.
    // source chunk pre-permuted: flip 32B-granule bit iff row bit2 (tid bit5) set.
    const int srow = tid >> 3;
    const int scol = ((tid & 7) ^ (((tid >> 5) & 1) << 1)) * 8;  // elements
    const unsigned short* gA = Xb + (size_t)(bm + srow) * DIM_ + scol;
    const unsigned short* gB = Wb + (size_t)(bn + srow) * DIM_ + scol;
    const int ldst = wid * 1024;

    // read-side: byte = row*128 + kk*64 + lg*16, then ^= ((row>>2)&1)<<5;
    // row = (64-mult) + lr -> (row>>2)&1 = (lr>>2)&1
    const int xsw  = ((lr >> 2) & 1) << 5;
    const int abase = wm * 8192 + lr * 128 + ((lg * 16) ^ xsw);
    const int bbase = wn * 8192 + lr * 128 + ((lg * 16) ^ xsw);

    fp32x4 acc[4][4] = {};

#define STGH1(BUF, T) do {                                                        \
    gld16(gA + (size_t)(T) * 64,                 &As_[BUF][ldst]);                \
    gld16(gA + (size_t)64 * DIM_ + (T) * 64,     &As_[BUF][8192 + ldst]);         \
    gld16(gB + (size_t)(T) * 64,                 &Bs_[BUF][ldst]);                \
} while (0)
#define STGH2(BUF, T) do {                                                        \
    gld16(gA + (size_t)128 * DIM_ + (T) * 64,    &As_[BUF][16384 + ldst]);        \
    gld16(gA + (size_t)192 * DIM_ + (T) * 64,    &As_[BUF][24576 + ldst]);        \
    gld16(gB + (size_t)64 * DIM_ + (T) * 64,     &Bs_[BUF][8192 + ldst]);         \
} while (0)

#define PH(AB, BB, KK, STG_STMT, WAIT_STMT) do {                                  \
    s16x8 fa0 = *reinterpret_cast<const s16x8*>(&(AB)[abase + (KK)*64]);          \
    s16x8 fa1 = *reinterpret_cast<const s16x8*>(&(AB)[abase + (KK)*64 + 2048]);   \
    s16x8 fa2 = *reinterpret_cast<const s16x8*>(&(AB)[abase + (KK)*64 + 4096]);   \
    s16x8 fa3 = *reinterpret_cast<const s16x8*>(&(AB)[abase + (KK)*64 + 6144]);   \
    s16x8 fb0 = *reinterpret_cast<const s16x8*>(&(BB)[bbase + (KK)*64]);          \
    s16x8 fb1 = *reinterpret_cast<const s16x8*>(&(BB)[bbase + (KK)*64 + 2048]);   \
    s16x8 fb2 = *reinterpret_cast<const s16x8*>(&(BB)[bbase + (KK)*64 + 4096]);   \
    s16x8 fb3 = *reinterpret_cast<const s16x8*>(&(BB)[bbase + (KK)*64 + 6144]);   \
    STG_STMT;                                                                     \
    __builtin_amdgcn_s_barrier();                                                 \
    asm volatile("s_waitcnt lgkmcnt(0)" ::: "memory");                            \
    __builtin_amdgcn_s_setprio(1);                                                \
    acc[0][0] = MFMA(fa0, fb0, acc[0][0]);                                        \
    acc[0][1] = MFMA(fa0, fb1, acc[0][1]);                                        \
    acc[0][2] = MFMA(fa0, fb2, acc[0][2]);                                        \
    acc[0][3] = MFMA(fa0, fb3, acc[0][3]);                                        \
    acc[1][0] = MFMA(fa1, fb0, acc[1][0]);                                        \
    acc[1][1] = MFMA(fa1, fb1, acc[1][1]);                                        \
    acc[1][2] = MFMA(fa1, fb2, acc[1][2]);                                        \
    acc[1][3] = MFMA(fa1, fb3, acc[1][3]);                                        \
    acc[2][0] = MFMA(fa2, fb0, acc[2][0]);                                        \
    acc[2][1] = MFMA(fa2, fb1, acc[2][1]);                                        \
    acc[2][2] = MFMA(fa2, fb2, acc[2][2]);                                        \
    acc[2][3] = MFMA(fa2, fb3, acc[2][3]);                                        \
    acc[3][0] = MFMA(fa3, fb0, acc[3][0]);                                        \
    acc[3][1] = MFMA(fa3, fb1, acc[3][1]);                                        \
    acc[3][2] = MFMA(fa3, fb2, acc[3][2]);                                        \
    acc[3][3] = MFMA(fa3, fb3, acc[3][3]);                                        \
    __builtin_amdgcn_s_setprio(0);                                                \
    WAIT_STMT;                                                                    \
    __builtin_amdgcn_s_barrier();                                                 \
} while (0)

#define W6 asm volatile("s_waitcnt vmcnt(6)" ::: "memory")
#define W0 asm volatile("s_waitcnt vmcnt(0)" ::: "memory")

    // prologue: S(0), S(1) fully (12 issues); vmcnt(6) -> S(0) landed
    STGH1(0, 0); STGH2(0, 0);
    STGH1(1, 1); STGH2(1, 1);
    W6;
    __builtin_amdgcn_s_barrier();

    for (int t = 0; t < NT_ - 2; ++t) {
        char* Ab = &As_[t % 3][0];
        char* Bb = &Bs_[t % 3][0];
        const int bnx = (t + 2) % 3;
        PH(Ab, Bb, 0, STGH1(bnx, t + 2), (void)0);
        PH(Ab, Bb, 1, STGH2(bnx, t + 2), W6);
    }
    {   // t = 30 (buf 0): no stages; drain S(31)
        char* Ab = &As_[0][0]; char* Bb = &Bs_[0][0];
        PH(Ab, Bb, 0, (void)0, (void)0);
        PH(Ab, Bb, 1, (void)0, W0);
    }
    {   // t = 31 (buf 1)
        char* Ab = &As_[1][0]; char* Bb = &Bs_[1][0];
        PH(Ab, Bb, 0, (void)0, (void)0);
        PH(Ab, Bb, 1, (void)0, (void)0);
    }

    // ---------------- epilogue ----------------
    const int bb = bm >> 11;
    const size_t bh0 = (size_t)(bb * H_) * (L_ * DH_);
    const int rbase = bm + wm * 64;
    const int cbase = bn + wn * 64;

    if (which == 2) {
        #pragma unroll
        for (int mf = 0; mf < 4; ++mf) {
            int l0 = (rbase + mf * 16 + lg * 4) & (L_ - 1);
            #pragma unroll
            for (int nf = 0; nf < 4; ++nf) {
                int dc = cbase + nf * 16 + lr;
                int h = dc >> 7, d = dc & 127;
                size_t off = bh0 + (size_t)h * (L_ * DH_)
                    + (size_t)(((l0 >> 5) * 8 + (d >> 4)) * 512
                    + ((d & 15) + (((l0 >> 3) & 3) << 4)) * 8 + (l0 & 7));
                ushort4 pk;
                pk.x = bf16_rne(acc[mf][nf][0]);
                pk.y = bf16_rne(acc[mf][nf][1]);
                pk.z = bf16_rne(acc[mf][nf][2]);
                pk.w = bf16_rne(acc[mf][nf][3]);
                *reinterpret_cast<ushort4*>(&v_ws[off]) = pk;
            }
        }
    } else if (which == 1) {
        #pragma unroll
        for (int mf = 0; mf < 4; ++mf)
            #pragma unroll
            for (int rr = 0; rr < 4; ++rr) {
                int l = (rbase + mf * 16 + lg * 4 + rr) & (L_ - 1);
                #pragma unroll
                for (int nf = 0; nf < 4; ++nf) {
                    int dc = cbase + nf * 16 + lr;
                    int h = dc >> 7, d = dc & 127;
                    size_t off = bh0 + (size_t)h * (L_ * DH_)
                        + (size_t)(((l >> 4) * 4 + (d >> 5)) * 512
                        + ((l & 15) + (((d >> 3) & 3) << 4)) * 8 + (d & 7));
                    k_ws[off] = bf16_rne(acc[mf][nf][rr]);
                }
            }
    } else {
        const float* mrow = mask + bb * L_;
        #pragma unroll
        for (int mf = 0; mf < 4; ++mf)
            #pragma unroll
            for (int rr = 0; rr < 4; ++rr) {
                int l = (rbase + mf * 16 + lg * 4 + rr) & (L_ - 1);
                float mvv = mrow[l];
                #pragma unroll
                for (int nf = 0; nf < 4; ++nf) {
                    int dc = cbase + nf * 16 + lr;
                    int h = dc >> 7, d = dc & 127;
                    q_ws[bh0 + (size_t)h * (L_ * DH_) + (size_t)l * DH_ + d]
                        = bf16_rne(acc[mf][nf][rr] * mvv);
                }
            }
    }
#undef STGH1
#undef STGH2
#undef PH
#undef W6
#undef W0
}

// ---------------------------------------------------------------------------
// Attention (unchanged): swapped QK^T, cvt_pk P-pack, ones-MFMA rowsums,
// mask pre-folded into Q, K via global_load_lds dbuf, V frag-linear direct.
// ---------------------------------------------------------------------------
__global__ void __launch_bounds__(256, 2)
attn_fused3(const unsigned short* __restrict__ qw, const unsigned short* __restrict__ kfr,
            const unsigned short* __restrict__ vfr, float* __restrict__ out)
{
    __shared__ __align__(16) char Ks[2][16384];
    __shared__ __align__(16) char Pl[4][4608];

    const int tid  = threadIdx.x;
    const int lane = tid & 63;
    const int wid  = tid >> 6;
    const int lr   = lane & 15;
    const int lg   = lane >> 4;

    const int p  = (blockIdx.x & 7) * 64 + (blockIdx.x >> 3);
    const int bh = p >> 4;
    const int qt = p & 15;
    const int b  = bh >> 4;
    const int h  = bh & 15;
    const int q0 = qt * 128 + wid * 32;

    const unsigned short* qbase = qw  + (size_t)bh * (L_ * DH_);
    const unsigned short* kbase = kfr + (size_t)bh * (L_ * DH_);
    const unsigned short* vbase = vfr + (size_t)bh * (L_ * DH_);

    s16x8 qf[2][4];
    #pragma unroll
    for (int qs = 0; qs < 2; ++qs)
        #pragma unroll
        for (int kc = 0; kc < 4; ++kc)
            qf[qs][kc] = *reinterpret_cast<const s16x8*>(
                &qbase[(size_t)(q0 + qs * 16 + lr) * DH_ + kc * 32 + lg * 8]);

    s16x8 ones;
    #pragma unroll
    for (int i = 0; i < 8; ++i) ones[i] = (short)0x3F80;

    fp32x4 acc[2][8] = {};
    fp32x4 racc[2] = {};

    char* P = &Pl[wid][0];

    auto STAGE = [&](int buf, int t) {
        const unsigned short* g = kbase + (size_t)t * 8192;
        #pragma unroll
        for (int c = 0; c < 4; ++c)
            gld16(g + c * 2048 + tid * 8, &Ks[buf][c * 4096 + wid * 1024]);
    };

    STAGE(0, 0);
    __syncthreads();

    for (int t = 0; t < L_ / 64; ++t) {
        const int buf = t & 1;
        if (t + 1 < L_ / 64) STAGE(buf ^ 1, t + 1);

        s16x8 vv0[8], vv1[8];
        #pragma unroll
        for (int ds = 0; ds < 8; ++ds)
            vv0[ds] = *reinterpret_cast<const s16x8*>(
                &vbase[(size_t)t * 8192 + (0 * 8 + ds) * 512 + lane * 8]);

        fp32x4 s2[2][4] = {};
        __builtin_amdgcn_s_setprio(1);
        #pragma unroll
        for (int kvs = 0; kvs < 4; ++kvs)
            #pragma unroll
            for (int kc = 0; kc < 4; ++kc) {
                s16x8 kf = *reinterpret_cast<const s16x8*>(
                    Ks[buf] + (kvs * 4 + kc) * 1024 + lane * 16);
                s2[0][kvs] = MFMA(kf, qf[0][kc], s2[0][kvs]);
                s2[1][kvs] = MFMA(kf, qf[1][kc], s2[1][kvs]);
            }
        __builtin_amdgcn_s_setprio(0);

        #pragma unroll
        for (int qs = 0; qs < 2; ++qs)
            #pragma unroll
            for (int kvs = 0; kvs < 4; ++kvs) {
                float e0 = exp2_raw(s2[qs][kvs][0]);
                float e1 = exp2_raw(s2[qs][kvs][1]);
                float e2 = exp2_raw(s2[qs][kvs][2]);
                float e3 = exp2_raw(s2[qs][kvs][3]);
                uint2 pk;
                pk.x = cvtpk_bf16(e0, e1);
                pk.y = cvtpk_bf16(e2, e3);
                *reinterpret_cast<uint2*>(P + qs * 2304 + lr * 144 + kvs * 32 + lg * 8) = pk;
            }

        #pragma unroll
        for (int ds = 0; ds < 8; ++ds)
            vv1[ds] = *reinterpret_cast<const s16x8*>(
                &vbase[(size_t)t * 8192 + (1 * 8 + ds) * 512 + lane * 8]);

        __builtin_amdgcn_s_setprio(1);
        #pragma unroll
        for (int qs = 0; qs < 2; ++qs) {
            s16x8 pa0 = *reinterpret_cast<const s16x8*>(P + qs * 2304 + lr * 144 + 0 * 64 + lg * 16);
            s16x8 pa1 = *reinterpret_cast<const s16x8*>(P + qs * 2304 + lr * 144 + 1 * 64 + lg * 16);
            racc[qs] = MFMA(pa0, ones, racc[qs]);
            racc[qs] = MFMA(pa1, ones, racc[qs]);
            #pragma unroll
            for (int ds = 0; ds < 8; ++ds) {
                acc[qs][ds] = MFMA(pa0, vv0[ds], acc[qs][ds]);
                acc[qs][ds] = MFMA(pa1, vv1[ds], acc[qs][ds]);
            }
        }
        __builtin_amdgcn_s_setprio(0);

        __syncthreads();
    }

    #pragma unroll
    for (int qs = 0; qs < 2; ++qs) {
        float inv[4];
        #pragma unroll
        for (int r = 0; r < 4; ++r) inv[r] = 1.0f / racc[qs][r];
        #pragma unroll
        for (int ds = 0; ds < 8; ++ds)
            #pragma unroll
            for (int r = 0; r < 4; ++r)
                out[((size_t)(b * L_ + q0 + qs * 16 + lg * 4 + r)) * DIM_ + h * DH_ + ds * 16 + lr]
                    = acc[qs][ds][r] * inv[r];
    }
}

extern "C" void kernel_launch(void* const* d_in, const int* in_sizes, int n_in,
                              void* d_out, int out_size, void* d_ws, size_t ws_size,
                              hipStream_t stream) {
    const float* query = (const float*)d_in[0];
    const float* value = (const float*)d_in[1];
    const float* mask  = (const float*)d_in[2];
    const float* Wq    = (const float*)d_in[3];
    const float* Wk    = (const float*)d_in[4];
    const float* Wv    = (const float*)d_in[5];
    float* out = (float*)d_out;

    const size_t elems  = (size_t)B_ * H_ * L_ * DH_;  // 8388608
    const size_t welems = elems / 2;                   // 4194304
    unsigned short* q_ws = (unsigned short*)d_ws;
    unsigned short* k_ws = q_ws + elems;
    unsigned short* v_ws = k_ws + elems;

    unsigned short* qbf  = v_ws + elems;
    unsigned short* vbf  = qbf + elems;
    unsigned short* wqbf = vbf + elems;
    unsigned short* wkbf = wqbf + welems;
    unsigned short* wvbf = wkbf + welems;

    dim3 blk(256, 1, 1);

    cvt_all<<<dim3(2048, 1, 1), blk, 0, stream>>>(query, value, Wq, Wk, Wv,
                                                  qbf, vbf, wqbf, wkbf, wvbf);
    gemm_qkv8<<<dim3(768, 1, 1), dim3(512, 1, 1), 0, stream>>>(
        qbf, vbf, wqbf, wkbf, wvbf, mask, q_ws, k_ws, v_ws);

    attn_fused3<<<dim3(512, 1, 1), blk, 0, stream>>>(q_ws, k_ws, v_ws, out);
}

// Round 9
// 203.316 us; speedup vs baseline: 3.2641x; 1.0537x over previous
//
#include <hip/hip_runtime.h>
#include <hip/hip_bf16.h>
#include <stdint.h>

#define DIM_ 2048
#define L_   2048
#define B_   2
#define H_   16
#define DH_  128
#define NT_  32   // K tiles of 64

// scale folded into Wq: (1/sqrt(128)) * log2(e)  -> softmax uses raw v_exp_f32
#define QSCALE_ 0.12751743f

typedef __attribute__((ext_vector_type(4))) float fp32x4;
typedef __attribute__((ext_vector_type(8))) short s16x8;

__device__ __forceinline__ unsigned short bf16_rne(float f) {
    unsigned u = __builtin_bit_cast(unsigned, f);
    u += 0x7fffu + ((u >> 16) & 1u);
    return (unsigned short)(u >> 16);
}

__device__ __forceinline__ fp32x4 MFMA(s16x8 a, s16x8 b, fp32x4 c) {
    return __builtin_amdgcn_mfma_f32_16x16x32_bf16(a, b, c, 0, 0, 0);
}

__device__ __forceinline__ void gld16(const void* g, void* l) {
    auto gp = reinterpret_cast<const uint32_t __attribute__((address_space(1)))*>(
        reinterpret_cast<uintptr_t>(g));
    auto lp = reinterpret_cast<uint32_t __attribute__((address_space(3)))*>(
        reinterpret_cast<uintptr_t>(l));
    __builtin_amdgcn_global_load_lds(gp, lp, 16, 0, 0);
}

__device__ __forceinline__ float exp2_raw(float x) {
    float r; asm("v_exp_f32 %0, %1" : "=v"(r) : "v"(x)); return r;
}

__device__ __forceinline__ unsigned cvtpk_bf16(float a, float b) {
    unsigned r; asm("v_cvt_pk_bf16_f32 %0, %1, %2" : "=v"(r) : "v"(a), "v"(b)); return r;
}

// ---------------------------------------------------------------------------
// Merged f32->bf16 conversion: query | value | Wq(*QSCALE_) | Wk | Wv
// ---------------------------------------------------------------------------
__global__ void __launch_bounds__(256)
cvt_all(const float* __restrict__ query, const float* __restrict__ value,
        const float* __restrict__ Wq, const float* __restrict__ Wk,
        const float* __restrict__ Wv,
        unsigned short* __restrict__ qb, unsigned short* __restrict__ vb,
        unsigned short* __restrict__ wqb, unsigned short* __restrict__ wkb,
        unsigned short* __restrict__ wvb)
{
    const int total4 = 7340032;
    int i = blockIdx.x * 256 + threadIdx.x;
    const int stride = gridDim.x * 256;
    for (; i < total4; i += stride) {
        const float4* s; ushort4* d; int off; float sc = 1.0f;
        if (i < 2097152)      { s = (const float4*)query; d = (ushort4*)qb;  off = i; }
        else if (i < 4194304) { s = (const float4*)value; d = (ushort4*)vb;  off = i - 2097152; }
        else if (i < 5242880) { s = (const float4*)Wq;    d = (ushort4*)wqb; off = i - 4194304; sc = QSCALE_; }
        else if (i < 6291456) { s = (const float4*)Wk;    d = (ushort4*)wkb; off = i - 5242880; }
        else                  { s = (const float4*)Wv;    d = (ushort4*)wvb; off = i - 6291456; }
        float4 v = s[off];
        ushort4 o;
        o.x = bf16_rne(v.x * sc); o.y = bf16_rne(v.y * sc);
        o.z = bf16_rne(v.z * sc); o.w = bf16_rne(v.w * sc);
        d[off] = o;
    }
}

// ---------------------------------------------------------------------------
// 256x128 QKV GEMM, fused-tile schedule: triple-buffered 48KB K-tiles,
// ONE barrier + one counted vmcnt(6) per tile (stages run 2 tiles ahead).
// LDS rows 128B; full 3-bit chunk swizzle: chunk ^= (row&7) applied on the
// gld16 SOURCE (per-lane global addr) and on the ds_read address (rule #21).
// Grid 768 = 3 exact rounds of 256 blocks (1 block/CU at 144KB LDS).
// which 0: q[bh][l][d]*mask (QSCALE_ in Wq); 1: K frag-linear; 2: V frag-linear
// ---------------------------------------------------------------------------
__global__ void __launch_bounds__(512, 2)
gemm_qkv8(const unsigned short* __restrict__ qb, const unsigned short* __restrict__ vb,
          const unsigned short* __restrict__ wqb, const unsigned short* __restrict__ wkb,
          const unsigned short* __restrict__ wvb, const float* __restrict__ mask,
          unsigned short* __restrict__ q_ws, unsigned short* __restrict__ k_ws,
          unsigned short* __restrict__ v_ws)
{
    __shared__ __align__(16) char As_[3][32768];   // 256 rows x 128B
    __shared__ __align__(16) char Bs_[3][16384];   // 128 rows x 128B

    const int tid  = threadIdx.x;
    const int lane = tid & 63;
    const int wid  = tid >> 6;     // 0..7
    const int wm   = wid >> 1;     // 0..3 (M quarter, 64 rows)
    const int wn   = wid & 1;      // 0..1 (N half, 64 cols)
    const int lr   = lane & 15;
    const int lg   = lane >> 4;

    const int g     = (blockIdx.x & 7) * 96 + (blockIdx.x >> 3);  // XCD swizzle, 768%8==0
    const int which = g >> 8;
    const int rb    = g & 255;
    const int bm    = (rb >> 4) << 8;   // 16 M-tiles of 256
    const int bn    = (rb & 15) << 7;   // 16 N-tiles of 128

    const unsigned short* Xb = (which == 0) ? qb : vb;
    const unsigned short* Wb = (which == 0) ? wqb : (which == 1) ? wkb : wvb;

    // staging: per 8KB issue, thread tid covers LDS byte tid*16 ->
    // row = tid>>3, chunk16 = tid&7. Source chunk pre-permuted by the full
    // 3-bit swizzle: srcchunk = (tid&7) ^ (row&7).
    const int srow = tid >> 3;
    const int scol = ((tid & 7) ^ ((tid >> 3) & 7)) * 8;  // elements
    const unsigned short* gA = Xb + (size_t)(bm + srow) * DIM_ + scol;
    const unsigned short* gB = Wb + (size_t)(bn + srow) * DIM_ + scol;
    const int ldst = wid * 1024;

    // read-side: byte = row*128 + (((kk<<6)|(lg<<4)) ^ ((row&7)<<4)); row&7==lr&7
    const int r7   = (lr & 7) << 4;
    const int arow = (wm * 64 + lr) * 128;
    const int brow = (wn * 64 + lr) * 128;
    const int off0 = (lg << 4) ^ r7;          // kk=0
    const int off1 = (64 | (lg << 4)) ^ r7;   // kk=1

    fp32x4 acc[4][4] = {};

#define STG6(SA, SB, T) do {                                                      \
    gld16(gA + (size_t)(T) * 64,                 (SA) + ldst);                    \
    gld16(gA + (size_t)64  * DIM_ + (T) * 64,    (SA) + 8192  + ldst);            \
    gld16(gA + (size_t)128 * DIM_ + (T) * 64,    (SA) + 16384 + ldst);            \
    gld16(gA + (size_t)192 * DIM_ + (T) * 64,    (SA) + 24576 + ldst);            \
    gld16(gB + (size_t)(T) * 64,                 (SB) + ldst);                    \
    gld16(gB + (size_t)64  * DIM_ + (T) * 64,    (SB) + 8192  + ldst);            \
} while (0)

    // prologue: S(0), S(1) (12 issues); vmcnt(6) -> S(0) landed
    STG6(&As_[0][0], &Bs_[0][0], 0);
    STG6(&As_[1][0], &Bs_[1][0], 1);
    asm volatile("s_waitcnt vmcnt(6)" ::: "memory");
    __builtin_amdgcn_s_barrier();

    for (int t = 0; t < NT_; ++t) {
        char* Ab = &As_[t % 3][0];
        char* Bb = &Bs_[t % 3][0];
        if (t < NT_ - 2) {
            char* An = &As_[(t + 2) % 3][0];
            char* Bn = &Bs_[(t + 2) % 3][0];
            STG6(An, Bn, t + 2);
        }

        s16x8 fa0[4], fa1[4], fb0[4], fb1[4];
        #pragma unroll
        for (int mi = 0; mi < 4; ++mi) {
            fa0[mi] = *reinterpret_cast<const s16x8*>(&Ab[arow + mi * 2048 + off0]);
            fa1[mi] = *reinterpret_cast<const s16x8*>(&Ab[arow + mi * 2048 + off1]);
        }
        #pragma unroll
        for (int nf = 0; nf < 4; ++nf) {
            fb0[nf] = *reinterpret_cast<const s16x8*>(&Bb[brow + nf * 2048 + off0]);
            fb1[nf] = *reinterpret_cast<const s16x8*>(&Bb[brow + nf * 2048 + off1]);
        }

        __builtin_amdgcn_s_setprio(1);
        #pragma unroll
        for (int mi = 0; mi < 4; ++mi)
            #pragma unroll
            for (int nf = 0; nf < 4; ++nf)
                acc[mi][nf] = MFMA(fa0[mi], fb0[nf], acc[mi][nf]);
        #pragma unroll
        for (int mi = 0; mi < 4; ++mi)
            #pragma unroll
            for (int nf = 0; nf < 4; ++nf)
                acc[mi][nf] = MFMA(fa1[mi], fb1[nf], acc[mi][nf]);
        __builtin_amdgcn_s_setprio(0);

        if (t < NT_ - 2) {
            asm volatile("s_waitcnt vmcnt(6)" ::: "memory");
            __builtin_amdgcn_s_barrier();
        } else if (t == NT_ - 2) {
            asm volatile("s_waitcnt vmcnt(0)" ::: "memory");
            __builtin_amdgcn_s_barrier();
        }
    }

    // ---------------- epilogue ----------------
    const int bb = bm >> 11;
    const size_t bh0 = (size_t)(bb * H_) * (L_ * DH_);
    const int rbase = bm + wm * 64;
    const int cbase = bn + wn * 64;

    if (which == 2) {
        #pragma unroll
        for (int mf = 0; mf < 4; ++mf) {
            int l0 = (rbase + mf * 16 + lg * 4) & (L_ - 1);
            #pragma unroll
            for (int nf = 0; nf < 4; ++nf) {
                int dc = cbase + nf * 16 + lr;
                int h = dc >> 7, d = dc & 127;
                size_t off = bh0 + (size_t)h * (L_ * DH_)
                    + (size_t)(((l0 >> 5) * 8 + (d >> 4)) * 512
                    + ((d & 15) + (((l0 >> 3) & 3) << 4)) * 8 + (l0 & 7));
                ushort4 pk;
                pk.x = bf16_rne(acc[mf][nf][0]);
                pk.y = bf16_rne(acc[mf][nf][1]);
                pk.z = bf16_rne(acc[mf][nf][2]);
                pk.w = bf16_rne(acc[mf][nf][3]);
                *reinterpret_cast<ushort4*>(&v_ws[off]) = pk;
            }
        }
    } else if (which == 1) {
        #pragma unroll
        for (int mf = 0; mf < 4; ++mf)
            #pragma unroll
            for (int rr = 0; rr < 4; ++rr) {
                int l = (rbase + mf * 16 + lg * 4 + rr) & (L_ - 1);
                #pragma unroll
                for (int nf = 0; nf < 4; ++nf) {
                    int dc = cbase + nf * 16 + lr;
                    int h = dc >> 7, d = dc & 127;
                    size_t off = bh0 + (size_t)h * (L_ * DH_)
                        + (size_t)(((l >> 4) * 4 + (d >> 5)) * 512
                        + ((l & 15) + (((d >> 3) & 3) << 4)) * 8 + (d & 7));
                    k_ws[off] = bf16_rne(acc[mf][nf][rr]);
                }
            }
    } else {
        const float* mrow = mask + bb * L_;
        #pragma unroll
        for (int mf = 0; mf < 4; ++mf)
            #pragma unroll
            for (int rr = 0; rr < 4; ++rr) {
                int l = (rbase + mf * 16 + lg * 4 + rr) & (L_ - 1);
                float mvv = mrow[l];
                #pragma unroll
                for (int nf = 0; nf < 4; ++nf) {
                    int dc = cbase + nf * 16 + lr;
                    int h = dc >> 7, d = dc & 127;
                    q_ws[bh0 + (size_t)h * (L_ * DH_) + (size_t)l * DH_ + d]
                        = bf16_rne(acc[mf][nf][rr] * mvv);
                }
            }
    }
#undef STG6
}

// ---------------------------------------------------------------------------
// Attention (unchanged): swapped QK^T, cvt_pk P-pack, ones-MFMA rowsums,
// mask pre-folded into Q, K via global_load_lds dbuf, V frag-linear direct.
// ---------------------------------------------------------------------------
__global__ void __launch_bounds__(256, 2)
attn_fused3(const unsigned short* __restrict__ qw, const unsigned short* __restrict__ kfr,
            const unsigned short* __restrict__ vfr, float* __restrict__ out)
{
    __shared__ __align__(16) char Ks[2][16384];
    __shared__ __align__(16) char Pl[4][4608];

    const int tid  = threadIdx.x;
    const int lane = tid & 63;
    const int wid  = tid >> 6;
    const int lr   = lane & 15;
    const int lg   = lane >> 4;

    const int p  = (blockIdx.x & 7) * 64 + (blockIdx.x >> 3);
    const int bh = p >> 4;
    const int qt = p & 15;
    const int b  = bh >> 4;
    const int h  = bh & 15;
    const int q0 = qt * 128 + wid * 32;

    const unsigned short* qbase = qw  + (size_t)bh * (L_ * DH_);
    const unsigned short* kbase = kfr + (size_t)bh * (L_ * DH_);
    const unsigned short* vbase = vfr + (size_t)bh * (L_ * DH_);

    s16x8 qf[2][4];
    #pragma unroll
    for (int qs = 0; qs < 2; ++qs)
        #pragma unroll
        for (int kc = 0; kc < 4; ++kc)
            qf[qs][kc] = *reinterpret_cast<const s16x8*>(
                &qbase[(size_t)(q0 + qs * 16 + lr) * DH_ + kc * 32 + lg * 8]);

    s16x8 ones;
    #pragma unroll
    for (int i = 0; i < 8; ++i) ones[i] = (short)0x3F80;

    fp32x4 acc[2][8] = {};
    fp32x4 racc[2] = {};

    char* P = &Pl[wid][0];

    auto STAGE = [&](int buf, int t) {
        const unsigned short* g = kbase + (size_t)t * 8192;
        #pragma unroll
        for (int c = 0; c < 4; ++c)
            gld16(g + c * 2048 + tid * 8, &Ks[buf][c * 4096 + wid * 1024]);
    };

    STAGE(0, 0);
    __syncthreads();

    for (int t = 0; t < L_ / 64; ++t) {
        const int buf = t & 1;
        if (t + 1 < L_ / 64) STAGE(buf ^ 1, t + 1);

        s16x8 vv0[8], vv1[8];
        #pragma unroll
        for (int ds = 0; ds < 8; ++ds)
            vv0[ds] = *reinterpret_cast<const s16x8*>(
                &vbase[(size_t)t * 8192 + (0 * 8 + ds) * 512 + lane * 8]);

        fp32x4 s2[2][4] = {};
        __builtin_amdgcn_s_setprio(1);
        #pragma unroll
        for (int kvs = 0; kvs < 4; ++kvs)
            #pragma unroll
            for (int kc = 0; kc < 4; ++kc) {
                s16x8 kf = *reinterpret_cast<const s16x8*>(
                    Ks[buf] + (kvs * 4 + kc) * 1024 + lane * 16);
                s2[0][kvs] = MFMA(kf, qf[0][kc], s2[0][kvs]);
                s2[1][kvs] = MFMA(kf, qf[1][kc], s2[1][kvs]);
            }
        __builtin_amdgcn_s_setprio(0);

        #pragma unroll
        for (int qs = 0; qs < 2; ++qs)
            #pragma unroll
            for (int kvs = 0; kvs < 4; ++kvs) {
                float e0 = exp2_raw(s2[qs][kvs][0]);
                float e1 = exp2_raw(s2[qs][kvs][1]);
                float e2 = exp2_raw(s2[qs][kvs][2]);
                float e3 = exp2_raw(s2[qs][kvs][3]);
                uint2 pk;
                pk.x = cvtpk_bf16(e0, e1);
                pk.y = cvtpk_bf16(e2, e3);
                *reinterpret_cast<uint2*>(P + qs * 2304 + lr * 144 + kvs * 32 + lg * 8) = pk;
            }

        #pragma unroll
        for (int ds = 0; ds < 8; ++ds)
            vv1[ds] = *reinterpret_cast<const s16x8*>(
                &vbase[(size_t)t * 8192 + (1 * 8 + ds) * 512 + lane * 8]);

        __builtin_amdgcn_s_setprio(1);
        #pragma unroll
        for (int qs = 0; qs < 2; ++qs) {
            s16x8 pa0 = *reinterpret_cast<const s16x8*>(P + qs * 2304 + lr * 144 + 0 * 64 + lg * 16);
            s16x8 pa1 = *reinterpret_cast<const s16x8*>(P + qs * 2304 + lr * 144 + 1 * 64 + lg * 16);
            racc[qs] = MFMA(pa0, ones, racc[qs]);
            racc[qs] = MFMA(pa1, ones, racc[qs]);
            #pragma unroll
            for (int ds = 0; ds < 8; ++ds) {
                acc[qs][ds] = MFMA(pa0, vv0[ds], acc[qs][ds]);
                acc[qs][ds] = MFMA(pa1, vv1[ds], acc[qs][ds]);
            }
        }
        __builtin_amdgcn_s_setprio(0);

        __syncthreads();
    }

    #pragma unroll
    for (int qs = 0; qs < 2; ++qs) {
        float inv[4];
        #pragma unroll
        for (int r = 0; r < 4; ++r) inv[r] = 1.0f / racc[qs][r];
        #pragma unroll
        for (int ds = 0; ds < 8; ++ds)
            #pragma unroll
            for (int r = 0; r < 4; ++r)
                out[((size_t)(b * L_ + q0 + qs * 16 + lg * 4 + r)) * DIM_ + h * DH_ + ds * 16 + lr]
                    = acc[qs][ds][r] * inv[r];
    }
}

extern "C" void kernel_launch(void* const* d_in, const int* in_sizes, int n_in,
                              void* d_out, int out_size, void* d_ws, size_t ws_size,
                              hipStream_t stream) {
    const float* query = (const float*)d_in[0];
    const float* value = (const float*)d_in[1];
    const float* mask  = (const float*)d_in[2];
    const float* Wq    = (const float*)d_in[3];
    const float* Wk    = (const float*)d_in[4];
    const float* Wv    = (const float*)d_in[5];
    float* out = (float*)d_out;

    const size_t elems  = (size_t)B_ * H_ * L_ * DH_;  // 8388608
    const size_t welems = elems / 2;                   // 4194304
    unsigned short* q_ws = (unsigned short*)d_ws;
    unsigned short* k_ws = q_ws + elems;
    unsigned short* v_ws = k_ws + elems;

    unsigned short* qbf  = v_ws + elems;
    unsigned short* vbf  = qbf + elems;
    unsigned short* wqbf = vbf + elems;
    unsigned short* wkbf = wqbf + welems;
    unsigned short* wvbf = wkbf + welems;

    dim3 blk(256, 1, 1);

    cvt_all<<<dim3(2048, 1, 1), blk, 0, stream>>>(query, value, Wq, Wk, Wv,
                                                  qbf, vbf, wqbf, wkbf, wvbf);
    gemm_qkv8<<<dim3(768, 1, 1), dim3(512, 1, 1), 0, stream>>>(
        qbf, vbf, wqbf, wkbf, wvbf, mask, q_ws, k_ws, v_ws);

    attn_fused3<<<dim3(512, 1, 1), blk, 0, stream>>>(q_ws, k_ws, v_ws, out);
}

// Round 10
// 194.713 us; speedup vs baseline: 3.4083x; 1.0442x over previous
//
#include <hip/hip_runtime.h>
#include <hip/hip_bf16.h>
#include <stdint.h>

#define DIM_ 2048
#define L_   2048
#define B_   2
#define H_   16
#define DH_  128
#define NT_  32   // K tiles of 64

// scale folded into Wq: (1/sqrt(128)) * log2(e)  -> softmax uses raw v_exp_f32
#define QSCALE_ 0.12751743f

typedef __attribute__((ext_vector_type(4))) float fp32x4;
typedef __attribute__((ext_vector_type(8))) short s16x8;

__device__ __forceinline__ unsigned short bf16_rne(float f) {
    unsigned u = __builtin_bit_cast(unsigned, f);
    u += 0x7fffu + ((u >> 16) & 1u);
    return (unsigned short)(u >> 16);
}

__device__ __forceinline__ fp32x4 MFMA(s16x8 a, s16x8 b, fp32x4 c) {
    return __builtin_amdgcn_mfma_f32_16x16x32_bf16(a, b, c, 0, 0, 0);
}

__device__ __forceinline__ void gld16(const void* g, void* l) {
    auto gp = reinterpret_cast<const uint32_t __attribute__((address_space(1)))*>(
        reinterpret_cast<uintptr_t>(g));
    auto lp = reinterpret_cast<uint32_t __attribute__((address_space(3)))*>(
        reinterpret_cast<uintptr_t>(l));
    __builtin_amdgcn_global_load_lds(gp, lp, 16, 0, 0);
}

__device__ __forceinline__ float exp2_raw(float x) {
    float r; asm("v_exp_f32 %0, %1" : "=v"(r) : "v"(x)); return r;
}

__device__ __forceinline__ unsigned cvtpk_bf16(float a, float b) {
    unsigned r; asm("v_cvt_pk_bf16_f32 %0, %1, %2" : "=v"(r) : "v"(a), "v"(b)); return r;
}

// ---------------------------------------------------------------------------
// Merged f32->bf16 conversion: query | value | Wq(*QSCALE_) | Wk | Wv
// ---------------------------------------------------------------------------
__global__ void __launch_bounds__(256)
cvt_all(const float* __restrict__ query, const float* __restrict__ value,
        const float* __restrict__ Wq, const float* __restrict__ Wk,
        const float* __restrict__ Wv,
        unsigned short* __restrict__ qb, unsigned short* __restrict__ vb,
        unsigned short* __restrict__ wqb, unsigned short* __restrict__ wkb,
        unsigned short* __restrict__ wvb)
{
    const int total4 = 7340032;
    int i = blockIdx.x * 256 + threadIdx.x;
    const int stride = gridDim.x * 256;
    for (; i < total4; i += stride) {
        const float4* s; ushort4* d; int off; float sc = 1.0f;
        if (i < 2097152)      { s = (const float4*)query; d = (ushort4*)qb;  off = i; }
        else if (i < 4194304) { s = (const float4*)value; d = (ushort4*)vb;  off = i - 2097152; }
        else if (i < 5242880) { s = (const float4*)Wq;    d = (ushort4*)wqb; off = i - 4194304; sc = QSCALE_; }
        else if (i < 6291456) { s = (const float4*)Wk;    d = (ushort4*)wkb; off = i - 5242880; }
        else                  { s = (const float4*)Wv;    d = (ushort4*)wvb; off = i - 6291456; }
        float4 v = s[off];
        ushort4 o;
        o.x = bf16_rne(v.x * sc); o.y = bf16_rne(v.y * sc);
        o.z = bf16_rne(v.z * sc); o.w = bf16_rne(v.w * sc);
        d[off] = o;
    }
}

// ---------------------------------------------------------------------------
// Q projection GEMM (round-9 structure): 256x128, triple-buffered, one
// barrier + counted vmcnt(6) per tile, full 3-bit both-sides chunk swizzle.
// Grid 256 = 1 exact round. Mask folded into epilogue.
// ---------------------------------------------------------------------------
__global__ void __launch_bounds__(512, 2)
qgemm(const unsigned short* __restrict__ qb, const unsigned short* __restrict__ wqb,
      const float* __restrict__ mask, unsigned short* __restrict__ q_ws)
{
    __shared__ __align__(16) char As_[3][32768];   // 256 rows x 128B
    __shared__ __align__(16) char Bs_[3][16384];   // 128 rows x 128B

    const int tid  = threadIdx.x;
    const int lane = tid & 63;
    const int wid  = tid >> 6;
    const int wm   = wid >> 1;
    const int wn   = wid & 1;
    const int lr   = lane & 15;
    const int lg   = lane >> 4;

    const int rb = (blockIdx.x & 7) * 32 + (blockIdx.x >> 3);  // XCD swizzle, 256%8==0
    const int bm = (rb >> 4) << 8;
    const int bn = (rb & 15) << 7;

    const int srow = tid >> 3;
    const int scol = ((tid & 7) ^ ((tid >> 3) & 7)) * 8;
    const unsigned short* gA = qb  + (size_t)(bm + srow) * DIM_ + scol;
    const unsigned short* gB = wqb + (size_t)(bn + srow) * DIM_ + scol;
    const int ldst = wid * 1024;

    const int r7   = (lr & 7) << 4;
    const int arow = (wm * 64 + lr) * 128;
    const int brow = (wn * 64 + lr) * 128;
    const int off0 = (lg << 4) ^ r7;
    const int off1 = (64 | (lg << 4)) ^ r7;

    fp32x4 acc[4][4] = {};

#define STG6(SA, SB, T) do {                                                      \
    gld16(gA + (size_t)(T) * 64,                 (SA) + ldst);                    \
    gld16(gA + (size_t)64  * DIM_ + (T) * 64,    (SA) + 8192  + ldst);            \
    gld16(gA + (size_t)128 * DIM_ + (T) * 64,    (SA) + 16384 + ldst);            \
    gld16(gA + (size_t)192 * DIM_ + (T) * 64,    (SA) + 24576 + ldst);            \
    gld16(gB + (size_t)(T) * 64,                 (SB) + ldst);                    \
    gld16(gB + (size_t)64  * DIM_ + (T) * 64,    (SB) + 8192  + ldst);            \
} while (0)

    STG6(&As_[0][0], &Bs_[0][0], 0);
    STG6(&As_[1][0], &Bs_[1][0], 1);
    asm volatile("s_waitcnt vmcnt(6)" ::: "memory");
    __builtin_amdgcn_s_barrier();

    for (int t = 0; t < NT_; ++t) {
        char* Ab = &As_[t % 3][0];
        char* Bb = &Bs_[t % 3][0];
        if (t < NT_ - 2) {
            STG6(&As_[(t + 2) % 3][0], &Bs_[(t + 2) % 3][0], t + 2);
        }

        s16x8 fa0[4], fa1[4], fb0[4], fb1[4];
        #pragma unroll
        for (int mi = 0; mi < 4; ++mi) {
            fa0[mi] = *reinterpret_cast<const s16x8*>(&Ab[arow + mi * 2048 + off0]);
            fa1[mi] = *reinterpret_cast<const s16x8*>(&Ab[arow + mi * 2048 + off1]);
        }
        #pragma unroll
        for (int nf = 0; nf < 4; ++nf) {
            fb0[nf] = *reinterpret_cast<const s16x8*>(&Bb[brow + nf * 2048 + off0]);
            fb1[nf] = *reinterpret_cast<const s16x8*>(&Bb[brow + nf * 2048 + off1]);
        }

        __builtin_amdgcn_s_setprio(1);
        #pragma unroll
        for (int mi = 0; mi < 4; ++mi)
            #pragma unroll
            for (int nf = 0; nf < 4; ++nf)
                acc[mi][nf] = MFMA(fa0[mi], fb0[nf], acc[mi][nf]);
        #pragma unroll
        for (int mi = 0; mi < 4; ++mi)
            #pragma unroll
            for (int nf = 0; nf < 4; ++nf)
                acc[mi][nf] = MFMA(fa1[mi], fb1[nf], acc[mi][nf]);
        __builtin_amdgcn_s_setprio(0);

        if (t < NT_ - 2) {
            asm volatile("s_waitcnt vmcnt(6)" ::: "memory");
            __builtin_amdgcn_s_barrier();
        } else if (t == NT_ - 2) {
            asm volatile("s_waitcnt vmcnt(0)" ::: "memory");
            __builtin_amdgcn_s_barrier();
        }
    }
#undef STG6

    const int bb = bm >> 11;
    const size_t bh0 = (size_t)(bb * H_) * (L_ * DH_);
    const int rbase = bm + wm * 64;
    const int cbase = bn + wn * 64;
    const float* mrow = mask + bb * L_;

    #pragma unroll
    for (int mf = 0; mf < 4; ++mf)
        #pragma unroll
        for (int rr = 0; rr < 4; ++rr) {
            int l = (rbase + mf * 16 + lg * 4 + rr) & (L_ - 1);
            float mvv = mrow[l];
            #pragma unroll
            for (int nf = 0; nf < 4; ++nf) {
                int dc = cbase + nf * 16 + lr;
                int h = dc >> 7, d = dc & 127;
                q_ws[bh0 + (size_t)h * (L_ * DH_) + (size_t)l * DH_ + d]
                    = bf16_rne(acc[mf][nf][rr] * mvv);
            }
        }
}

// ---------------------------------------------------------------------------
// Fused K+V projection GEMM: A (value) staged ONCE per tile, both Wk and Wv
// B-tiles staged; 64 MFMA per 24 ds_reads per wave per K-tile (2.67 ratio).
// 256x128 tile; A dbuf 2x32KB + Bk/Bv dbuf 2x16KB each = 128KB LDS.
// 2-phase schedule: stage(t+1) first, compute, vmcnt(0) (hidden), barrier.
// Grid 256 = 1 exact round. Epilogues: K and V fragment-linear layouts.
// ---------------------------------------------------------------------------
__global__ void __launch_bounds__(512, 2)
kvgemm(const unsigned short* __restrict__ vb, const unsigned short* __restrict__ wkb,
       const unsigned short* __restrict__ wvb,
       unsigned short* __restrict__ k_ws, unsigned short* __restrict__ v_ws)
{
    __shared__ __align__(16) char As_[2][32768];    // 256 rows x 128B
    __shared__ __align__(16) char Bks_[2][16384];   // 128 rows x 128B
    __shared__ __align__(16) char Bvs_[2][16384];

    const int tid  = threadIdx.x;
    const int lane = tid & 63;
    const int wid  = tid >> 6;
    const int wm   = wid >> 1;
    const int wn   = wid & 1;
    const int lr   = lane & 15;
    const int lg   = lane >> 4;

    const int rb = (blockIdx.x & 7) * 32 + (blockIdx.x >> 3);  // XCD swizzle
    const int bm = (rb >> 4) << 8;
    const int bn = (rb & 15) << 7;

    const int srow = tid >> 3;
    const int scol = ((tid & 7) ^ ((tid >> 3) & 7)) * 8;
    const unsigned short* gA  = vb  + (size_t)(bm + srow) * DIM_ + scol;
    const unsigned short* gBk = wkb + (size_t)(bn + srow) * DIM_ + scol;
    const unsigned short* gBv = wvb + (size_t)(bn + srow) * DIM_ + scol;
    const int ldst = wid * 1024;

    const int r7   = (lr & 7) << 4;
    const int arow = (wm * 64 + lr) * 128;
    const int brow = (wn * 64 + lr) * 128;
    const int off0 = (lg << 4) ^ r7;
    const int off1 = (64 | (lg << 4)) ^ r7;

    fp32x4 acck[4][4] = {};
    fp32x4 accv[4][4] = {};

#define STG8(BUF, T) do {                                                         \
    gld16(gA  + (size_t)(T) * 64,               &As_[BUF][ldst]);                 \
    gld16(gA  + (size_t)64  * DIM_ + (T) * 64,  &As_[BUF][8192  + ldst]);         \
    gld16(gA  + (size_t)128 * DIM_ + (T) * 64,  &As_[BUF][16384 + ldst]);         \
    gld16(gA  + (size_t)192 * DIM_ + (T) * 64,  &As_[BUF][24576 + ldst]);         \
    gld16(gBk + (size_t)(T) * 64,               &Bks_[BUF][ldst]);                \
    gld16(gBk + (size_t)64  * DIM_ + (T) * 64,  &Bks_[BUF][8192 + ldst]);         \
    gld16(gBv + (size_t)(T) * 64,               &Bvs_[BUF][ldst]);                \
    gld16(gBv + (size_t)64  * DIM_ + (T) * 64,  &Bvs_[BUF][8192 + ldst]);         \
} while (0)

    STG8(0, 0);
    asm volatile("s_waitcnt vmcnt(0)" ::: "memory");
    __builtin_amdgcn_s_barrier();

    for (int t = 0; t < NT_; ++t) {
        const int buf = t & 1;
        if (t + 1 < NT_) STG8(buf ^ 1, t + 1);

        char* Ab  = &As_[buf][0];
        char* Bkb = &Bks_[buf][0];
        char* Bvb = &Bvs_[buf][0];

        #pragma unroll
        for (int kk = 0; kk < 2; ++kk) {
            const int o = kk ? off1 : off0;
            s16x8 fa[4], fk[4];
            #pragma unroll
            for (int mi = 0; mi < 4; ++mi)
                fa[mi] = *reinterpret_cast<const s16x8*>(&Ab[arow + mi * 2048 + o]);
            #pragma unroll
            for (int nf = 0; nf < 4; ++nf)
                fk[nf] = *reinterpret_cast<const s16x8*>(&Bkb[brow + nf * 2048 + o]);
            __builtin_amdgcn_s_setprio(1);
            #pragma unroll
            for (int mi = 0; mi < 4; ++mi)
                #pragma unroll
                for (int nf = 0; nf < 4; ++nf)
                    acck[mi][nf] = MFMA(fa[mi], fk[nf], acck[mi][nf]);
            __builtin_amdgcn_s_setprio(0);
            s16x8 fv[4];
            #pragma unroll
            for (int nf = 0; nf < 4; ++nf)
                fv[nf] = *reinterpret_cast<const s16x8*>(&Bvb[brow + nf * 2048 + o]);
            __builtin_amdgcn_s_setprio(1);
            #pragma unroll
            for (int mi = 0; mi < 4; ++mi)
                #pragma unroll
                for (int nf = 0; nf < 4; ++nf)
                    accv[mi][nf] = MFMA(fa[mi], fv[nf], accv[mi][nf]);
            __builtin_amdgcn_s_setprio(0);
        }

        if (t + 1 < NT_) {
            asm volatile("s_waitcnt vmcnt(0)" ::: "memory");
            __builtin_amdgcn_s_barrier();
        }
    }
#undef STG8

    // epilogues: K frag-linear, V frag-linear
    const int bb = bm >> 11;
    const size_t bh0 = (size_t)(bb * H_) * (L_ * DH_);
    const int rbase = bm + wm * 64;
    const int cbase = bn + wn * 64;

    #pragma unroll
    for (int mf = 0; mf < 4; ++mf)
        #pragma unroll
        for (int rr = 0; rr < 4; ++rr) {
            int l = (rbase + mf * 16 + lg * 4 + rr) & (L_ - 1);
            #pragma unroll
            for (int nf = 0; nf < 4; ++nf) {
                int dc = cbase + nf * 16 + lr;
                int h = dc >> 7, d = dc & 127;
                size_t off = bh0 + (size_t)h * (L_ * DH_)
                    + (size_t)(((l >> 4) * 4 + (d >> 5)) * 512
                    + ((l & 15) + (((d >> 3) & 3) << 4)) * 8 + (d & 7));
                k_ws[off] = bf16_rne(acck[mf][nf][rr]);
            }
        }

    #pragma unroll
    for (int mf = 0; mf < 4; ++mf) {
        int l0 = (rbase + mf * 16 + lg * 4) & (L_ - 1);
        #pragma unroll
        for (int nf = 0; nf < 4; ++nf) {
            int dc = cbase + nf * 16 + lr;
            int h = dc >> 7, d = dc & 127;
            size_t off = bh0 + (size_t)h * (L_ * DH_)
                + (size_t)(((l0 >> 5) * 8 + (d >> 4)) * 512
                + ((d & 15) + (((l0 >> 3) & 3) << 4)) * 8 + (l0 & 7));
            ushort4 pk;
            pk.x = bf16_rne(accv[mf][nf][0]);
            pk.y = bf16_rne(accv[mf][nf][1]);
            pk.z = bf16_rne(accv[mf][nf][2]);
            pk.w = bf16_rne(accv[mf][nf][3]);
            *reinterpret_cast<ushort4*>(&v_ws[off]) = pk;
        }
    }
}

// ---------------------------------------------------------------------------
// Attention (unchanged): swapped QK^T, cvt_pk P-pack, ones-MFMA rowsums,
// mask pre-folded into Q, K via global_load_lds dbuf, V frag-linear direct.
// ---------------------------------------------------------------------------
__global__ void __launch_bounds__(256, 2)
attn_fused3(const unsigned short* __restrict__ qw, const unsigned short* __restrict__ kfr,
            const unsigned short* __restrict__ vfr, float* __restrict__ out)
{
    __shared__ __align__(16) char Ks[2][16384];
    __shared__ __align__(16) char Pl[4][4608];

    const int tid  = threadIdx.x;
    const int lane = tid & 63;
    const int wid  = tid >> 6;
    const int lr   = lane & 15;
    const int lg   = lane >> 4;

    const int p  = (blockIdx.x & 7) * 64 + (blockIdx.x >> 3);
    const int bh = p >> 4;
    const int qt = p & 15;
    const int b  = bh >> 4;
    const int h  = bh & 15;
    const int q0 = qt * 128 + wid * 32;

    const unsigned short* qbase = qw  + (size_t)bh * (L_ * DH_);
    const unsigned short* kbase = kfr + (size_t)bh * (L_ * DH_);
    const unsigned short* vbase = vfr + (size_t)bh * (L_ * DH_);

    s16x8 qf[2][4];
    #pragma unroll
    for (int qs = 0; qs < 2; ++qs)
        #pragma unroll
        for (int kc = 0; kc < 4; ++kc)
            qf[qs][kc] = *reinterpret_cast<const s16x8*>(
                &qbase[(size_t)(q0 + qs * 16 + lr) * DH_ + kc * 32 + lg * 8]);

    s16x8 ones;
    #pragma unroll
    for (int i = 0; i < 8; ++i) ones[i] = (short)0x3F80;

    fp32x4 acc[2][8] = {};
    fp32x4 racc[2] = {};

    char* P = &Pl[wid][0];

    auto STAGE = [&](int buf, int t) {
        const unsigned short* g = kbase + (size_t)t * 8192;
        #pragma unroll
        for (int c = 0; c < 4; ++c)
            gld16(g + c * 2048 + tid * 8, &Ks[buf][c * 4096 + wid * 1024]);
    };

    STAGE(0, 0);
    __syncthreads();

    for (int t = 0; t < L_ / 64; ++t) {
        const int buf = t & 1;
        if (t + 1 < L_ / 64) STAGE(buf ^ 1, t + 1);

        s16x8 vv0[8], vv1[8];
        #pragma unroll
        for (int ds = 0; ds < 8; ++ds)
            vv0[ds] = *reinterpret_cast<const s16x8*>(
                &vbase[(size_t)t * 8192 + (0 * 8 + ds) * 512 + lane * 8]);

        fp32x4 s2[2][4] = {};
        __builtin_amdgcn_s_setprio(1);
        #pragma unroll
        for (int kvs = 0; kvs < 4; ++kvs)
            #pragma unroll
            for (int kc = 0; kc < 4; ++kc) {
                s16x8 kf = *reinterpret_cast<const s16x8*>(
                    Ks[buf] + (kvs * 4 + kc) * 1024 + lane * 16);
                s2[0][kvs] = MFMA(kf, qf[0][kc], s2[0][kvs]);
                s2[1][kvs] = MFMA(kf, qf[1][kc], s2[1][kvs]);
            }
        __builtin_amdgcn_s_setprio(0);

        #pragma unroll
        for (int qs = 0; qs < 2; ++qs)
            #pragma unroll
            for (int kvs = 0; kvs < 4; ++kvs) {
                float e0 = exp2_raw(s2[qs][kvs][0]);
                float e1 = exp2_raw(s2[qs][kvs][1]);
                float e2 = exp2_raw(s2[qs][kvs][2]);
                float e3 = exp2_raw(s2[qs][kvs][3]);
                uint2 pk;
                pk.x = cvtpk_bf16(e0, e1);
                pk.y = cvtpk_bf16(e2, e3);
                *reinterpret_cast<uint2*>(P + qs * 2304 + lr * 144 + kvs * 32 + lg * 8) = pk;
            }

        #pragma unroll
        for (int ds = 0; ds < 8; ++ds)
            vv1[ds] = *reinterpret_cast<const s16x8*>(
                &vbase[(size_t)t * 8192 + (1 * 8 + ds) * 512 + lane * 8]);

        __builtin_amdgcn_s_setprio(1);
        #pragma unroll
        for (int qs = 0; qs < 2; ++qs) {
            s16x8 pa0 = *reinterpret_cast<const s16x8*>(P + qs * 2304 + lr * 144 + 0 * 64 + lg * 16);
            s16x8 pa1 = *reinterpret_cast<const s16x8*>(P + qs * 2304 + lr * 144 + 1 * 64 + lg * 16);
            racc[qs] = MFMA(pa0, ones, racc[qs]);
            racc[qs] = MFMA(pa1, ones, racc[qs]);
            #pragma unroll
            for (int ds = 0; ds < 8; ++ds) {
                acc[qs][ds] = MFMA(pa0, vv0[ds], acc[qs][ds]);
                acc[qs][ds] = MFMA(pa1, vv1[ds], acc[qs][ds]);
            }
        }
        __builtin_amdgcn_s_setprio(0);

        __syncthreads();
    }

    #pragma unroll
    for (int qs = 0; qs < 2; ++qs) {
        float inv[4];
        #pragma unroll
        for (int r = 0; r < 4; ++r) inv[r] = 1.0f / racc[qs][r];
        #pragma unroll
        for (int ds = 0; ds < 8; ++ds)
            #pragma unroll
            for (int r = 0; r < 4; ++r)
                out[((size_t)(b * L_ + q0 + qs * 16 + lg * 4 + r)) * DIM_ + h * DH_ + ds * 16 + lr]
                    = acc[qs][ds][r] * inv[r];
    }
}

extern "C" void kernel_launch(void* const* d_in, const int* in_sizes, int n_in,
                              void* d_out, int out_size, void* d_ws, size_t ws_size,
                              hipStream_t stream) {
    const float* query = (const float*)d_in[0];
    const float* value = (const float*)d_in[1];
    const float* mask  = (const float*)d_in[2];
    const float* Wq    = (const float*)d_in[3];
    const float* Wk    = (const float*)d_in[4];
    const float* Wv    = (const float*)d_in[5];
    float* out = (float*)d_out;

    const size_t elems  = (size_t)B_ * H_ * L_ * DH_;  // 8388608
    const size_t welems = elems / 2;                   // 4194304
    unsigned short* q_ws = (unsigned short*)d_ws;
    unsigned short* k_ws = q_ws + elems;
    unsigned short* v_ws = k_ws + elems;

    unsigned short* qbf  = v_ws + elems;
    unsigned short* vbf  = qbf + elems;
    unsigned short* wqbf = vbf + elems;
    unsigned short* wkbf = wqbf + welems;
    unsigned short* wvbf = wkbf + welems;

    dim3 blk(256, 1, 1);

    cvt_all<<<dim3(2048, 1, 1), blk, 0, stream>>>(query, value, Wq, Wk, Wv,
                                                  qbf, vbf, wqbf, wkbf, wvbf);
    qgemm<<<dim3(256, 1, 1), dim3(512, 1, 1), 0, stream>>>(qbf, wqbf, mask, q_ws);
    kvgemm<<<dim3(256, 1, 1), dim3(512, 1, 1), 0, stream>>>(vbf, wkbf, wvbf, k_ws, v_ws);

    attn_fused3<<<dim3(512, 1, 1), blk, 0, stream>>>(q_ws, k_ws, v_ws, out);
}

// Round 11
// 194.645 us; speedup vs baseline: 3.4095x; 1.0003x over previous
//
#include <hip/hip_runtime.h>
#include <hip/hip_bf16.h>
#include <stdint.h>

#define DIM_ 2048
#define L_   2048
#define B_   2
#define H_   16
#define DH_  128
#define NT_  32   // K tiles of 64

// scale folded into Wq: (1/sqrt(128)) * log2(e)  -> softmax uses raw v_exp_f32
#define QSCALE_ 0.12751743f

typedef __attribute__((ext_vector_type(4))) float fp32x4;
typedef __attribute__((ext_vector_type(8))) short s16x8;

__device__ __forceinline__ unsigned short bf16_rne(float f) {
    unsigned u = __builtin_bit_cast(unsigned, f);
    u += 0x7fffu + ((u >> 16) & 1u);
    return (unsigned short)(u >> 16);
}

__device__ __forceinline__ fp32x4 MFMA(s16x8 a, s16x8 b, fp32x4 c) {
    return __builtin_amdgcn_mfma_f32_16x16x32_bf16(a, b, c, 0, 0, 0);
}

__device__ __forceinline__ void gld16(const void* g, void* l) {
    auto gp = reinterpret_cast<const uint32_t __attribute__((address_space(1)))*>(
        reinterpret_cast<uintptr_t>(g));
    auto lp = reinterpret_cast<uint32_t __attribute__((address_space(3)))*>(
        reinterpret_cast<uintptr_t>(l));
    __builtin_amdgcn_global_load_lds(gp, lp, 16, 0, 0);
}

__device__ __forceinline__ float exp2_raw(float x) {
    float r; asm("v_exp_f32 %0, %1" : "=v"(r) : "v"(x)); return r;
}

__device__ __forceinline__ unsigned cvtpk_bf16(float a, float b) {
    unsigned r; asm("v_cvt_pk_bf16_f32 %0, %1, %2" : "=v"(r) : "v"(a), "v"(b)); return r;
}

// ---------------------------------------------------------------------------
// Merged f32->bf16 conversion: query | value | Wq(*QSCALE_) | Wk | Wv
// ---------------------------------------------------------------------------
__global__ void __launch_bounds__(256)
cvt_all(const float* __restrict__ query, const float* __restrict__ value,
        const float* __restrict__ Wq, const float* __restrict__ Wk,
        const float* __restrict__ Wv,
        unsigned short* __restrict__ qb, unsigned short* __restrict__ vb,
        unsigned short* __restrict__ wqb, unsigned short* __restrict__ wkb,
        unsigned short* __restrict__ wvb)
{
    const int total4 = 7340032;
    int i = blockIdx.x * 256 + threadIdx.x;
    const int stride = gridDim.x * 256;
    for (; i < total4; i += stride) {
        const float4* s; ushort4* d; int off; float sc = 1.0f;
        if (i < 2097152)      { s = (const float4*)query; d = (ushort4*)qb;  off = i; }
        else if (i < 4194304) { s = (const float4*)value; d = (ushort4*)vb;  off = i - 2097152; }
        else if (i < 5242880) { s = (const float4*)Wq;    d = (ushort4*)wqb; off = i - 4194304; sc = QSCALE_; }
        else if (i < 6291456) { s = (const float4*)Wk;    d = (ushort4*)wkb; off = i - 5242880; }
        else                  { s = (const float4*)Wv;    d = (ushort4*)wvb; off = i - 6291456; }
        float4 v = s[off];
        ushort4 o;
        o.x = bf16_rne(v.x * sc); o.y = bf16_rne(v.y * sc);
        o.z = bf16_rne(v.z * sc); o.w = bf16_rne(v.w * sc);
        d[off] = o;
    }
}

// ---------------------------------------------------------------------------
// Q projection GEMM (unchanged): 256x128, triple-buffered, one barrier +
// counted vmcnt(6) per tile, full 3-bit both-sides chunk swizzle.
// ---------------------------------------------------------------------------
__global__ void __launch_bounds__(512, 2)
qgemm(const unsigned short* __restrict__ qb, const unsigned short* __restrict__ wqb,
      const float* __restrict__ mask, unsigned short* __restrict__ q_ws)
{
    __shared__ __align__(16) char As_[3][32768];
    __shared__ __align__(16) char Bs_[3][16384];

    const int tid  = threadIdx.x;
    const int lane = tid & 63;
    const int wid  = tid >> 6;
    const int wm   = wid >> 1;
    const int wn   = wid & 1;
    const int lr   = lane & 15;
    const int lg   = lane >> 4;

    const int rb = (blockIdx.x & 7) * 32 + (blockIdx.x >> 3);
    const int bm = (rb >> 4) << 8;
    const int bn = (rb & 15) << 7;

    const int srow = tid >> 3;
    const int scol = ((tid & 7) ^ ((tid >> 3) & 7)) * 8;
    const unsigned short* gA = qb  + (size_t)(bm + srow) * DIM_ + scol;
    const unsigned short* gB = wqb + (size_t)(bn + srow) * DIM_ + scol;
    const int ldst = wid * 1024;

    const int r7   = (lr & 7) << 4;
    const int arow = (wm * 64 + lr) * 128;
    const int brow = (wn * 64 + lr) * 128;
    const int off0 = (lg << 4) ^ r7;
    const int off1 = (64 | (lg << 4)) ^ r7;

    fp32x4 acc[4][4] = {};

#define STG6(SA, SB, T) do {                                                      \
    gld16(gA + (size_t)(T) * 64,                 (SA) + ldst);                    \
    gld16(gA + (size_t)64  * DIM_ + (T) * 64,    (SA) + 8192  + ldst);            \
    gld16(gA + (size_t)128 * DIM_ + (T) * 64,    (SA) + 16384 + ldst);            \
    gld16(gA + (size_t)192 * DIM_ + (T) * 64,    (SA) + 24576 + ldst);            \
    gld16(gB + (size_t)(T) * 64,                 (SB) + ldst);                    \
    gld16(gB + (size_t)64  * DIM_ + (T) * 64,    (SB) + 8192  + ldst);            \
} while (0)

    STG6(&As_[0][0], &Bs_[0][0], 0);
    STG6(&As_[1][0], &Bs_[1][0], 1);
    asm volatile("s_waitcnt vmcnt(6)" ::: "memory");
    __builtin_amdgcn_s_barrier();

    for (int t = 0; t < NT_; ++t) {
        char* Ab = &As_[t % 3][0];
        char* Bb = &Bs_[t % 3][0];
        if (t < NT_ - 2) {
            STG6(&As_[(t + 2) % 3][0], &Bs_[(t + 2) % 3][0], t + 2);
        }

        s16x8 fa0[4], fa1[4], fb0[4], fb1[4];
        #pragma unroll
        for (int mi = 0; mi < 4; ++mi) {
            fa0[mi] = *reinterpret_cast<const s16x8*>(&Ab[arow + mi * 2048 + off0]);
            fa1[mi] = *reinterpret_cast<const s16x8*>(&Ab[arow + mi * 2048 + off1]);
        }
        #pragma unroll
        for (int nf = 0; nf < 4; ++nf) {
            fb0[nf] = *reinterpret_cast<const s16x8*>(&Bb[brow + nf * 2048 + off0]);
            fb1[nf] = *reinterpret_cast<const s16x8*>(&Bb[brow + nf * 2048 + off1]);
        }

        __builtin_amdgcn_s_setprio(1);
        #pragma unroll
        for (int mi = 0; mi < 4; ++mi)
            #pragma unroll
            for (int nf = 0; nf < 4; ++nf)
                acc[mi][nf] = MFMA(fa0[mi], fb0[nf], acc[mi][nf]);
        #pragma unroll
        for (int mi = 0; mi < 4; ++mi)
            #pragma unroll
            for (int nf = 0; nf < 4; ++nf)
                acc[mi][nf] = MFMA(fa1[mi], fb1[nf], acc[mi][nf]);
        __builtin_amdgcn_s_setprio(0);

        if (t < NT_ - 2) {
            asm volatile("s_waitcnt vmcnt(6)" ::: "memory");
            __builtin_amdgcn_s_barrier();
        } else if (t == NT_ - 2) {
            asm volatile("s_waitcnt vmcnt(0)" ::: "memory");
            __builtin_amdgcn_s_barrier();
        }
    }
#undef STG6

    const int bb = bm >> 11;
    const size_t bh0 = (size_t)(bb * H_) * (L_ * DH_);
    const int rbase = bm + wm * 64;
    const int cbase = bn + wn * 64;
    const float* mrow = mask + bb * L_;

    #pragma unroll
    for (int mf = 0; mf < 4; ++mf)
        #pragma unroll
        for (int rr = 0; rr < 4; ++rr) {
            int l = (rbase + mf * 16 + lg * 4 + rr) & (L_ - 1);
            float mvv = mrow[l];
            #pragma unroll
            for (int nf = 0; nf < 4; ++nf) {
                int dc = cbase + nf * 16 + lr;
                int h = dc >> 7, d = dc & 127;
                q_ws[bh0 + (size_t)h * (L_ * DH_) + (size_t)l * DH_ + d]
                    = bf16_rne(acc[mf][nf][rr] * mvv);
            }
        }
}

// ---------------------------------------------------------------------------
// Fused K+V projection GEMM (unchanged from round 10).
// ---------------------------------------------------------------------------
__global__ void __launch_bounds__(512, 2)
kvgemm(const unsigned short* __restrict__ vb, const unsigned short* __restrict__ wkb,
       const unsigned short* __restrict__ wvb,
       unsigned short* __restrict__ k_ws, unsigned short* __restrict__ v_ws)
{
    __shared__ __align__(16) char As_[2][32768];
    __shared__ __align__(16) char Bks_[2][16384];
    __shared__ __align__(16) char Bvs_[2][16384];

    const int tid  = threadIdx.x;
    const int lane = tid & 63;
    const int wid  = tid >> 6;
    const int wm   = wid >> 1;
    const int wn   = wid & 1;
    const int lr   = lane & 15;
    const int lg   = lane >> 4;

    const int rb = (blockIdx.x & 7) * 32 + (blockIdx.x >> 3);
    const int bm = (rb >> 4) << 8;
    const int bn = (rb & 15) << 7;

    const int srow = tid >> 3;
    const int scol = ((tid & 7) ^ ((tid >> 3) & 7)) * 8;
    const unsigned short* gA  = vb  + (size_t)(bm + srow) * DIM_ + scol;
    const unsigned short* gBk = wkb + (size_t)(bn + srow) * DIM_ + scol;
    const unsigned short* gBv = wvb + (size_t)(bn + srow) * DIM_ + scol;
    const int ldst = wid * 1024;

    const int r7   = (lr & 7) << 4;
    const int arow = (wm * 64 + lr) * 128;
    const int brow = (wn * 64 + lr) * 128;
    const int off0 = (lg << 4) ^ r7;
    const int off1 = (64 | (lg << 4)) ^ r7;

    fp32x4 acck[4][4] = {};
    fp32x4 accv[4][4] = {};

#define STG8(BUF, T) do {                                                         \
    gld16(gA  + (size_t)(T) * 64,               &As_[BUF][ldst]);                 \
    gld16(gA  + (size_t)64  * DIM_ + (T) * 64,  &As_[BUF][8192  + ldst]);         \
    gld16(gA  + (size_t)128 * DIM_ + (T) * 64,  &As_[BUF][16384 + ldst]);         \
    gld16(gA  + (size_t)192 * DIM_ + (T) * 64,  &As_[BUF][24576 + ldst]);         \
    gld16(gBk + (size_t)(T) * 64,               &Bks_[BUF][ldst]);                \
    gld16(gBk + (size_t)64  * DIM_ + (T) * 64,  &Bks_[BUF][8192 + ldst]);         \
    gld16(gBv + (size_t)(T) * 64,               &Bvs_[BUF][ldst]);                \
    gld16(gBv + (size_t)64  * DIM_ + (T) * 64,  &Bvs_[BUF][8192 + ldst]);         \
} while (0)

    STG8(0, 0);
    asm volatile("s_waitcnt vmcnt(0)" ::: "memory");
    __builtin_amdgcn_s_barrier();

    for (int t = 0; t < NT_; ++t) {
        const int buf = t & 1;
        if (t + 1 < NT_) STG8(buf ^ 1, t + 1);

        char* Ab  = &As_[buf][0];
        char* Bkb = &Bks_[buf][0];
        char* Bvb = &Bvs_[buf][0];

        #pragma unroll
        for (int kk = 0; kk < 2; ++kk) {
            const int o = kk ? off1 : off0;
            s16x8 fa[4], fk[4];
            #pragma unroll
            for (int mi = 0; mi < 4; ++mi)
                fa[mi] = *reinterpret_cast<const s16x8*>(&Ab[arow + mi * 2048 + o]);
            #pragma unroll
            for (int nf = 0; nf < 4; ++nf)
                fk[nf] = *reinterpret_cast<const s16x8*>(&Bkb[brow + nf * 2048 + o]);
            __builtin_amdgcn_s_setprio(1);
            #pragma unroll
            for (int mi = 0; mi < 4; ++mi)
                #pragma unroll
                for (int nf = 0; nf < 4; ++nf)
                    acck[mi][nf] = MFMA(fa[mi], fk[nf], acck[mi][nf]);
            __builtin_amdgcn_s_setprio(0);
            s16x8 fv[4];
            #pragma unroll
            for (int nf = 0; nf < 4; ++nf)
                fv[nf] = *reinterpret_cast<const s16x8*>(&Bvb[brow + nf * 2048 + o]);
            __builtin_amdgcn_s_setprio(1);
            #pragma unroll
            for (int mi = 0; mi < 4; ++mi)
                #pragma unroll
                for (int nf = 0; nf < 4; ++nf)
                    accv[mi][nf] = MFMA(fa[mi], fv[nf], accv[mi][nf]);
            __builtin_amdgcn_s_setprio(0);
        }

        if (t + 1 < NT_) {
            asm volatile("s_waitcnt vmcnt(0)" ::: "memory");
            __builtin_amdgcn_s_barrier();
        }
    }
#undef STG8

    const int bb = bm >> 11;
    const size_t bh0 = (size_t)(bb * H_) * (L_ * DH_);
    const int rbase = bm + wm * 64;
    const int cbase = bn + wn * 64;

    #pragma unroll
    for (int mf = 0; mf < 4; ++mf)
        #pragma unroll
        for (int rr = 0; rr < 4; ++rr) {
            int l = (rbase + mf * 16 + lg * 4 + rr) & (L_ - 1);
            #pragma unroll
            for (int nf = 0; nf < 4; ++nf) {
                int dc = cbase + nf * 16 + lr;
                int h = dc >> 7, d = dc & 127;
                size_t off = bh0 + (size_t)h * (L_ * DH_)
                    + (size_t)(((l >> 4) * 4 + (d >> 5)) * 512
                    + ((l & 15) + (((d >> 3) & 3) << 4)) * 8 + (d & 7));
                k_ws[off] = bf16_rne(acck[mf][nf][rr]);
            }
        }

    #pragma unroll
    for (int mf = 0; mf < 4; ++mf) {
        int l0 = (rbase + mf * 16 + lg * 4) & (L_ - 1);
        #pragma unroll
        for (int nf = 0; nf < 4; ++nf) {
            int dc = cbase + nf * 16 + lr;
            int h = dc >> 7, d = dc & 127;
            size_t off = bh0 + (size_t)h * (L_ * DH_)
                + (size_t)(((l0 >> 5) * 8 + (d >> 4)) * 512
                + ((d & 15) + (((l0 >> 3) & 3) << 4)) * 8 + (l0 & 7));
            ushort4 pk;
            pk.x = bf16_rne(accv[mf][nf][0]);
            pk.y = bf16_rne(accv[mf][nf][1]);
            pk.z = bf16_rne(accv[mf][nf][2]);
            pk.w = bf16_rne(accv[mf][nf][3]);
            *reinterpret_cast<ushort4*>(&v_ws[off]) = pk;
        }
    }
}

// ---------------------------------------------------------------------------
// Attention v4 — T15 double-pipeline: tile t = { stage K(t+1); load V(t-1);
// softmax(t-1)->P; QK(t)->s_cur; rowsum+PV(t-1) }. QK results are consumed
// one tile later, so their latency hides under softmax+PV; the exp segment
// is data-ready at tile start. Ping-pong sA/sB (static indexing, rule #20).
// ---------------------------------------------------------------------------
__global__ void __launch_bounds__(256, 2)
attn_fused4(const unsigned short* __restrict__ qw, const unsigned short* __restrict__ kfr,
            const unsigned short* __restrict__ vfr, float* __restrict__ out)
{
    __shared__ __align__(16) char Ks[2][16384];
    __shared__ __align__(16) char Pl[4][4608];

    const int tid  = threadIdx.x;
    const int lane = tid & 63;
    const int wid  = tid >> 6;
    const int lr   = lane & 15;
    const int lg   = lane >> 4;

    const int p  = (blockIdx.x & 7) * 64 + (blockIdx.x >> 3);
    const int bh = p >> 4;
    const int qt = p & 15;
    const int b  = bh >> 4;
    const int h  = bh & 15;
    const int q0 = qt * 128 + wid * 32;

    const unsigned short* qbase = qw  + (size_t)bh * (L_ * DH_);
    const unsigned short* kbase = kfr + (size_t)bh * (L_ * DH_);
    const unsigned short* vbase = vfr + (size_t)bh * (L_ * DH_);

    s16x8 qf[2][4];
    #pragma unroll
    for (int qs = 0; qs < 2; ++qs)
        #pragma unroll
        for (int kc = 0; kc < 4; ++kc)
            qf[qs][kc] = *reinterpret_cast<const s16x8*>(
                &qbase[(size_t)(q0 + qs * 16 + lr) * DH_ + kc * 32 + lg * 8]);

    s16x8 ones;
    #pragma unroll
    for (int i = 0; i < 8; ++i) ones[i] = (short)0x3F80;

    fp32x4 acc[2][8] = {};
    fp32x4 racc[2] = {};
    fp32x4 sA[2][4], sB[2][4];

    char* P = &Pl[wid][0];

    auto STAGE = [&](int buf, int t) {
        const unsigned short* g = kbase + (size_t)t * 8192;
        #pragma unroll
        for (int c = 0; c < 4; ++c)
            gld16(g + c * 2048 + tid * 8, &Ks[buf][c * 4096 + wid * 1024]);
    };

    // QK(t) -> sc (zero-init inside)
    auto qk_tile = [&](int t, fp32x4 (&sc)[2][4]) {
        char* kb = &Ks[t & 1][0];
        #pragma unroll
        for (int qs = 0; qs < 2; ++qs)
            #pragma unroll
            for (int kvs = 0; kvs < 4; ++kvs)
                sc[qs][kvs] = fp32x4{0.f, 0.f, 0.f, 0.f};
        #pragma unroll
        for (int kvs = 0; kvs < 4; ++kvs)
            #pragma unroll
            for (int kc = 0; kc < 4; ++kc) {
                s16x8 kf = *reinterpret_cast<const s16x8*>(
                    kb + (kvs * 4 + kc) * 1024 + lane * 16);
                sc[0][kvs] = MFMA(kf, qf[0][kc], sc[0][kvs]);
                sc[1][kvs] = MFMA(kf, qf[1][kc], sc[1][kvs]);
            }
    };

    // softmax(sp) -> P (per-wave LDS, in-order; no barrier needed)
    auto smax = [&](fp32x4 (&sp)[2][4]) {
        #pragma unroll
        for (int qs = 0; qs < 2; ++qs)
            #pragma unroll
            for (int kvs = 0; kvs < 4; ++kvs) {
                float e0 = exp2_raw(sp[qs][kvs][0]);
                float e1 = exp2_raw(sp[qs][kvs][1]);
                float e2 = exp2_raw(sp[qs][kvs][2]);
                float e3 = exp2_raw(sp[qs][kvs][3]);
                uint2 pk;
                pk.x = cvtpk_bf16(e0, e1);
                pk.y = cvtpk_bf16(e2, e3);
                *reinterpret_cast<uint2*>(P + qs * 2304 + lr * 144 + kvs * 32 + lg * 8) = pk;
            }
    };

    // rowsum + PV from P and vv
    auto pv = [&](s16x8 (&vv0)[8], s16x8 (&vv1)[8]) {
        #pragma unroll
        for (int qs = 0; qs < 2; ++qs) {
            s16x8 pa0 = *reinterpret_cast<const s16x8*>(P + qs * 2304 + lr * 144 + 0 * 64 + lg * 16);
            s16x8 pa1 = *reinterpret_cast<const s16x8*>(P + qs * 2304 + lr * 144 + 1 * 64 + lg * 16);
            racc[qs] = MFMA(pa0, ones, racc[qs]);
            racc[qs] = MFMA(pa1, ones, racc[qs]);
            #pragma unroll
            for (int ds = 0; ds < 8; ++ds) {
                acc[qs][ds] = MFMA(pa0, vv0[ds], acc[qs][ds]);
                acc[qs][ds] = MFMA(pa1, vv1[ds], acc[qs][ds]);
            }
        }
    };

    // body for tile t>=1: QK(t) plus finish of t-1
    auto body = [&](int t, fp32x4 (&sc)[2][4], fp32x4 (&sp)[2][4]) {
        if (t + 1 < NT_) STAGE((t + 1) & 1, t + 1);
        s16x8 vv0[8], vv1[8];
        const size_t vbt = (size_t)(t - 1) * 8192;
        #pragma unroll
        for (int ds = 0; ds < 8; ++ds)
            vv0[ds] = *reinterpret_cast<const s16x8*>(&vbase[vbt + ds * 512 + lane * 8]);
        #pragma unroll
        for (int ds = 0; ds < 8; ++ds)
            vv1[ds] = *reinterpret_cast<const s16x8*>(&vbase[vbt + (8 + ds) * 512 + lane * 8]);

        smax(sp);                         // data-ready: prev tile's scores

        __builtin_amdgcn_s_setprio(1);
        qk_tile(t, sc);                   // 16 ds_read + 32 MFMA
        pv(vv0, vv1);                     // 4 + 32 MFMA, operands all ready
        __builtin_amdgcn_s_setprio(0);

        __syncthreads();                  // drains K-stage vmcnt + buffer WAR
    };

    // prologue: K0 staged + synced; tile 0 = QK only
    STAGE(0, 0);
    __syncthreads();
    STAGE(1, 1);
    qk_tile(0, sA);
    __syncthreads();

    for (int t = 1; t + 1 < NT_; t += 2) {
        body(t, sB, sA);
        body(t + 1, sA, sB);
    }
    body(NT_ - 1, sB, sA);                // QK(31), PV(30)

    // epilogue: finish tile 31
    {
        s16x8 vv0[8], vv1[8];
        const size_t vbt = (size_t)(NT_ - 1) * 8192;
        #pragma unroll
        for (int ds = 0; ds < 8; ++ds)
            vv0[ds] = *reinterpret_cast<const s16x8*>(&vbase[vbt + ds * 512 + lane * 8]);
        #pragma unroll
        for (int ds = 0; ds < 8; ++ds)
            vv1[ds] = *reinterpret_cast<const s16x8*>(&vbase[vbt + (8 + ds) * 512 + lane * 8]);
        smax(sB);
        pv(vv0, vv1);
    }

    #pragma unroll
    for (int qs = 0; qs < 2; ++qs) {
        float inv[4];
        #pragma unroll
        for (int r = 0; r < 4; ++r) inv[r] = 1.0f / racc[qs][r];
        #pragma unroll
        for (int ds = 0; ds < 8; ++ds)
            #pragma unroll
            for (int r = 0; r < 4; ++r)
                out[((size_t)(b * L_ + q0 + qs * 16 + lg * 4 + r)) * DIM_ + h * DH_ + ds * 16 + lr]
                    = acc[qs][ds][r] * inv[r];
    }
}

extern "C" void kernel_launch(void* const* d_in, const int* in_sizes, int n_in,
                              void* d_out, int out_size, void* d_ws, size_t ws_size,
                              hipStream_t stream) {
    const float* query = (const float*)d_in[0];
    const float* value = (const float*)d_in[1];
    const float* mask  = (const float*)d_in[2];
    const float* Wq    = (const float*)d_in[3];
    const float* Wk    = (const float*)d_in[4];
    const float* Wv    = (const float*)d_in[5];
    float* out = (float*)d_out;

    const size_t elems  = (size_t)B_ * H_ * L_ * DH_;  // 8388608
    const size_t welems = elems / 2;                   // 4194304
    unsigned short* q_ws = (unsigned short*)d_ws;
    unsigned short* k_ws = q_ws + elems;
    unsigned short* v_ws = k_ws + elems;

    unsigned short* qbf  = v_ws + elems;
    unsigned short* vbf  = qbf + elems;
    unsigned short* wqbf = vbf + elems;
    unsigned short* wkbf = wqbf + welems;
    unsigned short* wvbf = wkbf + welems;

    dim3 blk(256, 1, 1);

    cvt_all<<<dim3(2048, 1, 1), blk, 0, stream>>>(query, value, Wq, Wk, Wv,
                                                  qbf, vbf, wqbf, wkbf, wvbf);
    qgemm<<<dim3(256, 1, 1), dim3(512, 1, 1), 0, stream>>>(qbf, wqbf, mask, q_ws);
    kvgemm<<<dim3(256, 1, 1), dim3(512, 1, 1), 0, stream>>>(vbf, wkbf, wvbf, k_ws, v_ws);

    attn_fused4<<<dim3(512, 1, 1), blk, 0, stream>>>(q_ws, k_ws, v_ws, out);
}